// Round 11
// baseline (427.909 us; speedup 1.0000x reference)
//
#include <hip/hip_runtime.h>

// NeuralAudioGraph: N=256, D=H=512, E=128, 4 heads, 3 GAT layers.
// r18: k_uv split-K 4. Cost model (fits r8-r17): wall = per-wave serial
// load-chain x ~430cyc/wait; waves run chains concurrently, so only FEWER
// WAITS PER WAVE helps. k_uv had 256 waits (44us); split-K 4 -> 64 waits
// (~11.5us) at 2048 blocks = 8 waves/SIMD. Partials: f64 for ep (keeps the
// validated f64 pipeline; reassoc ~2^-51, invisible at f32), f32 for ef
// (ulp wiggle << bf16-dominated absmax). k_uvr sums partials in fixed order
// + bias. k_s MFMA path (r17, 612->410) and all else frozen.
// Baseline r17: 410us, absmax 0.0078125.

typedef __attribute__((ext_vector_type(8))) short short8;   // 8 x bf16 (MFMA frag)
typedef __attribute__((ext_vector_type(4))) float f32x4;    // MFMA accumulator
typedef unsigned short u16;
typedef unsigned int u32;

__device__ __forceinline__ float bf2f(u16 h) { return __uint_as_float(((u32)h) << 16); }
__device__ __forceinline__ u16 f2bf(float f) {
  u32 u = __float_as_uint(f);
  u += 0x7fffu + ((u >> 16) & 1u);   // round-to-nearest-even
  return (u16)(u >> 16);
}
__device__ __forceinline__ float lrelu(float v) { return fmaxf(v, 0.2f * v); }
__device__ __forceinline__ float ldany(int f32mode, const void* p, int i) {
  return f32mode ? ((const float*)p)[i] : bf2f(((const u16*)p)[i]);
}

// ---------------- dtype detector ----------------------------------------------------
__global__ __launch_bounds__(256) void k_detect(const u16* emb, int* flag) {
  bool big = false;
  for (int i = blockIdx.x * 256 + threadIdx.x; i < 131072; i += 256 * 64) {
    float v = bf2f(emb[i]);
    big |= !(fabsf(v) <= 1e6f);
  }
  unsigned long long m = __ballot(big);
  if (m && (threadIdx.x & 63) == 0) atomicOr(flag, 1);
}

// ---------------- small-vector ingest -> canonical f32 ------------------------------
struct VD { const void* src; int dst, n; };
struct VArgs { VD v[16]; };
__global__ __launch_bounds__(256) void k_vec(VArgs a, const int* flag, float* out) {
  int f = *flag;
  VD d = a.v[blockIdx.x];
  for (int i = threadIdx.x; i < d.n; i += 256)
    out[d.dst + i] = ldany(f, d.src, i);
}

// ---------------- big-matrix ingest -> canonical f32 --------------------------------
struct CArgs { const void* src[7]; float* dst[7]; int n[7]; };
__global__ __launch_bounds__(256) void k_cvt(CArgs a, const int* flag) {
  int f = *flag;
  int e = blockIdx.y;
  const void* s = a.src[e];
  float* d = a.dst[e];
  int n = a.n[e];
  for (int i = blockIdx.x * 256 + threadIdx.x; i < n; i += 2048 * 256)
    d[i] = ldany(f, s, i);
}

// ---------------- ef_w2 f32 [512][128] -> bf16 MFMA-fragment-linear -----------------
// w2fr[(kc*8+nt)*512 + l*8 + e] = bf16(w2[c = kc*32+(l>>4)*8+e][n = nt*16+(l&15)])
__global__ __launch_bounds__(256) void k_w2tb(const float* efw2f, u16* w2fr) {
  int idx = blockIdx.x * 256 + threadIdx.x;   // 65536
  int e = idx & 7, l = (idx >> 3) & 63, nt = (idx >> 9) & 7, kc = idx >> 12;
  int n = nt * 16 + (l & 15);
  int c = kc * 32 + ((l >> 4) << 3) + e;
  w2fr[idx] = f2bf(efw2f[c * 128 + n]);
}

// ---------------- V rows -> f32 MFMA-fragment-linear --------------------------------
// vfrag[jb*8192 + kc*512 + l*8 + e] = V[jb*16+(l&15)][kc*32+(l>>4)*8+e]
__global__ __launch_bounds__(256) void k_vfr(const float* uvf, float* vfrag) {
  const float* V = uvf + 393216;
  int idx = blockIdx.x * 256 + threadIdx.x;   // grid 512 -> 131072
  int e = idx & 7, l = (idx >> 3) & 63, kc = (idx >> 9) & 15, jb = idx >> 13;
  int j = jb * 16 + (l & 15);
  int c = kc * 32 + ((l >> 4) << 3) + e;
  vfrag[idx] = V[j * 512 + c];
}

// ---------------- GAT W[l] -> fragment-linear interleaved bf16 hi/lo ----------------
__global__ __launch_bounds__(256) void k_wfr(const float* Wf, u16* wfr) {
  int idx = blockIdx.x * 256 + threadIdx.x;   // 131072
  int lane = idx & 63, kc = (idx >> 6) & 15, nt = idx >> 10;
  int n = nt * 16 + (lane & 15);
  int c0 = kc * 32 + ((lane >> 4) << 3);
  u16* dst = wfr + idx * 16;
#pragma unroll
  for (int e = 0; e < 8; ++e) {
    float v = Wf[(c0 + e) * 2048 + n];
    u16 hi = f2bf(v);
    dst[e] = hi;
    dst[8 + e] = f2bf(v - bf2f(hi));
  }
}

// ---------------- x -> fragment-linear interleaved bf16 hi/lo -----------------------
__global__ __launch_bounds__(256) void k_xb(const float* x, u16* xfr) {
  int idx = blockIdx.x * 256 + threadIdx.x;   // 16384
  int lane = idx & 63, kc = (idx >> 6) & 15, it = idx >> 10;
  int i = it * 16 + (lane & 15);
  int c0 = kc * 32 + ((lane >> 4) << 3);
  const float* src = x + i * 512 + c0;
  float4 v0 = *(const float4*)(src);
  float4 v1 = *(const float4*)(src + 4);
  float vv[8] = {v0.x, v0.y, v0.z, v0.w, v1.x, v1.y, v1.z, v1.w};
  u16* dst = xfr + idx * 16;
#pragma unroll
  for (int e = 0; e < 8; ++e) {
    u16 hi = f2bf(vv[e]);
    dst[e] = hi;
    dst[8 + e] = f2bf(vv[e] - bf2f(hi));
  }
}

// ---------------- GAT s = x @ W[l] as MFMA (hi/lo 3-product) ------------------------
__global__ __launch_bounds__(256) void k_sm(const u16* xfr, const u16* wfr, float* sf) {
  int tid = threadIdx.x, lane = tid & 63, w = tid >> 6;
  int n0 = blockIdx.x * 32 + (w & 1) * 16;     // grid.x = 64
  int i0 = blockIdx.y * 32 + (w >> 1) * 16;    // grid.y = 8
  int it = i0 >> 4, nt = n0 >> 4;
  const u16* ap = xfr + (it * 16) * 1024 + lane * 16;
  const u16* bp = wfr + (nt * 16) * 1024 + lane * 16;
  f32x4 acc = (f32x4){0.f, 0.f, 0.f, 0.f};
#pragma unroll
  for (int kc = 0; kc < 16; ++kc) {
    short8 ah = *(const short8*)(ap + kc * 1024);
    short8 al = *(const short8*)(ap + kc * 1024 + 8);
    short8 bh = *(const short8*)(bp + kc * 1024);
    short8 bl = *(const short8*)(bp + kc * 1024 + 8);
    acc = __builtin_amdgcn_mfma_f32_16x16x32_bf16(ah, bh, acc, 0, 0, 0);
    acc = __builtin_amdgcn_mfma_f32_16x16x32_bf16(ah, bl, acc, 0, 0, 0);
    acc = __builtin_amdgcn_mfma_f32_16x16x32_bf16(al, bh, acc, 0, 0, 0);
  }
  int col = n0 + (lane & 15);
#pragma unroll
  for (int r = 0; r < 4; ++r) {
    int row = i0 + (lane >> 4) * 4 + r;
    sf[row * 2048 + col] = acc[r];
  }
}

// ---------------- U/V partials: split-K 4; f64 for ep (arr 0,1), f32 for ef ---------
// grid (2, 64, 16): x = col half, y = 4-row group, z = kq*4+arr. Same per-chunk
// accumulation expressions & k-order as the validated k_uv.
__global__ __launch_bounds__(256) void k_uv_sk(const float* embf, const float* epw1f,
    const float* efw1f, double* uvpd, float* uvpf) {
  int tid = threadIdx.x;
  int col = blockIdx.x * 256 + tid;
  int r0 = blockIdx.y * 4;
  int z = blockIdx.z;
  int arr = z & 3, kq = z >> 2;
  const float* W = ((arr < 2) ? epw1f : efw1f) + (arr & 1) * 262144 + col;
  const float* e = embf + r0 * 512;
  int kbeg = kq * 128, kend = kbeg + 128;
  if (arr < 2) {
    double a0 = 0.0, a1 = 0.0, a2 = 0.0, a3 = 0.0;
    for (int k = kbeg; k < kend; k += 2) {
      double w0 = (double)W[k * 512];
      double w1 = (double)W[(k + 1) * 512];
      float2 e0 = *(const float2*)(e + k);
      float2 e1 = *(const float2*)(e + 512 + k);
      float2 e2 = *(const float2*)(e + 1024 + k);
      float2 e3 = *(const float2*)(e + 1536 + k);
      a0 += (double)e0.x * w0 + (double)e0.y * w1;
      a1 += (double)e1.x * w0 + (double)e1.y * w1;
      a2 += (double)e2.x * w0 + (double)e2.y * w1;
      a3 += (double)e3.x * w0 + (double)e3.y * w1;
    }
    double* outp = uvpd + (kq * 2 + arr) * 131072 + r0 * 512 + col;
    outp[0]    = a0;
    outp[512]  = a1;
    outp[1024] = a2;
    outp[1536] = a3;
  } else {
    float a0 = 0.f, a1 = 0.f, a2 = 0.f, a3 = 0.f;
    for (int k = kbeg; k < kend; k += 2) {
      float w0 = W[k * 512], w1 = W[(k + 1) * 512];
      float2 e0 = *(const float2*)(e + k);
      float2 e1 = *(const float2*)(e + 512 + k);
      float2 e2 = *(const float2*)(e + 1024 + k);
      float2 e3 = *(const float2*)(e + 1536 + k);
      a0 = fmaf(e0.x, w0, fmaf(e0.y, w1, a0));
      a1 = fmaf(e1.x, w0, fmaf(e1.y, w1, a1));
      a2 = fmaf(e2.x, w0, fmaf(e2.y, w1, a2));
      a3 = fmaf(e3.x, w0, fmaf(e3.y, w1, a3));
    }
    float* outp = uvpf + (kq * 2 + (arr - 2)) * 131072 + r0 * 512 + col;
    outp[0]    = a0;
    outp[512]  = a1;
    outp[1024] = a2;
    outp[1536] = a3;
  }
}

// ---------------- reduce split-K partials (fixed order) + bias -> uvf ---------------
__global__ __launch_bounds__(256) void k_uvr(const double* uvpd, const float* uvpf,
    const float* vecf, float* uvf) {
  int idx = blockIdx.x * 256 + threadIdx.x;   // grid 2048 -> 524288
  int arr = idx >> 17;
  int off = idx & 131071;
  int col = off & 511;
  if (arr < 2) {
    double s = uvpd[arr * 131072 + off];
    s += uvpd[(2 + arr) * 131072 + off];
    s += uvpd[(4 + arr) * 131072 + off];
    s += uvpd[(6 + arr) * 131072 + off];
    double bias = (arr == 1) ? (double)vecf[col] : 0.0;
    uvf[idx] = (float)(s + bias);
  } else {
    int a = arr - 2;
    float s = uvpf[a * 131072 + off];
    s += uvpf[(2 + a) * 131072 + off];
    s += uvpf[(4 + a) * 131072 + off];
    s += uvpf[(6 + a) * 131072 + off];
    float bias = (arr == 3) ? vecf[2064 + col] : 0.f;
    uvf[idx] = s + bias;
  }
}

// ---------------- f64 row sums / sums-of-squares ------------------------------------
__global__ __launch_bounds__(64) void k_stats64(const float* uvf, double* sums, double* sumsq) {
  int bid = blockIdx.x;           // arr*256 + row
  int lane = threadIdx.x;
  const float* p = uvf + bid * 512;
  double s = 0.0, s2 = 0.0;
  for (int q = lane; q < 512; q += 64) { double v = p[q]; s += v; s2 += v * v; }
#pragma unroll
  for (int m = 1; m < 64; m <<= 1) { s += __shfl_xor(s, m, 64); s2 += __shfl_xor(s2, m, 64); }
  if (lane == 0) { sums[bid] = s; sumsq[bid] = s2; }
}

// ---------------- cross[i][j] = U_i . V_j (f64): z=0 -> ep, z=1 -> ef ---------------
__global__ __launch_bounds__(256) void k_cross(const float* uvf, double* crossep,
                                               double* crossef) {
  __shared__ float Uc[16][132], Vc[16][132];
  int z = blockIdx.z;
  const float* U = uvf + z * 262144;
  const float* V = U + 131072;
  double* out = z ? crossef : crossep;
  int tid = threadIdx.x, ti = tid & 15, tj = tid >> 4;
  int i0 = blockIdx.y * 16, j0 = blockIdx.x * 16;
  double acc = 0.0;
  for (int c0 = 0; c0 < 512; c0 += 128) {
    __syncthreads();
    for (int idx = tid; idx < 2048; idx += 256) {
      int r = idx >> 7, c = idx & 127;
      Uc[r][c] = U[(i0 + r) * 512 + c0 + c];
      Vc[r][c] = V[(j0 + r) * 512 + c0 + c];
    }
    __syncthreads();
#pragma unroll
    for (int c4 = 0; c4 < 128; c4 += 4) {
      float4 uu = *(const float4*)&Uc[ti][c4];
      float4 vv = *(const float4*)&Vc[tj][c4];
      float p = fmaf(uu.x, vv.x, fmaf(uu.y, vv.y, fmaf(uu.z, vv.z, uu.w * vv.w)));
      acc += (double)p;
    }
  }
  out[(i0 + ti) * 256 + j0 + tj] = acc;
}

// ---------------- edge predictor, stats-based tiled (1 thread / pair) ---------------
__global__ __launch_bounds__(256) void k_ep_t(const float* uvf, const double* sums,
    const double* sumsq, const double* crossep, const float* vecf,
    float* act, float* maskv) {
  __shared__ float Uc[16][132], Vc[16][132];
  int tid = threadIdx.x, ti = tid & 15, tj = tid >> 4;
  int i0 = blockIdx.y * 16, j0 = blockIdx.x * 16;
  int i = i0 + ti, j = j0 + tj;
  double md = (sums[i] + sums[256 + j]) * (1.0 / 512.0);
  double qd = (sumsq[i] + 2.0 * crossep[i * 256 + j] + sumsq[256 + j]) * (1.0 / 512.0);
  float iv = (float)(1.0 / sqrt(qd - md * md + 1e-5));
  float bb = (float)(-md) * iv;
  const float* U = uvf;
  const float* V = uvf + 131072;
  const float* g_ = vecf + 512;
  const float* be_ = vecf + 1024;
  const float* w2_ = vecf + 1536;
  double acc = 0.0;
  for (int c0 = 0; c0 < 512; c0 += 128) {
    __syncthreads();
    for (int idx = tid; idx < 2048; idx += 256) {
      int r = idx >> 7, c = idx & 127;
      Uc[r][c] = U[(i0 + r) * 512 + c0 + c];
      Vc[r][c] = V[(j0 + r) * 512 + c0 + c];
    }
    __syncthreads();
#pragma unroll
    for (int c4 = 0; c4 < 128; c4 += 4) {
      float4 uu = *(const float4*)&Uc[ti][c4];
      float4 vv = *(const float4*)&Vc[tj][c4];
      float4 gg = *(const float4*)(g_ + c0 + c4);
      float4 b4 = *(const float4*)(be_ + c0 + c4);
      float4 w4 = *(const float4*)(w2_ + c0 + c4);
      float z, s4 = 0.f;
      z = fmaf(fmaf(uu.x + vv.x, iv, bb), gg.x, b4.x); s4 = fmaf(lrelu(z), w4.x, s4);
      z = fmaf(fmaf(uu.y + vv.y, iv, bb), gg.y, b4.y); s4 = fmaf(lrelu(z), w4.y, s4);
      z = fmaf(fmaf(uu.z + vv.z, iv, bb), gg.z, b4.z); s4 = fmaf(lrelu(z), w4.z, s4);
      z = fmaf(fmaf(uu.w + vv.w, iv, bb), gg.w, b4.w); s4 = fmaf(lrelu(z), w4.w, s4);
      acc += (double)s4;
    }
  }
  double logit = acc + (double)vecf[2048];
  bool a = (logit > 0.0) && (i != j);
  act[i * 256 + j] = a ? 1.0f : 0.0f;
  maskv[j * 256 + i] = (a || i == j) ? 0.f : -1e9f;         // adj[dst][src] mask
}

// ---------------- edge features: all-LDS inner loop + bf16 MFMA (r15, validated) ----
__global__ __launch_bounds__(512, 2) void k_ef(const float* uvf, const double* sums,
    const double* sumsq, const double* crossef, const float* vecf,
    const u16* w2fr, const float* vfrag, float* ef_f) {
  __shared__ u16 w2S[16384];                 // 32 KB: 4 kc x 8 nt x 512
  __shared__ float vS0[4096], vS1[4096];     // 16+16 KB
  __shared__ float uS[8192];                 // 32 KB: 16 rows x 512
  __shared__ float gS[512], beS[512];        // 4 KB
  int tid = threadIdx.x;
  int lane = tid & 63, w = tid >> 6;         // w 0..7
  int bx = blockIdx.x;
  int bi = bx >> 4, bj = bx & 15;
  int i0 = bi * 16;
  int iA = i0 + w * 2, iB = iA + 1;
  int l15 = lane & 15;
  int j = bj * 16 + l15;
  int ksl = (lane >> 4) * 8;

  double sj = sums[768 + j], s2j = sumsq[768 + j];
  double mA = (sums[512 + iA] + sj) * (1.0 / 512.0);
  double qA = (sumsq[512 + iA] + 2.0 * crossef[iA * 256 + j] + s2j) * (1.0 / 512.0);
  float ivA = (float)(1.0 / sqrt(qA - mA * mA + 1e-5));
  float bbA = (float)(-mA) * ivA;
  double mB = (sums[512 + iB] + sj) * (1.0 / 512.0);
  double qB = (sumsq[512 + iB] + 2.0 * crossef[iB * 256 + j] + s2j) * (1.0 / 512.0);
  float ivB = (float)(1.0 / sqrt(qB - mB * mB + 1e-5));
  float bbB = (float)(-mB) * ivB;

  const float* Vg = vfrag + bj * 8192;
  for (int q = tid; q < 2048; q += 512) {
    float4 v = *(const float4*)(Vg + q * 4);
    int kc = q >> 7, r = q & 127, ln = r >> 1;
    if (r & 1) *(float4*)(vS1 + kc * 256 + ln * 4) = v;
    else       *(float4*)(vS0 + kc * 256 + ln * 4) = v;
  }
  const float* Ug = uvf + 262144 + i0 * 512;
  for (int q = tid; q < 2048; q += 512)
    *(float4*)(uS + q * 4) = *(const float4*)(Ug + q * 4);
  if (tid < 128)      *(float4*)(gS + tid * 4)  = *(const float4*)(vecf + 2576 + tid * 4);
  else if (tid < 256) *(float4*)(beS + (tid - 128) * 4) = *(const float4*)(vecf + 3088 + (tid - 128) * 4);

  f32x4 acc[2][8];
#pragma unroll
  for (int ai = 0; ai < 2; ++ai)
#pragma unroll
    for (int bq = 0; bq < 8; ++bq) acc[ai][bq] = (f32x4){0.f, 0.f, 0.f, 0.f};

  auto H8 = [&](float4 u0, float4 u1, float4 v0, float4 v1, float4 g0, float4 g1,
                float4 e0, float4 e1, float iv, float bb) -> short8 {
    short8 a; float z;
    z = fmaf(u0.x + v0.x, iv, bb); z = fmaf(z, g0.x, e0.x); a[0] = (short)f2bf(lrelu(z));
    z = fmaf(u0.y + v0.y, iv, bb); z = fmaf(z, g0.y, e0.y); a[1] = (short)f2bf(lrelu(z));
    z = fmaf(u0.z + v0.z, iv, bb); z = fmaf(z, g0.z, e0.z); a[2] = (short)f2bf(lrelu(z));
    z = fmaf(u0.w + v0.w, iv, bb); z = fmaf(z, g0.w, e0.w); a[3] = (short)f2bf(lrelu(z));
    z = fmaf(u1.x + v1.x, iv, bb); z = fmaf(z, g1.x, e1.x); a[4] = (short)f2bf(lrelu(z));
    z = fmaf(u1.y + v1.y, iv, bb); z = fmaf(z, g1.y, e1.y); a[5] = (short)f2bf(lrelu(z));
    z = fmaf(u1.z + v1.z, iv, bb); z = fmaf(z, g1.z, e1.z); a[6] = (short)f2bf(lrelu(z));
    z = fmaf(u1.w + v1.w, iv, bb); z = fmaf(z, g1.w, e1.w); a[7] = (short)f2bf(lrelu(z));
    return a;
  };

  const float* uA = uS + (w * 2) * 512;
  const float* uB = uA + 512;

  for (int kq = 0; kq < 4; ++kq) {
    __syncthreads();
    const short8* src = (const short8*)(w2fr + kq * 16384);
    for (int q = tid; q < 2048; q += 512)
      *(short8*)(w2S + q * 8) = src[q];
    __syncthreads();
#pragma unroll
    for (int kk = 0; kk < 4; ++kk) {
      int kc = kq * 4 + kk;
      int k0 = kc * 32 + ksl;
      float4 u0 = *(const float4*)(uA + k0);
      float4 u1 = *(const float4*)(uA + k0 + 4);
      float4 b0 = *(const float4*)(uB + k0);
      float4 b1 = *(const float4*)(uB + k0 + 4);
      float4 v0 = *(const float4*)(vS0 + kc * 256 + lane * 4);
      float4 v1 = *(const float4*)(vS1 + kc * 256 + lane * 4);
      float4 g0 = *(const float4*)(gS + k0);
      float4 g1 = *(const float4*)(gS + k0 + 4);
      float4 e0 = *(const float4*)(beS + k0);
      float4 e1 = *(const float4*)(beS + k0 + 4);
      short8 aA = H8(u0, u1, v0, v1, g0, g1, e0, e1, ivA, bbA);
      short8 aB = H8(b0, b1, v0, v1, g0, g1, e0, e1, ivB, bbB);
#pragma unroll
      for (int nt = 0; nt < 8; ++nt) {
        short8 bv = *(const short8*)(w2S + kk * 4096 + nt * 512 + lane * 8);
        acc[0][nt] = __builtin_amdgcn_mfma_f32_16x16x32_bf16(aA, bv, acc[0][nt], 0, 0, 0);
        acc[1][nt] = __builtin_amdgcn_mfma_f32_16x16x32_bf16(aB, bv, acc[1][nt], 0, 0, 0);
      }
    }
  }
#pragma unroll
  for (int mi = 0; mi < 2; ++mi) {
    int ii = mi ? iB : iA;
#pragma unroll
    for (int nt = 0; nt < 8; ++nt) {
      int n = nt * 16 + l15;
      float bias = vecf[3600 + n];
#pragma unroll
      for (int r = 0; r < 4; ++r) {
        int row = (lane >> 4) * 4 + r;
        ef_f[(ii * 256 + bj * 16 + row) * 128 + n] = acc[mi][nt][r] + bias;
      }
    }
  }
}

// ---------------- naive a_src/a_dst dots (block per (n,h)) --------------------------
__global__ __launch_bounds__(64) void k_ad(const float* sf, const float* vecf, int l,
                                           float* asf, float* adf) {
  int b = blockIdx.x;            // n*4+h
  int n = b >> 2, h = b & 3;
  int lane = threadIdx.x;
  const float* s = sf + n * 2048 + h * 512;
  const float* as_ = vecf + 3728 + l * 2048 + h * 512;
  const float* ad_ = vecf + 9872 + l * 2048 + h * 512;
  float sa = 0.f, sd = 0.f;
  for (int c = lane; c < 512; c += 64) { sa = fmaf(s[c], as_[c], sa); sd = fmaf(s[c], ad_[c], sd); }
#pragma unroll
  for (int m = 1; m < 64; m <<= 1) { sa += __shfl_xor(sa, m, 64); sd += __shfl_xor(sd, m, 64); }
  if (lane == 0) { asf[b] = sa; adf[b] = sd; }
}

// ---------------- GAT attention softmax -> alpha bf16 hi/lo [dst][h*256+src] --------
__global__ __launch_bounds__(256) void k_alpha(const float* asf, const float* adf,
    const float* maskv, u16* a_hib, u16* a_lob) {
  int dd = blockIdx.x, s = threadIdx.x;
  int lane = s & 63, w = s >> 6;
  __shared__ float wr[2][4][4];
  float mk = maskv[dd * 256 + s];
  float lg[4];
#pragma unroll
  for (int h = 0; h < 4; ++h) {
    float v = adf[dd * 4 + h] + asf[s * 4 + h];
    lg[h] = lrelu(v) + mk;
  }
#pragma unroll
  for (int h = 0; h < 4; ++h) {
    float v = lg[h];
#pragma unroll
    for (int m = 1; m < 64; m <<= 1) v = fmaxf(v, __shfl_xor(v, m, 64));
    if (lane == 0) wr[0][h][w] = v;
  }
  __syncthreads();
  float e[4];
#pragma unroll
  for (int h = 0; h < 4; ++h) {
    float mx = fmaxf(fmaxf(wr[0][h][0], wr[0][h][1]), fmaxf(wr[0][h][2], wr[0][h][3]));
    float v = __expf(lg[h] - mx);
    e[h] = v;
#pragma unroll
    for (int m = 1; m < 64; m <<= 1) v += __shfl_xor(v, m, 64);
    if (lane == 0) wr[1][h][w] = v;
  }
  __syncthreads();
#pragma unroll
  for (int h = 0; h < 4; ++h) {
    float sm = wr[1][h][0] + wr[1][h][1] + wr[1][h][2] + wr[1][h][3];
    float v = e[h] / sm;
    u16 hi = f2bf(v);
    int o = dd * 1024 + h * 256 + s;
    a_hib[o] = hi;
    a_lob[o] = f2bf(v - bf2f(hi));    // v-hi exact in f32
  }
}

// ---------------- s transpose -> sT bf16 hi/lo: sT[c][h*256+n] = s[n][h*512+c] ------
__global__ __launch_bounds__(256) void k_st(const float* sf, u16* sT_hi, u16* sT_lo) {
  __shared__ float T[64][65];
  int tid = threadIdx.x;
  int hc0 = blockIdx.x * 64;
  int n0 = blockIdx.y * 64;
  int h = hc0 >> 9, c0 = hc0 & 511, q0 = h * 256 + n0;
  int cl = tid & 63, rw = tid >> 6;
#pragma unroll
  for (int rr = 0; rr < 16; ++rr) {
    int r = rr * 4 + rw;
    T[r][cl] = sf[(n0 + r) * 2048 + hc0 + cl];
  }
  __syncthreads();
#pragma unroll
  for (int rr = 0; rr < 16; ++rr) {
    int r = rr * 4 + rw;              // c-offset within tile
    float v = T[cl][r];               // stride-65 read: conflict-free
    u16 hi = f2bf(v);
    int o = (c0 + r) * 1024 + q0 + cl;
    sT_hi[o] = hi;
    sT_lo[o] = f2bf(v - bf2f(hi));
  }
}

// ---------------- aggregation as MFMA GEMM: x[i][c] = lrelu(0.25*A.B + b) -----------
__global__ __launch_bounds__(256) void k_aggm(const u16* a_hi, const u16* a_lo,
    const u16* sT_hi, const u16* sT_lo, const float* vecf, int l, float* xout) {
  int tid = threadIdx.x, lane = tid & 63, w = tid >> 6;
  int c0 = blockIdx.x * 32 + (w & 1) * 16;     // grid.x = 16
  int i0 = blockIdx.y * 32 + (w >> 1) * 16;    // grid.y = 8
  int kb = (lane >> 4) * 8;
  int ar = (i0 + (lane & 15)) * 1024 + kb;
  int br = (c0 + (lane & 15)) * 1024 + kb;
  f32x4 acc = (f32x4){0.f, 0.f, 0.f, 0.f};
#pragma unroll 4
  for (int k0 = 0; k0 < 1024; k0 += 32) {
    short8 ah = *(const short8*)(a_hi + ar + k0);
    short8 al = *(const short8*)(a_lo + ar + k0);
    short8 bh = *(const short8*)(sT_hi + br + k0);
    short8 bl = *(const short8*)(sT_lo + br + k0);
    acc = __builtin_amdgcn_mfma_f32_16x16x32_bf16(ah, bh, acc, 0, 0, 0);
    acc = __builtin_amdgcn_mfma_f32_16x16x32_bf16(ah, bl, acc, 0, 0, 0);
    acc = __builtin_amdgcn_mfma_f32_16x16x32_bf16(al, bh, acc, 0, 0, 0);
  }
  int c = c0 + (lane & 15);
  float b = vecf[16016 + l * 512 + c];
#pragma unroll
  for (int r = 0; r < 4; ++r) {
    int i = i0 + (lane >> 4) * 4 + r;
    xout[i * 512 + c] = lrelu(fmaf(acc[r], 0.25f, b));
  }
}

// ---------------- linear: out[i][c] = x[i].W[:,c] + bias; 2 rows/thread -------------
__global__ __launch_bounds__(256) void k_op(const float* x, const float* Wf,
    const float* bias, float* out) {
  int tid = threadIdx.x;
  int c = blockIdx.x * 256 + tid;            // grid.x = 2
  int i0 = blockIdx.y * 2;                   // grid.y = 128
  const float* xr = x + i0 * 512;
  float a0 = 0.f, a1 = 0.f;
  for (int k = 0; k < 512; k += 2) {
    float w0 = Wf[k * 512 + c], w1 = Wf[(k + 1) * 512 + c];
    float2 x0 = *(const float2*)(xr + k);
    float2 x1 = *(const float2*)(xr + 512 + k);
    a0 = fmaf(x0.x, w0, fmaf(x0.y, w1, a0));
    a1 = fmaf(x1.x, w0, fmaf(x1.y, w1, a1));
  }
  out[(i0 + 0) * 512 + c] = a0 + bias[c];
  out[(i0 + 1) * 512 + c] = a1 + bias[c];
}

// ---------------- output-proj LayerNorm + leaky -> f32 ------------------------------
__global__ __launch_bounds__(256) void k_ln(const float* t1, const float* vecf, float* h1f) {
  const float* g_ = vecf + 18064;
  const float* be_ = vecf + 18576;
  int row = blockIdx.x, tid = threadIdx.x, lane = tid & 63, w = tid >> 6;
  __shared__ float wr[2][4];
  float v0 = t1[row * 512 + tid];
  float v1 = t1[row * 512 + 256 + tid];
  float s = v0 + v1, s2 = fmaf(v0, v0, v1 * v1);
#pragma unroll
  for (int m = 1; m < 64; m <<= 1) { s += __shfl_xor(s, m, 64); s2 += __shfl_xor(s2, m, 64); }
  if (lane == 0) { wr[0][w] = s; wr[1][w] = s2; }
  __syncthreads();
  s = wr[0][0] + wr[0][1] + wr[0][2] + wr[0][3];
  s2 = wr[1][0] + wr[1][1] + wr[1][2] + wr[1][3];
  float m = s * (1.f / 512.f);
  float var = fmaxf(s2 * (1.f / 512.f) - m * m, 0.f);
  float iv = 1.f / sqrtf(var + 1e-5f);
  float z0 = (v0 - m) * iv * g_[tid] + be_[tid];
  float z1 = (v1 - m) * iv * g_[tid + 256] + be_[tid + 256];
  h1f[row * 512 + tid] = lrelu(z0);
  h1f[row * 512 + 256 + tid] = lrelu(z1);
}

// ---------------- final linear -> f32 out; 2 rows/thread ----------------------------
__global__ __launch_bounds__(256) void k_op2(const float* x, const float* Wf,
    const float* vecf, float* outf) {
  int tid = threadIdx.x;
  int c = blockIdx.x * 256 + tid;            // grid.x = 2
  int i0 = blockIdx.y * 2;                   // grid.y = 128
  const float* xr = x + i0 * 512;
  float a0 = 0.f, a1 = 0.f;
  for (int k = 0; k < 512; k += 2) {
    float w0 = Wf[k * 512 + c], w1 = Wf[(k + 1) * 512 + c];
    float2 x0 = *(const float2*)(xr + k);
    float2 x1 = *(const float2*)(xr + 512 + k);
    a0 = fmaf(x0.x, w0, fmaf(x0.y, w1, a0));
    a1 = fmaf(x1.x, w0, fmaf(x1.y, w1, a1));
  }
  outf[(i0 + 0) * 512 + c] = a0 + vecf[19088 + c];
  outf[(i0 + 1) * 512 + c] = a1 + vecf[19088 + c];
}

extern "C" void kernel_launch(void* const* d_in, const int* in_sizes, int n_in,
                              void* d_out, int out_size, void* d_ws, size_t ws_size,
                              hipStream_t stream) {
  (void)out_size;
  static const int dictT[23] = {0,1,2,3,4,5,6,7,8,9,10,11,12,13,14,15,16,17,18,19,20,21,22};
  static const int alphaT[23] = {6,11,7,10,9,12,8,4,0,3,2,5,1,13,15,14,16,21,17,20,19,22,18};
  const int* tbl = (n_in == 23 && in_sizes[0] == 512) ? alphaT : dictT;
  auto IN = [&](int role) -> const void* { return d_in[tbl[role]]; };

  float* out_f = (float*)d_out;                    // [256,512] f32
  float* act_f = out_f + 256 * 512;                // [256,256] f32 0/1
  float* ef_f  = out_f + 256 * 512 + 256 * 256;    // [256,256,128] f32

  char* cur = (char*)d_ws;
  auto alloc = [&](size_t bytes) -> void* {
    void* r = (void*)cur;
    cur += (bytes + 255) & ~(size_t)255;
    return r;
  };
  float* vecf    = (float*)alloc(20480 * 4);
  float* embf    = (float*)alloc(131072 * 4);
  float* epw1f   = (float*)alloc(524288 * 4);
  float* efw1f   = (float*)alloc(524288 * 4);
  float* gatWf   = (float*)alloc(3145728 * 4);
  float* opw1f   = (float*)alloc(262144 * 4);
  float* opw2f   = (float*)alloc(262144 * 4);
  float* efw2f   = (float*)alloc(65536 * 4);
  float* uvf     = (float*)alloc(524288 * 4);
  float* sf      = (float*)alloc(524288 * 4);
  float* asf     = (float*)alloc(1024 * 4);
  float* adf     = (float*)alloc(1024 * 4);
  float* xf      = (float*)alloc(262144 * 4);
  float* t1      = (float*)alloc(131072 * 4);
  float* h1f     = (float*)alloc(131072 * 4);
  float* maskv   = (float*)alloc(65536 * 4);
  double* sums   = (double*)alloc(1024 * 8);
  double* sumsq  = (double*)alloc(1024 * 8);
  double* crossep = (double*)alloc(65536 * 8);
  double* crossef = (double*)alloc(65536 * 8);
  u16* w2tb      = (u16*)alloc(65536 * 2);
  float* vfrag   = (float*)alloc(131072 * 4);
  u16* wfrb      = (u16*)alloc(2097152 * 2);   // per-layer W frag-linear hi/lo (4MB)
  u16* xfrb      = (u16*)alloc(262144 * 2);    // per-layer x frag-linear hi/lo (512KB)
  double* uvpd   = (double*)alloc(1048576 * 8); // split-K f64 partials (ep) 8MB
  float* uvpf    = (float*)alloc(1048576 * 4);  // split-K f32 partials (ef) 4MB
  int* flag      = (int*)alloc(256);
  if ((size_t)(cur - (char*)d_ws) > ws_size) return;

  // GAT-phase buffers aliased onto epw1f/efw1f (both dead after k_uv_sk):
  u16* sT_hi = (u16*)epw1f;            // 512*1024 u16 = 1 MB
  u16* sT_lo = sT_hi + 524288;         // second 1 MB of epw1f's 2 MB
  u16* a_hib = (u16*)efw1f;            // 256*1024 u16 = 512 KB
  u16* a_lob = a_hib + 262144;         // next 512 KB of efw1f's 2 MB

  hipMemsetAsync(flag, 0, 256, stream);
  hipLaunchKernelGGL(k_detect, dim3(64), dim3(256), 0, stream, (const u16*)IN(0), flag);

  { // small vectors -> canonical f32
    VArgs va;
    auto setV = [&](int qi, int role, int dst, int n) { va.v[qi] = {IN(role), dst, n}; };
    setV(0, 2, 0, 512);       // ep_b1
    setV(1, 3, 512, 512);     // ep_g
    setV(2, 4, 1024, 512);    // ep_beta
    setV(3, 5, 1536, 512);    // ep_w2
    setV(4, 6, 2048, 1);      // ep_b2
    setV(5, 8, 2064, 512);    // ef_b1
    setV(6, 9, 2576, 512);    // ef_g
    setV(7, 10, 3088, 512);   // ef_beta
    setV(8, 12, 3600, 128);   // ef_b2
    setV(9, 14, 3728, 6144);  // gat_a_src
    setV(10, 15, 9872, 6144); // gat_a_dst
    setV(11, 16, 16016, 1536);// gat_b
    setV(12, 18, 17552, 512); // op_b1
    setV(13, 19, 18064, 512); // op_g
    setV(14, 20, 18576, 512); // op_beta
    setV(15, 22, 19088, 512); // op_b2
    hipLaunchKernelGGL(k_vec, dim3(16), dim3(256), 0, stream, va, (const int*)flag, vecf);
  }

  { // big matrices -> canonical f32
    CArgs ca;
    ca.src[0] = IN(0);  ca.dst[0] = embf;  ca.n[0] = 131072;
    ca.src[1] = IN(1);  ca.dst[1] = epw1f; ca.n[1] = 524288;
    ca.src[2] = IN(7);  ca.dst[2] = efw1f; ca.n[2] = 524288;
    ca.src[3] = IN(13); ca.dst[3] = gatWf; ca.n[3] = 3145728;
    ca.src[4] = IN(17); ca.dst[4] = opw1f; ca.n[4] = 262144;
    ca.src[5] = IN(21); ca.dst[5] = opw2f; ca.n[5] = 262144;
    ca.src[6] = IN(11); ca.dst[6] = efw2f; ca.n[6] = 65536;
    hipLaunchKernelGGL(k_cvt, dim3(2048, 7), dim3(256), 0, stream, ca, (const int*)flag);
  }
  hipLaunchKernelGGL(k_w2tb, dim3(256), dim3(256), 0, stream, efw2f, w2tb);

  hipLaunchKernelGGL(k_uv_sk, dim3(2, 64, 16), dim3(256), 0, stream,
                     embf, epw1f, efw1f, uvpd, uvpf);
  hipLaunchKernelGGL(k_uvr, dim3(2048), dim3(256), 0, stream, uvpd, uvpf, vecf, uvf);
  hipLaunchKernelGGL(k_vfr, dim3(512), dim3(256), 0, stream, uvf, vfrag);
  hipLaunchKernelGGL(k_stats64, dim3(1024), dim3(64), 0, stream, uvf, sums, sumsq);
  hipLaunchKernelGGL(k_cross, dim3(16, 16, 2), dim3(256), 0, stream, uvf, crossep, crossef);

  hipLaunchKernelGGL(k_ep_t, dim3(16, 16), dim3(256), 0, stream,
                     uvf, sums, sumsq, crossep, vecf, act_f, maskv);
  hipLaunchKernelGGL(k_ef, dim3(256), dim3(512), 0, stream,
                     uvf, sums, sumsq, crossef, vecf, w2tb, vfrag, ef_f);

  const float* xsrc = embf;
  for (int l = 0; l < 3; ++l) {
    hipLaunchKernelGGL(k_wfr, dim3(512), dim3(256), 0, stream,
                       gatWf + l * 1048576, wfrb);
    hipLaunchKernelGGL(k_xb, dim3(64), dim3(256), 0, stream, xsrc, xfrb);
    hipLaunchKernelGGL(k_sm, dim3(64, 8), dim3(256), 0, stream, xfrb, wfrb, sf);
    hipLaunchKernelGGL(k_ad, dim3(1024), dim3(64), 0, stream, sf, vecf, l, asf, adf);
    hipLaunchKernelGGL(k_alpha, dim3(256), dim3(256), 0, stream, asf, adf, maskv,
                       a_hib, a_lob);
    hipLaunchKernelGGL(k_st, dim3(32, 4), dim3(256), 0, stream, sf, sT_hi, sT_lo);
    float* xdst = xf + (l & 1) * 131072;
    hipLaunchKernelGGL(k_aggm, dim3(16, 8), dim3(256), 0, stream,
                       a_hib, a_lob, sT_hi, sT_lo, vecf, l, xdst);
    xsrc = xdst;
  }

  hipLaunchKernelGGL(k_op, dim3(2, 128), dim3(256), 0, stream, xsrc, opw1f, vecf + 17552, t1);
  hipLaunchKernelGGL(k_ln, dim3(256), dim3(256), 0, stream, t1, vecf, h1f);
  hipLaunchKernelGGL(k_op2, dim3(2, 128), dim3(256), 0, stream, h1f, opw2f, vecf, out_f);
}

// Round 12
// 425.713 us; speedup vs baseline: 1.0052x; 1.0052x over previous
//
#include <hip/hip_runtime.h>

// NeuralAudioGraph: N=256, D=H=512, E=128, 4 heads, 3 GAT layers.
// r19: k_uv split by precision. r18 post-mortem: split-K raised occupancy
// 5x yet k_uv got SLOWER (44->52us) -- no model predicted it; but every
// MFMA+frag-linear kernel shipped (k_ef/k_aggm/k_sm) runs fast. So: ep half
// (f64, guards the logit>0 act threshold) reverts to r17's validated
// streaming k_uv at grid (2,64,2) -- bit-identical act, ~half the time;
// ef half (f32-tolerant) becomes k_uvef, a k_sm-clone MFMA hi/lo GEMM
// (256x1024 @ K=512) fed by k_xb(embf) + new k_wfr_ef(efw1). uvf_ef moves
// ~2^-16 rel; stats/cross/h are computed FROM uvf (self-consistent) and bf16
// h-rounding dominates absmax. Split-K kernels + 12MB partials dropped.
// Baseline r17: 410us (r18: 428), absmax 0.0078125.

typedef __attribute__((ext_vector_type(8))) short short8;   // 8 x bf16 (MFMA frag)
typedef __attribute__((ext_vector_type(4))) float f32x4;    // MFMA accumulator
typedef unsigned short u16;
typedef unsigned int u32;

__device__ __forceinline__ float bf2f(u16 h) { return __uint_as_float(((u32)h) << 16); }
__device__ __forceinline__ u16 f2bf(float f) {
  u32 u = __float_as_uint(f);
  u += 0x7fffu + ((u >> 16) & 1u);   // round-to-nearest-even
  return (u16)(u >> 16);
}
__device__ __forceinline__ float lrelu(float v) { return fmaxf(v, 0.2f * v); }
__device__ __forceinline__ float ldany(int f32mode, const void* p, int i) {
  return f32mode ? ((const float*)p)[i] : bf2f(((const u16*)p)[i]);
}

// ---------------- dtype detector ----------------------------------------------------
__global__ __launch_bounds__(256) void k_detect(const u16* emb, int* flag) {
  bool big = false;
  for (int i = blockIdx.x * 256 + threadIdx.x; i < 131072; i += 256 * 64) {
    float v = bf2f(emb[i]);
    big |= !(fabsf(v) <= 1e6f);
  }
  unsigned long long m = __ballot(big);
  if (m && (threadIdx.x & 63) == 0) atomicOr(flag, 1);
}

// ---------------- small-vector ingest -> canonical f32 ------------------------------
struct VD { const void* src; int dst, n; };
struct VArgs { VD v[16]; };
__global__ __launch_bounds__(256) void k_vec(VArgs a, const int* flag, float* out) {
  int f = *flag;
  VD d = a.v[blockIdx.x];
  for (int i = threadIdx.x; i < d.n; i += 256)
    out[d.dst + i] = ldany(f, d.src, i);
}

// ---------------- big-matrix ingest -> canonical f32 --------------------------------
struct CArgs { const void* src[7]; float* dst[7]; int n[7]; };
__global__ __launch_bounds__(256) void k_cvt(CArgs a, const int* flag) {
  int f = *flag;
  int e = blockIdx.y;
  const void* s = a.src[e];
  float* d = a.dst[e];
  int n = a.n[e];
  for (int i = blockIdx.x * 256 + threadIdx.x; i < n; i += 2048 * 256)
    d[i] = ldany(f, s, i);
}

// ---------------- ef_w2 f32 [512][128] -> bf16 MFMA-fragment-linear -----------------
// w2fr[(kc*8+nt)*512 + l*8 + e] = bf16(w2[c = kc*32+(l>>4)*8+e][n = nt*16+(l&15)])
__global__ __launch_bounds__(256) void k_w2tb(const float* efw2f, u16* w2fr) {
  int idx = blockIdx.x * 256 + threadIdx.x;   // 65536
  int e = idx & 7, l = (idx >> 3) & 63, nt = (idx >> 9) & 7, kc = idx >> 12;
  int n = nt * 16 + (l & 15);
  int c = kc * 32 + ((l >> 4) << 3) + e;
  w2fr[idx] = f2bf(efw2f[c * 128 + n]);
}

// ---------------- V rows -> f32 MFMA-fragment-linear --------------------------------
// vfrag[jb*8192 + kc*512 + l*8 + e] = V[jb*16+(l&15)][kc*32+(l>>4)*8+e]
__global__ __launch_bounds__(256) void k_vfr(const float* uvf, float* vfrag) {
  const float* V = uvf + 393216;
  int idx = blockIdx.x * 256 + threadIdx.x;   // grid 512 -> 131072
  int e = idx & 7, l = (idx >> 3) & 63, kc = (idx >> 9) & 15, jb = idx >> 13;
  int j = jb * 16 + (l & 15);
  int c = kc * 32 + ((l >> 4) << 3) + e;
  vfrag[idx] = V[j * 512 + c];
}

// ---------------- GAT W[l] -> fragment-linear interleaved bf16 hi/lo ----------------
__global__ __launch_bounds__(256) void k_wfr(const float* Wf, u16* wfr) {
  int idx = blockIdx.x * 256 + threadIdx.x;   // 131072
  int lane = idx & 63, kc = (idx >> 6) & 15, nt = idx >> 10;
  int n = nt * 16 + (lane & 15);
  int c0 = kc * 32 + ((lane >> 4) << 3);
  u16* dst = wfr + idx * 16;
#pragma unroll
  for (int e = 0; e < 8; ++e) {
    float v = Wf[(c0 + e) * 2048 + n];
    u16 hi = f2bf(v);
    dst[e] = hi;
    dst[8 + e] = f2bf(v - bf2f(hi));
  }
}

// ---------------- ef W1 ([512][512] x2 halves) -> frag-linear hi/lo, N=1024 ---------
__global__ __launch_bounds__(256) void k_wfr_ef(const float* efw1f, u16* wfr) {
  int idx = blockIdx.x * 256 + threadIdx.x;   // 65536
  int lane = idx & 63, kc = (idx >> 6) & 15, nt = idx >> 10;   // nt in [0,64)
  int n = nt * 16 + (lane & 15);              // [0,1024)
  int c0 = kc * 32 + ((lane >> 4) << 3);
  const float* base = (n < 512) ? (efw1f + n) : (efw1f + 262144 + n - 512);
  u16* dst = wfr + idx * 16;
#pragma unroll
  for (int e = 0; e < 8; ++e) {
    float v = base[(c0 + e) * 512];
    u16 hi = f2bf(v);
    dst[e] = hi;
    dst[8 + e] = f2bf(v - bf2f(hi));
  }
}

// ---------------- x -> fragment-linear interleaved bf16 hi/lo -----------------------
__global__ __launch_bounds__(256) void k_xb(const float* x, u16* xfr) {
  int idx = blockIdx.x * 256 + threadIdx.x;   // 16384
  int lane = idx & 63, kc = (idx >> 6) & 15, it = idx >> 10;
  int i = it * 16 + (lane & 15);
  int c0 = kc * 32 + ((lane >> 4) << 3);
  const float* src = x + i * 512 + c0;
  float4 v0 = *(const float4*)(src);
  float4 v1 = *(const float4*)(src + 4);
  float vv[8] = {v0.x, v0.y, v0.z, v0.w, v1.x, v1.y, v1.z, v1.w};
  u16* dst = xfr + idx * 16;
#pragma unroll
  for (int e = 0; e < 8; ++e) {
    u16 hi = f2bf(vv[e]);
    dst[e] = hi;
    dst[8 + e] = f2bf(vv[e] - bf2f(hi));
  }
}

// ---------------- GAT s = x @ W[l] as MFMA (hi/lo 3-product) ------------------------
__global__ __launch_bounds__(256) void k_sm(const u16* xfr, const u16* wfr, float* sf) {
  int tid = threadIdx.x, lane = tid & 63, w = tid >> 6;
  int n0 = blockIdx.x * 32 + (w & 1) * 16;     // grid.x = 64
  int i0 = blockIdx.y * 32 + (w >> 1) * 16;    // grid.y = 8
  int it = i0 >> 4, nt = n0 >> 4;
  const u16* ap = xfr + (it * 16) * 1024 + lane * 16;
  const u16* bp = wfr + (nt * 16) * 1024 + lane * 16;
  f32x4 acc = (f32x4){0.f, 0.f, 0.f, 0.f};
#pragma unroll
  for (int kc = 0; kc < 16; ++kc) {
    short8 ah = *(const short8*)(ap + kc * 1024);
    short8 al = *(const short8*)(ap + kc * 1024 + 8);
    short8 bh = *(const short8*)(bp + kc * 1024);
    short8 bl = *(const short8*)(bp + kc * 1024 + 8);
    acc = __builtin_amdgcn_mfma_f32_16x16x32_bf16(ah, bh, acc, 0, 0, 0);
    acc = __builtin_amdgcn_mfma_f32_16x16x32_bf16(ah, bl, acc, 0, 0, 0);
    acc = __builtin_amdgcn_mfma_f32_16x16x32_bf16(al, bh, acc, 0, 0, 0);
  }
  int col = n0 + (lane & 15);
#pragma unroll
  for (int r = 0; r < 4; ++r) {
    int row = i0 + (lane >> 4) * 4 + r;
    sf[row * 2048 + col] = acc[r];
  }
}

// ---------------- U/V_ef = emb @ efW1 as MFMA (hi/lo 3-product) ---------------------
// grid (32, 8), 256 thr = 4 waves; cols n in [0,1024): n<512 -> U_ef (no bias),
// n>=512 -> V_ef (+ ef_b1). Same fragment scheme as validated k_sm.
__global__ __launch_bounds__(256) void k_uvef(const u16* xfr, const u16* wfr,
    const float* vecf, float* uvf) {
  int tid = threadIdx.x, lane = tid & 63, w = tid >> 6;
  int n0 = blockIdx.x * 32 + (w & 1) * 16;     // grid.x = 32
  int i0 = blockIdx.y * 32 + (w >> 1) * 16;    // grid.y = 8
  int it = i0 >> 4, nt = n0 >> 4;
  const u16* ap = xfr + (it * 16) * 1024 + lane * 16;
  const u16* bp = wfr + (nt * 16) * 1024 + lane * 16;
  f32x4 acc = (f32x4){0.f, 0.f, 0.f, 0.f};
#pragma unroll
  for (int kc = 0; kc < 16; ++kc) {
    short8 ah = *(const short8*)(ap + kc * 1024);
    short8 al = *(const short8*)(ap + kc * 1024 + 8);
    short8 bh = *(const short8*)(bp + kc * 1024);
    short8 bl = *(const short8*)(bp + kc * 1024 + 8);
    acc = __builtin_amdgcn_mfma_f32_16x16x32_bf16(ah, bh, acc, 0, 0, 0);
    acc = __builtin_amdgcn_mfma_f32_16x16x32_bf16(ah, bl, acc, 0, 0, 0);
    acc = __builtin_amdgcn_mfma_f32_16x16x32_bf16(al, bh, acc, 0, 0, 0);
  }
  int col = n0 + (lane & 15);
  float bias = (col >= 512) ? vecf[2064 + col - 512] : 0.f;
  float* outb = (col < 512) ? (uvf + 262144 + col) : (uvf + 393216 + col - 512);
#pragma unroll
  for (int r = 0; r < 4; ++r) {
    int row = i0 + (lane >> 4) * 4 + r;
    outb[row * 512] = acc[r] + bias;
  }
}

// ---------------- U/V_ep = emb @ epW1 halves, f64 (r17-validated, ep only) ----------
// grid (2, 64, 2): x = col half, y = 4-row group, z = arr (0,1). Bit-identical
// to r17's ep path -> act/maskv unchanged.
__global__ __launch_bounds__(256) void k_uv(const float* embf, const float* epw1f,
    const float* vecf, float* uvf) {
  int tid = threadIdx.x;
  int col = blockIdx.x * 256 + tid;
  int r0 = blockIdx.y * 4;
  int arr = blockIdx.z;
  const float* W = epw1f + arr * 262144 + col;
  const float* e = embf + r0 * 512;
  float bias = (arr == 1) ? vecf[col] : 0.f;
  float* outp = uvf + arr * 131072 + r0 * 512 + col;
  double a0 = 0.0, a1 = 0.0, a2 = 0.0, a3 = 0.0;
  for (int k = 0; k < 512; k += 2) {
    double w0 = (double)W[k * 512];
    double w1 = (double)W[(k + 1) * 512];
    float2 e0 = *(const float2*)(e + k);
    float2 e1 = *(const float2*)(e + 512 + k);
    float2 e2 = *(const float2*)(e + 1024 + k);
    float2 e3 = *(const float2*)(e + 1536 + k);
    a0 += (double)e0.x * w0 + (double)e0.y * w1;
    a1 += (double)e1.x * w0 + (double)e1.y * w1;
    a2 += (double)e2.x * w0 + (double)e2.y * w1;
    a3 += (double)e3.x * w0 + (double)e3.y * w1;
  }
  outp[0]    = (float)(a0 + (double)bias);
  outp[512]  = (float)(a1 + (double)bias);
  outp[1024] = (float)(a2 + (double)bias);
  outp[1536] = (float)(a3 + (double)bias);
}

// ---------------- f64 row sums / sums-of-squares ------------------------------------
__global__ __launch_bounds__(64) void k_stats64(const float* uvf, double* sums, double* sumsq) {
  int bid = blockIdx.x;           // arr*256 + row
  int lane = threadIdx.x;
  const float* p = uvf + bid * 512;
  double s = 0.0, s2 = 0.0;
  for (int q = lane; q < 512; q += 64) { double v = p[q]; s += v; s2 += v * v; }
#pragma unroll
  for (int m = 1; m < 64; m <<= 1) { s += __shfl_xor(s, m, 64); s2 += __shfl_xor(s2, m, 64); }
  if (lane == 0) { sums[bid] = s; sumsq[bid] = s2; }
}

// ---------------- cross[i][j] = U_i . V_j (f64): z=0 -> ep, z=1 -> ef ---------------
__global__ __launch_bounds__(256) void k_cross(const float* uvf, double* crossep,
                                               double* crossef) {
  __shared__ float Uc[16][132], Vc[16][132];
  int z = blockIdx.z;
  const float* U = uvf + z * 262144;
  const float* V = U + 131072;
  double* out = z ? crossef : crossep;
  int tid = threadIdx.x, ti = tid & 15, tj = tid >> 4;
  int i0 = blockIdx.y * 16, j0 = blockIdx.x * 16;
  double acc = 0.0;
  for (int c0 = 0; c0 < 512; c0 += 128) {
    __syncthreads();
    for (int idx = tid; idx < 2048; idx += 256) {
      int r = idx >> 7, c = idx & 127;
      Uc[r][c] = U[(i0 + r) * 512 + c0 + c];
      Vc[r][c] = V[(j0 + r) * 512 + c0 + c];
    }
    __syncthreads();
#pragma unroll
    for (int c4 = 0; c4 < 128; c4 += 4) {
      float4 uu = *(const float4*)&Uc[ti][c4];
      float4 vv = *(const float4*)&Vc[tj][c4];
      float p = fmaf(uu.x, vv.x, fmaf(uu.y, vv.y, fmaf(uu.z, vv.z, uu.w * vv.w)));
      acc += (double)p;
    }
  }
  out[(i0 + ti) * 256 + j0 + tj] = acc;
}

// ---------------- edge predictor, stats-based tiled (1 thread / pair) ---------------
__global__ __launch_bounds__(256) void k_ep_t(const float* uvf, const double* sums,
    const double* sumsq, const double* crossep, const float* vecf,
    float* act, float* maskv) {
  __shared__ float Uc[16][132], Vc[16][132];
  int tid = threadIdx.x, ti = tid & 15, tj = tid >> 4;
  int i0 = blockIdx.y * 16, j0 = blockIdx.x * 16;
  int i = i0 + ti, j = j0 + tj;
  double md = (sums[i] + sums[256 + j]) * (1.0 / 512.0);
  double qd = (sumsq[i] + 2.0 * crossep[i * 256 + j] + sumsq[256 + j]) * (1.0 / 512.0);
  float iv = (float)(1.0 / sqrt(qd - md * md + 1e-5));
  float bb = (float)(-md) * iv;
  const float* U = uvf;
  const float* V = uvf + 131072;
  const float* g_ = vecf + 512;
  const float* be_ = vecf + 1024;
  const float* w2_ = vecf + 1536;
  double acc = 0.0;
  for (int c0 = 0; c0 < 512; c0 += 128) {
    __syncthreads();
    for (int idx = tid; idx < 2048; idx += 256) {
      int r = idx >> 7, c = idx & 127;
      Uc[r][c] = U[(i0 + r) * 512 + c0 + c];
      Vc[r][c] = V[(j0 + r) * 512 + c0 + c];
    }
    __syncthreads();
#pragma unroll
    for (int c4 = 0; c4 < 128; c4 += 4) {
      float4 uu = *(const float4*)&Uc[ti][c4];
      float4 vv = *(const float4*)&Vc[tj][c4];
      float4 gg = *(const float4*)(g_ + c0 + c4);
      float4 b4 = *(const float4*)(be_ + c0 + c4);
      float4 w4 = *(const float4*)(w2_ + c0 + c4);
      float z, s4 = 0.f;
      z = fmaf(fmaf(uu.x + vv.x, iv, bb), gg.x, b4.x); s4 = fmaf(lrelu(z), w4.x, s4);
      z = fmaf(fmaf(uu.y + vv.y, iv, bb), gg.y, b4.y); s4 = fmaf(lrelu(z), w4.y, s4);
      z = fmaf(fmaf(uu.z + vv.z, iv, bb), gg.z, b4.z); s4 = fmaf(lrelu(z), w4.z, s4);
      z = fmaf(fmaf(uu.w + vv.w, iv, bb), gg.w, b4.w); s4 = fmaf(lrelu(z), w4.w, s4);
      acc += (double)s4;
    }
  }
  double logit = acc + (double)vecf[2048];
  bool a = (logit > 0.0) && (i != j);
  act[i * 256 + j] = a ? 1.0f : 0.0f;
  maskv[j * 256 + i] = (a || i == j) ? 0.f : -1e9f;         // adj[dst][src] mask
}

// ---------------- edge features: all-LDS inner loop + bf16 MFMA (r15, validated) ----
__global__ __launch_bounds__(512, 2) void k_ef(const float* uvf, const double* sums,
    const double* sumsq, const double* crossef, const float* vecf,
    const u16* w2fr, const float* vfrag, float* ef_f) {
  __shared__ u16 w2S[16384];                 // 32 KB: 4 kc x 8 nt x 512
  __shared__ float vS0[4096], vS1[4096];     // 16+16 KB
  __shared__ float uS[8192];                 // 32 KB: 16 rows x 512
  __shared__ float gS[512], beS[512];        // 4 KB
  int tid = threadIdx.x;
  int lane = tid & 63, w = tid >> 6;         // w 0..7
  int bx = blockIdx.x;
  int bi = bx >> 4, bj = bx & 15;
  int i0 = bi * 16;
  int iA = i0 + w * 2, iB = iA + 1;
  int l15 = lane & 15;
  int j = bj * 16 + l15;
  int ksl = (lane >> 4) * 8;

  double sj = sums[768 + j], s2j = sumsq[768 + j];
  double mA = (sums[512 + iA] + sj) * (1.0 / 512.0);
  double qA = (sumsq[512 + iA] + 2.0 * crossef[iA * 256 + j] + s2j) * (1.0 / 512.0);
  float ivA = (float)(1.0 / sqrt(qA - mA * mA + 1e-5));
  float bbA = (float)(-mA) * ivA;
  double mB = (sums[512 + iB] + sj) * (1.0 / 512.0);
  double qB = (sumsq[512 + iB] + 2.0 * crossef[iB * 256 + j] + s2j) * (1.0 / 512.0);
  float ivB = (float)(1.0 / sqrt(qB - mB * mB + 1e-5));
  float bbB = (float)(-mB) * ivB;

  const float* Vg = vfrag + bj * 8192;
  for (int q = tid; q < 2048; q += 512) {
    float4 v = *(const float4*)(Vg + q * 4);
    int kc = q >> 7, r = q & 127, ln = r >> 1;
    if (r & 1) *(float4*)(vS1 + kc * 256 + ln * 4) = v;
    else       *(float4*)(vS0 + kc * 256 + ln * 4) = v;
  }
  const float* Ug = uvf + 262144 + i0 * 512;
  for (int q = tid; q < 2048; q += 512)
    *(float4*)(uS + q * 4) = *(const float4*)(Ug + q * 4);
  if (tid < 128)      *(float4*)(gS + tid * 4)  = *(const float4*)(vecf + 2576 + tid * 4);
  else if (tid < 256) *(float4*)(beS + (tid - 128) * 4) = *(const float4*)(vecf + 3088 + (tid - 128) * 4);

  f32x4 acc[2][8];
#pragma unroll
  for (int ai = 0; ai < 2; ++ai)
#pragma unroll
    for (int bq = 0; bq < 8; ++bq) acc[ai][bq] = (f32x4){0.f, 0.f, 0.f, 0.f};

  auto H8 = [&](float4 u0, float4 u1, float4 v0, float4 v1, float4 g0, float4 g1,
                float4 e0, float4 e1, float iv, float bb) -> short8 {
    short8 a; float z;
    z = fmaf(u0.x + v0.x, iv, bb); z = fmaf(z, g0.x, e0.x); a[0] = (short)f2bf(lrelu(z));
    z = fmaf(u0.y + v0.y, iv, bb); z = fmaf(z, g0.y, e0.y); a[1] = (short)f2bf(lrelu(z));
    z = fmaf(u0.z + v0.z, iv, bb); z = fmaf(z, g0.z, e0.z); a[2] = (short)f2bf(lrelu(z));
    z = fmaf(u0.w + v0.w, iv, bb); z = fmaf(z, g0.w, e0.w); a[3] = (short)f2bf(lrelu(z));
    z = fmaf(u1.x + v1.x, iv, bb); z = fmaf(z, g1.x, e1.x); a[4] = (short)f2bf(lrelu(z));
    z = fmaf(u1.y + v1.y, iv, bb); z = fmaf(z, g1.y, e1.y); a[5] = (short)f2bf(lrelu(z));
    z = fmaf(u1.z + v1.z, iv, bb); z = fmaf(z, g1.z, e1.z); a[6] = (short)f2bf(lrelu(z));
    z = fmaf(u1.w + v1.w, iv, bb); z = fmaf(z, g1.w, e1.w); a[7] = (short)f2bf(lrelu(z));
    return a;
  };

  const float* uA = uS + (w * 2) * 512;
  const float* uB = uA + 512;

  for (int kq = 0; kq < 4; ++kq) {
    __syncthreads();
    const short8* src = (const short8*)(w2fr + kq * 16384);
    for (int q = tid; q < 2048; q += 512)
      *(short8*)(w2S + q * 8) = src[q];
    __syncthreads();
#pragma unroll
    for (int kk = 0; kk < 4; ++kk) {
      int kc = kq * 4 + kk;
      int k0 = kc * 32 + ksl;
      float4 u0 = *(const float4*)(uA + k0);
      float4 u1 = *(const float4*)(uA + k0 + 4);
      float4 b0 = *(const float4*)(uB + k0);
      float4 b1 = *(const float4*)(uB + k0 + 4);
      float4 v0 = *(const float4*)(vS0 + kc * 256 + lane * 4);
      float4 v1 = *(const float4*)(vS1 + kc * 256 + lane * 4);
      float4 g0 = *(const float4*)(gS + k0);
      float4 g1 = *(const float4*)(gS + k0 + 4);
      float4 e0 = *(const float4*)(beS + k0);
      float4 e1 = *(const float4*)(beS + k0 + 4);
      short8 aA = H8(u0, u1, v0, v1, g0, g1, e0, e1, ivA, bbA);
      short8 aB = H8(b0, b1, v0, v1, g0, g1, e0, e1, ivB, bbB);
#pragma unroll
      for (int nt = 0; nt < 8; ++nt) {
        short8 bv = *(const short8*)(w2S + kk * 4096 + nt * 512 + lane * 8);
        acc[0][nt] = __builtin_amdgcn_mfma_f32_16x16x32_bf16(aA, bv, acc[0][nt], 0, 0, 0);
        acc[1][nt] = __builtin_amdgcn_mfma_f32_16x16x32_bf16(aB, bv, acc[1][nt], 0, 0, 0);
      }
    }
  }
#pragma unroll
  for (int mi = 0; mi < 2; ++mi) {
    int ii = mi ? iB : iA;
#pragma unroll
    for (int nt = 0; nt < 8; ++nt) {
      int n = nt * 16 + l15;
      float bias = vecf[3600 + n];
#pragma unroll
      for (int r = 0; r < 4; ++r) {
        int row = (lane >> 4) * 4 + r;
        ef_f[(ii * 256 + bj * 16 + row) * 128 + n] = acc[mi][nt][r] + bias;
      }
    }
  }
}

// ---------------- naive a_src/a_dst dots (block per (n,h)) --------------------------
__global__ __launch_bounds__(64) void k_ad(const float* sf, const float* vecf, int l,
                                           float* asf, float* adf) {
  int b = blockIdx.x;            // n*4+h
  int n = b >> 2, h = b & 3;
  int lane = threadIdx.x;
  const float* s = sf + n * 2048 + h * 512;
  const float* as_ = vecf + 3728 + l * 2048 + h * 512;
  const float* ad_ = vecf + 9872 + l * 2048 + h * 512;
  float sa = 0.f, sd = 0.f;
  for (int c = lane; c < 512; c += 64) { sa = fmaf(s[c], as_[c], sa); sd = fmaf(s[c], ad_[c], sd); }
#pragma unroll
  for (int m = 1; m < 64; m <<= 1) { sa += __shfl_xor(sa, m, 64); sd += __shfl_xor(sd, m, 64); }
  if (lane == 0) { asf[b] = sa; adf[b] = sd; }
}

// ---------------- GAT attention softmax -> alpha bf16 hi/lo [dst][h*256+src] --------
__global__ __launch_bounds__(256) void k_alpha(const float* asf, const float* adf,
    const float* maskv, u16* a_hib, u16* a_lob) {
  int dd = blockIdx.x, s = threadIdx.x;
  int lane = s & 63, w = s >> 6;
  __shared__ float wr[2][4][4];
  float mk = maskv[dd * 256 + s];
  float lg[4];
#pragma unroll
  for (int h = 0; h < 4; ++h) {
    float v = adf[dd * 4 + h] + asf[s * 4 + h];
    lg[h] = lrelu(v) + mk;
  }
#pragma unroll
  for (int h = 0; h < 4; ++h) {
    float v = lg[h];
#pragma unroll
    for (int m = 1; m < 64; m <<= 1) v = fmaxf(v, __shfl_xor(v, m, 64));
    if (lane == 0) wr[0][h][w] = v;
  }
  __syncthreads();
  float e[4];
#pragma unroll
  for (int h = 0; h < 4; ++h) {
    float mx = fmaxf(fmaxf(wr[0][h][0], wr[0][h][1]), fmaxf(wr[0][h][2], wr[0][h][3]));
    float v = __expf(lg[h] - mx);
    e[h] = v;
#pragma unroll
    for (int m = 1; m < 64; m <<= 1) v += __shfl_xor(v, m, 64);
    if (lane == 0) wr[1][h][w] = v;
  }
  __syncthreads();
#pragma unroll
  for (int h = 0; h < 4; ++h) {
    float sm = wr[1][h][0] + wr[1][h][1] + wr[1][h][2] + wr[1][h][3];
    float v = e[h] / sm;
    u16 hi = f2bf(v);
    int o = dd * 1024 + h * 256 + s;
    a_hib[o] = hi;
    a_lob[o] = f2bf(v - bf2f(hi));    // v-hi exact in f32
  }
}

// ---------------- s transpose -> sT bf16 hi/lo: sT[c][h*256+n] = s[n][h*512+c] ------
__global__ __launch_bounds__(256) void k_st(const float* sf, u16* sT_hi, u16* sT_lo) {
  __shared__ float T[64][65];
  int tid = threadIdx.x;
  int hc0 = blockIdx.x * 64;
  int n0 = blockIdx.y * 64;
  int h = hc0 >> 9, c0 = hc0 & 511, q0 = h * 256 + n0;
  int cl = tid & 63, rw = tid >> 6;
#pragma unroll
  for (int rr = 0; rr < 16; ++rr) {
    int r = rr * 4 + rw;
    T[r][cl] = sf[(n0 + r) * 2048 + hc0 + cl];
  }
  __syncthreads();
#pragma unroll
  for (int rr = 0; rr < 16; ++rr) {
    int r = rr * 4 + rw;              // c-offset within tile
    float v = T[cl][r];               // stride-65 read: conflict-free
    u16 hi = f2bf(v);
    int o = (c0 + r) * 1024 + q0 + cl;
    sT_hi[o] = hi;
    sT_lo[o] = f2bf(v - bf2f(hi));
  }
}

// ---------------- aggregation as MFMA GEMM: x[i][c] = lrelu(0.25*A.B + b) -----------
__global__ __launch_bounds__(256) void k_aggm(const u16* a_hi, const u16* a_lo,
    const u16* sT_hi, const u16* sT_lo, const float* vecf, int l, float* xout) {
  int tid = threadIdx.x, lane = tid & 63, w = tid >> 6;
  int c0 = blockIdx.x * 32 + (w & 1) * 16;     // grid.x = 16
  int i0 = blockIdx.y * 32 + (w >> 1) * 16;    // grid.y = 8
  int kb = (lane >> 4) * 8;
  int ar = (i0 + (lane & 15)) * 1024 + kb;
  int br = (c0 + (lane & 15)) * 1024 + kb;
  f32x4 acc = (f32x4){0.f, 0.f, 0.f, 0.f};
#pragma unroll 4
  for (int k0 = 0; k0 < 1024; k0 += 32) {
    short8 ah = *(const short8*)(a_hi + ar + k0);
    short8 al = *(const short8*)(a_lo + ar + k0);
    short8 bh = *(const short8*)(sT_hi + br + k0);
    short8 bl = *(const short8*)(sT_lo + br + k0);
    acc = __builtin_amdgcn_mfma_f32_16x16x32_bf16(ah, bh, acc, 0, 0, 0);
    acc = __builtin_amdgcn_mfma_f32_16x16x32_bf16(ah, bl, acc, 0, 0, 0);
    acc = __builtin_amdgcn_mfma_f32_16x16x32_bf16(al, bh, acc, 0, 0, 0);
  }
  int c = c0 + (lane & 15);
  float b = vecf[16016 + l * 512 + c];
#pragma unroll
  for (int r = 0; r < 4; ++r) {
    int i = i0 + (lane >> 4) * 4 + r;
    xout[i * 512 + c] = lrelu(fmaf(acc[r], 0.25f, b));
  }
}

// ---------------- linear: out[i][c] = x[i].W[:,c] + bias; 2 rows/thread -------------
__global__ __launch_bounds__(256) void k_op(const float* x, const float* Wf,
    const float* bias, float* out) {
  int tid = threadIdx.x;
  int c = blockIdx.x * 256 + tid;            // grid.x = 2
  int i0 = blockIdx.y * 2;                   // grid.y = 128
  const float* xr = x + i0 * 512;
  float a0 = 0.f, a1 = 0.f;
  for (int k = 0; k < 512; k += 2) {
    float w0 = Wf[k * 512 + c], w1 = Wf[(k + 1) * 512 + c];
    float2 x0 = *(const float2*)(xr + k);
    float2 x1 = *(const float2*)(xr + 512 + k);
    a0 = fmaf(x0.x, w0, fmaf(x0.y, w1, a0));
    a1 = fmaf(x1.x, w0, fmaf(x1.y, w1, a1));
  }
  out[(i0 + 0) * 512 + c] = a0 + bias[c];
  out[(i0 + 1) * 512 + c] = a1 + bias[c];
}

// ---------------- output-proj LayerNorm + leaky -> f32 ------------------------------
__global__ __launch_bounds__(256) void k_ln(const float* t1, const float* vecf, float* h1f) {
  const float* g_ = vecf + 18064;
  const float* be_ = vecf + 18576;
  int row = blockIdx.x, tid = threadIdx.x, lane = tid & 63, w = tid >> 6;
  __shared__ float wr[2][4];
  float v0 = t1[row * 512 + tid];
  float v1 = t1[row * 512 + 256 + tid];
  float s = v0 + v1, s2 = fmaf(v0, v0, v1 * v1);
#pragma unroll
  for (int m = 1; m < 64; m <<= 1) { s += __shfl_xor(s, m, 64); s2 += __shfl_xor(s2, m, 64); }
  if (lane == 0) { wr[0][w] = s; wr[1][w] = s2; }
  __syncthreads();
  s = wr[0][0] + wr[0][1] + wr[0][2] + wr[0][3];
  s2 = wr[1][0] + wr[1][1] + wr[1][2] + wr[1][3];
  float m = s * (1.f / 512.f);
  float var = fmaxf(s2 * (1.f / 512.f) - m * m, 0.f);
  float iv = 1.f / sqrtf(var + 1e-5f);
  float z0 = (v0 - m) * iv * g_[tid] + be_[tid];
  float z1 = (v1 - m) * iv * g_[tid + 256] + be_[tid + 256];
  h1f[row * 512 + tid] = lrelu(z0);
  h1f[row * 512 + 256 + tid] = lrelu(z1);
}

// ---------------- final linear -> f32 out; 2 rows/thread ----------------------------
__global__ __launch_bounds__(256) void k_op2(const float* x, const float* Wf,
    const float* vecf, float* outf) {
  int tid = threadIdx.x;
  int c = blockIdx.x * 256 + tid;            // grid.x = 2
  int i0 = blockIdx.y * 2;                   // grid.y = 128
  const float* xr = x + i0 * 512;
  float a0 = 0.f, a1 = 0.f;
  for (int k = 0; k < 512; k += 2) {
    float w0 = Wf[k * 512 + c], w1 = Wf[(k + 1) * 512 + c];
    float2 x0 = *(const float2*)(xr + k);
    float2 x1 = *(const float2*)(xr + 512 + k);
    a0 = fmaf(x0.x, w0, fmaf(x0.y, w1, a0));
    a1 = fmaf(x1.x, w0, fmaf(x1.y, w1, a1));
  }
  outf[(i0 + 0) * 512 + c] = a0 + vecf[19088 + c];
  outf[(i0 + 1) * 512 + c] = a1 + vecf[19088 + c];
}

extern "C" void kernel_launch(void* const* d_in, const int* in_sizes, int n_in,
                              void* d_out, int out_size, void* d_ws, size_t ws_size,
                              hipStream_t stream) {
  (void)out_size;
  static const int dictT[23] = {0,1,2,3,4,5,6,7,8,9,10,11,12,13,14,15,16,17,18,19,20,21,22};
  static const int alphaT[23] = {6,11,7,10,9,12,8,4,0,3,2,5,1,13,15,14,16,21,17,20,19,22,18};
  const int* tbl = (n_in == 23 && in_sizes[0] == 512) ? alphaT : dictT;
  auto IN = [&](int role) -> const void* { return d_in[tbl[role]]; };

  float* out_f = (float*)d_out;                    // [256,512] f32
  float* act_f = out_f + 256 * 512;                // [256,256] f32 0/1
  float* ef_f  = out_f + 256 * 512 + 256 * 256;    // [256,256,128] f32

  char* cur = (char*)d_ws;
  auto alloc = [&](size_t bytes) -> void* {
    void* r = (void*)cur;
    cur += (bytes + 255) & ~(size_t)255;
    return r;
  };
  float* vecf    = (float*)alloc(20480 * 4);
  float* embf    = (float*)alloc(131072 * 4);
  float* epw1f   = (float*)alloc(524288 * 4);
  float* efw1f   = (float*)alloc(524288 * 4);
  float* gatWf   = (float*)alloc(3145728 * 4);
  float* opw1f   = (float*)alloc(262144 * 4);
  float* opw2f   = (float*)alloc(262144 * 4);
  float* efw2f   = (float*)alloc(65536 * 4);
  float* uvf     = (float*)alloc(524288 * 4);
  float* sf      = (float*)alloc(524288 * 4);
  float* asf     = (float*)alloc(1024 * 4);
  float* adf     = (float*)alloc(1024 * 4);
  float* xf      = (float*)alloc(262144 * 4);
  float* t1      = (float*)alloc(131072 * 4);
  float* h1f     = (float*)alloc(131072 * 4);
  float* maskv   = (float*)alloc(65536 * 4);
  double* sums   = (double*)alloc(1024 * 8);
  double* sumsq  = (double*)alloc(1024 * 8);
  double* crossep = (double*)alloc(65536 * 8);
  double* crossef = (double*)alloc(65536 * 8);
  u16* w2tb      = (u16*)alloc(65536 * 2);
  float* vfrag   = (float*)alloc(131072 * 4);
  u16* wfrb      = (u16*)alloc(2097152 * 2);   // W frag-linear hi/lo (4MB; also ef-pack)
  u16* xfrb      = (u16*)alloc(262144 * 2);    // x frag-linear hi/lo (512KB)
  int* flag      = (int*)alloc(256);
  if ((size_t)(cur - (char*)d_ws) > ws_size) return;

  // GAT-phase buffers aliased onto epw1f/efw1f (both dead after k_uv/k_uvef):
  u16* sT_hi = (u16*)epw1f;            // 512*1024 u16 = 1 MB
  u16* sT_lo = sT_hi + 524288;         // second 1 MB of epw1f's 2 MB
  u16* a_hib = (u16*)efw1f;            // 256*1024 u16 = 512 KB
  u16* a_lob = a_hib + 262144;         // next 512 KB of efw1f's 2 MB

  hipMemsetAsync(flag, 0, 256, stream);
  hipLaunchKernelGGL(k_detect, dim3(64), dim3(256), 0, stream, (const u16*)IN(0), flag);

  { // small vectors -> canonical f32
    VArgs va;
    auto setV = [&](int qi, int role, int dst, int n) { va.v[qi] = {IN(role), dst, n}; };
    setV(0, 2, 0, 512);       // ep_b1
    setV(1, 3, 512, 512);     // ep_g
    setV(2, 4, 1024, 512);    // ep_beta
    setV(3, 5, 1536, 512);    // ep_w2
    setV(4, 6, 2048, 1);      // ep_b2
    setV(5, 8, 2064, 512);    // ef_b1
    setV(6, 9, 2576, 512);    // ef_g
    setV(7, 10, 3088, 512);   // ef_beta
    setV(8, 12, 3600, 128);   // ef_b2
    setV(9, 14, 3728, 6144);  // gat_a_src
    setV(10, 15, 9872, 6144); // gat_a_dst
    setV(11, 16, 16016, 1536);// gat_b
    setV(12, 18, 17552, 512); // op_b1
    setV(13, 19, 18064, 512); // op_g
    setV(14, 20, 18576, 512); // op_beta
    setV(15, 22, 19088, 512); // op_b2
    hipLaunchKernelGGL(k_vec, dim3(16), dim3(256), 0, stream, va, (const int*)flag, vecf);
  }

  { // big matrices -> canonical f32
    CArgs ca;
    ca.src[0] = IN(0);  ca.dst[0] = embf;  ca.n[0] = 131072;
    ca.src[1] = IN(1);  ca.dst[1] = epw1f; ca.n[1] = 524288;
    ca.src[2] = IN(7);  ca.dst[2] = efw1f; ca.n[2] = 524288;
    ca.src[3] = IN(13); ca.dst[3] = gatWf; ca.n[3] = 3145728;
    ca.src[4] = IN(17); ca.dst[4] = opw1f; ca.n[4] = 262144;
    ca.src[5] = IN(21); ca.dst[5] = opw2f; ca.n[5] = 262144;
    ca.src[6] = IN(11); ca.dst[6] = efw2f; ca.n[6] = 65536;
    hipLaunchKernelGGL(k_cvt, dim3(2048, 7), dim3(256), 0, stream, ca, (const int*)flag);
  }
  hipLaunchKernelGGL(k_w2tb, dim3(256), dim3(256), 0, stream, efw2f, w2tb);

  // ef half via MFMA: pack emb + efW1, then GEMM with bias on V half.
  hipLaunchKernelGGL(k_xb, dim3(64), dim3(256), 0, stream, embf, xfrb);
  hipLaunchKernelGGL(k_wfr_ef, dim3(256), dim3(256), 0, stream, efw1f, wfrb);
  hipLaunchKernelGGL(k_uvef, dim3(32, 8), dim3(256), 0, stream, xfrb, wfrb, vecf, uvf);
  // ep half: r17-validated f64 streaming (bit-identical act).
  hipLaunchKernelGGL(k_uv, dim3(2, 64, 2), dim3(256), 0, stream, embf, epw1f, vecf, uvf);

  hipLaunchKernelGGL(k_vfr, dim3(512), dim3(256), 0, stream, uvf, vfrag);
  hipLaunchKernelGGL(k_stats64, dim3(1024), dim3(64), 0, stream, uvf, sums, sumsq);
  hipLaunchKernelGGL(k_cross, dim3(16, 16, 2), dim3(256), 0, stream, uvf, crossep, crossef);

  hipLaunchKernelGGL(k_ep_t, dim3(16, 16), dim3(256), 0, stream,
                     uvf, sums, sumsq, crossep, vecf, act_f, maskv);
  hipLaunchKernelGGL(k_ef, dim3(256), dim3(512), 0, stream,
                     uvf, sums, sumsq, crossef, vecf, w2tb, vfrag, ef_f);

  const float* xsrc = embf;
  for (int l = 0; l < 3; ++l) {
    hipLaunchKernelGGL(k_wfr, dim3(512), dim3(256), 0, stream,
                       gatWf + l * 1048576, wfrb);
    hipLaunchKernelGGL(k_xb, dim3(64), dim3(256), 0, stream, xsrc, xfrb);
    hipLaunchKernelGGL(k_sm, dim3(64, 8), dim3(256), 0, stream, xfrb, wfrb, sf);
    hipLaunchKernelGGL(k_ad, dim3(1024), dim3(64), 0, stream, sf, vecf, l, asf, adf);
    hipLaunchKernelGGL(k_alpha, dim3(256), dim3(256), 0, stream, asf, adf, maskv,
                       a_hib, a_lob);
    hipLaunchKernelGGL(k_st, dim3(32, 4), dim3(256), 0, stream, sf, sT_hi, sT_lo);
    float* xdst = xf + (l & 1) * 131072;
    hipLaunchKernelGGL(k_aggm, dim3(16, 8), dim3(256), 0, stream,
                       a_hib, a_lob, sT_hi, sT_lo, vecf, l, xdst);
    xsrc = xdst;
  }

  hipLaunchKernelGGL(k_op, dim3(2, 128), dim3(256), 0, stream, xsrc, opw1f, vecf + 17552, t1);
  hipLaunchKernelGGL(k_ln, dim3(256), dim3(256), 0, stream, t1, vecf, h1f);
  hipLaunchKernelGGL(k_op2, dim3(2, 128), dim3(256), 0, stream, h1f, opw2f, vecf, out_f);
}

// Round 13
// 396.710 us; speedup vs baseline: 1.0786x; 1.0731x over previous
//
#include <hip/hip_runtime.h>

// NeuralAudioGraph: N=256, D=H=512, E=128, 4 heads, 3 GAT layers.
// r20: k_op/k_op2 -> MFMA. r19 post-mortem: top-5 is now all harness fills
// (cutoff 42us); the remaining streaming-VALU GEMMs hide under it. k_op/k_op2
// have the exact anatomy that measured 44us in k_uv (512-deep W-load loop,
// 1 block/CU) and are f32-tolerant (t1 feeds LN; out error budget is the
// 0.0078125 bf16-ef absmax; hi/lo 3-product adds ~1e-5). Convert both to the
// VALIDATED k_sm scheme: k_wop packs opw1/opw2 frag-linear hi/lo (1MB each,
// once), k_xb packs inputs, k_opm = k_sm clone (N=512 + bias). ep k_uv stays
// f64 streaming (act-threshold safety). Baseline r19: 425.7us (r17: 410),
// absmax 0.0078125.

typedef __attribute__((ext_vector_type(8))) short short8;   // 8 x bf16 (MFMA frag)
typedef __attribute__((ext_vector_type(4))) float f32x4;    // MFMA accumulator
typedef unsigned short u16;
typedef unsigned int u32;

__device__ __forceinline__ float bf2f(u16 h) { return __uint_as_float(((u32)h) << 16); }
__device__ __forceinline__ u16 f2bf(float f) {
  u32 u = __float_as_uint(f);
  u += 0x7fffu + ((u >> 16) & 1u);   // round-to-nearest-even
  return (u16)(u >> 16);
}
__device__ __forceinline__ float lrelu(float v) { return fmaxf(v, 0.2f * v); }
__device__ __forceinline__ float ldany(int f32mode, const void* p, int i) {
  return f32mode ? ((const float*)p)[i] : bf2f(((const u16*)p)[i]);
}

// ---------------- dtype detector ----------------------------------------------------
__global__ __launch_bounds__(256) void k_detect(const u16* emb, int* flag) {
  bool big = false;
  for (int i = blockIdx.x * 256 + threadIdx.x; i < 131072; i += 256 * 64) {
    float v = bf2f(emb[i]);
    big |= !(fabsf(v) <= 1e6f);
  }
  unsigned long long m = __ballot(big);
  if (m && (threadIdx.x & 63) == 0) atomicOr(flag, 1);
}

// ---------------- small-vector ingest -> canonical f32 ------------------------------
struct VD { const void* src; int dst, n; };
struct VArgs { VD v[16]; };
__global__ __launch_bounds__(256) void k_vec(VArgs a, const int* flag, float* out) {
  int f = *flag;
  VD d = a.v[blockIdx.x];
  for (int i = threadIdx.x; i < d.n; i += 256)
    out[d.dst + i] = ldany(f, d.src, i);
}

// ---------------- big-matrix ingest -> canonical f32 --------------------------------
struct CArgs { const void* src[7]; float* dst[7]; int n[7]; };
__global__ __launch_bounds__(256) void k_cvt(CArgs a, const int* flag) {
  int f = *flag;
  int e = blockIdx.y;
  const void* s = a.src[e];
  float* d = a.dst[e];
  int n = a.n[e];
  for (int i = blockIdx.x * 256 + threadIdx.x; i < n; i += 2048 * 256)
    d[i] = ldany(f, s, i);
}

// ---------------- ef_w2 f32 [512][128] -> bf16 MFMA-fragment-linear -----------------
__global__ __launch_bounds__(256) void k_w2tb(const float* efw2f, u16* w2fr) {
  int idx = blockIdx.x * 256 + threadIdx.x;   // 65536
  int e = idx & 7, l = (idx >> 3) & 63, nt = (idx >> 9) & 7, kc = idx >> 12;
  int n = nt * 16 + (l & 15);
  int c = kc * 32 + ((l >> 4) << 3) + e;
  w2fr[idx] = f2bf(efw2f[c * 128 + n]);
}

// ---------------- V rows -> f32 MFMA-fragment-linear --------------------------------
__global__ __launch_bounds__(256) void k_vfr(const float* uvf, float* vfrag) {
  const float* V = uvf + 393216;
  int idx = blockIdx.x * 256 + threadIdx.x;   // grid 512 -> 131072
  int e = idx & 7, l = (idx >> 3) & 63, kc = (idx >> 9) & 15, jb = idx >> 13;
  int j = jb * 16 + (l & 15);
  int c = kc * 32 + ((l >> 4) << 3) + e;
  vfrag[idx] = V[j * 512 + c];
}

// ---------------- GAT W[l] -> fragment-linear interleaved bf16 hi/lo ----------------
__global__ __launch_bounds__(256) void k_wfr(const float* Wf, u16* wfr) {
  int idx = blockIdx.x * 256 + threadIdx.x;   // 131072
  int lane = idx & 63, kc = (idx >> 6) & 15, nt = idx >> 10;
  int n = nt * 16 + (lane & 15);
  int c0 = kc * 32 + ((lane >> 4) << 3);
  u16* dst = wfr + idx * 16;
#pragma unroll
  for (int e = 0; e < 8; ++e) {
    float v = Wf[(c0 + e) * 2048 + n];
    u16 hi = f2bf(v);
    dst[e] = hi;
    dst[8 + e] = f2bf(v - bf2f(hi));
  }
}

// ---------------- ef W1 ([512][512] x2 halves) -> frag-linear hi/lo, N=1024 ---------
__global__ __launch_bounds__(256) void k_wfr_ef(const float* efw1f, u16* wfr) {
  int idx = blockIdx.x * 256 + threadIdx.x;   // 65536
  int lane = idx & 63, kc = (idx >> 6) & 15, nt = idx >> 10;   // nt in [0,64)
  int n = nt * 16 + (lane & 15);              // [0,1024)
  int c0 = kc * 32 + ((lane >> 4) << 3);
  const float* base = (n < 512) ? (efw1f + n) : (efw1f + 262144 + n - 512);
  u16* dst = wfr + idx * 16;
#pragma unroll
  for (int e = 0; e < 8; ++e) {
    float v = base[(c0 + e) * 512];
    u16 hi = f2bf(v);
    dst[e] = hi;
    dst[8 + e] = f2bf(v - bf2f(hi));
  }
}

// ---------------- W [512][512] -> frag-linear interleaved bf16 hi/lo, N=512 ---------
__global__ __launch_bounds__(256) void k_wop(const float* Wf, u16* wop) {
  int idx = blockIdx.x * 256 + threadIdx.x;   // grid 128 -> 32768
  int lane = idx & 63, kc = (idx >> 6) & 15, nt = idx >> 10;   // nt in [0,32)
  int n = nt * 16 + (lane & 15);              // [0,512)
  int c0 = kc * 32 + ((lane >> 4) << 3);
  u16* dst = wop + idx * 16;
#pragma unroll
  for (int e = 0; e < 8; ++e) {
    float v = Wf[(c0 + e) * 512 + n];
    u16 hi = f2bf(v);
    dst[e] = hi;
    dst[8 + e] = f2bf(v - bf2f(hi));
  }
}

// ---------------- x -> fragment-linear interleaved bf16 hi/lo -----------------------
__global__ __launch_bounds__(256) void k_xb(const float* x, u16* xfr) {
  int idx = blockIdx.x * 256 + threadIdx.x;   // 16384
  int lane = idx & 63, kc = (idx >> 6) & 15, it = idx >> 10;
  int i = it * 16 + (lane & 15);
  int c0 = kc * 32 + ((lane >> 4) << 3);
  const float* src = x + i * 512 + c0;
  float4 v0 = *(const float4*)(src);
  float4 v1 = *(const float4*)(src + 4);
  float vv[8] = {v0.x, v0.y, v0.z, v0.w, v1.x, v1.y, v1.z, v1.w};
  u16* dst = xfr + idx * 16;
#pragma unroll
  for (int e = 0; e < 8; ++e) {
    u16 hi = f2bf(vv[e]);
    dst[e] = hi;
    dst[8 + e] = f2bf(vv[e] - bf2f(hi));
  }
}

// ---------------- GAT s = x @ W[l] as MFMA (hi/lo 3-product) ------------------------
__global__ __launch_bounds__(256) void k_sm(const u16* xfr, const u16* wfr, float* sf) {
  int tid = threadIdx.x, lane = tid & 63, w = tid >> 6;
  int n0 = blockIdx.x * 32 + (w & 1) * 16;     // grid.x = 64
  int i0 = blockIdx.y * 32 + (w >> 1) * 16;    // grid.y = 8
  int it = i0 >> 4, nt = n0 >> 4;
  const u16* ap = xfr + (it * 16) * 1024 + lane * 16;
  const u16* bp = wfr + (nt * 16) * 1024 + lane * 16;
  f32x4 acc = (f32x4){0.f, 0.f, 0.f, 0.f};
#pragma unroll
  for (int kc = 0; kc < 16; ++kc) {
    short8 ah = *(const short8*)(ap + kc * 1024);
    short8 al = *(const short8*)(ap + kc * 1024 + 8);
    short8 bh = *(const short8*)(bp + kc * 1024);
    short8 bl = *(const short8*)(bp + kc * 1024 + 8);
    acc = __builtin_amdgcn_mfma_f32_16x16x32_bf16(ah, bh, acc, 0, 0, 0);
    acc = __builtin_amdgcn_mfma_f32_16x16x32_bf16(ah, bl, acc, 0, 0, 0);
    acc = __builtin_amdgcn_mfma_f32_16x16x32_bf16(al, bh, acc, 0, 0, 0);
  }
  int col = n0 + (lane & 15);
#pragma unroll
  for (int r = 0; r < 4; ++r) {
    int row = i0 + (lane >> 4) * 4 + r;
    sf[row * 2048 + col] = acc[r];
  }
}

// ---------------- generic 256x512 @ K=512 MFMA linear + bias (k_op/k_op2) -----------
// grid (16, 8), 256 thr = 4 waves. Same fragment scheme as validated k_sm.
__global__ __launch_bounds__(256) void k_opm(const u16* xfr, const u16* wop,
    const float* bias, float* out) {
  int tid = threadIdx.x, lane = tid & 63, w = tid >> 6;
  int n0 = blockIdx.x * 32 + (w & 1) * 16;     // grid.x = 16
  int i0 = blockIdx.y * 32 + (w >> 1) * 16;    // grid.y = 8
  int it = i0 >> 4, nt = n0 >> 4;
  const u16* ap = xfr + (it * 16) * 1024 + lane * 16;
  const u16* bp = wop + (nt * 16) * 1024 + lane * 16;
  f32x4 acc = (f32x4){0.f, 0.f, 0.f, 0.f};
#pragma unroll
  for (int kc = 0; kc < 16; ++kc) {
    short8 ah = *(const short8*)(ap + kc * 1024);
    short8 al = *(const short8*)(ap + kc * 1024 + 8);
    short8 bh = *(const short8*)(bp + kc * 1024);
    short8 bl = *(const short8*)(bp + kc * 1024 + 8);
    acc = __builtin_amdgcn_mfma_f32_16x16x32_bf16(ah, bh, acc, 0, 0, 0);
    acc = __builtin_amdgcn_mfma_f32_16x16x32_bf16(ah, bl, acc, 0, 0, 0);
    acc = __builtin_amdgcn_mfma_f32_16x16x32_bf16(al, bh, acc, 0, 0, 0);
  }
  int col = n0 + (lane & 15);
  float b = bias[col];
#pragma unroll
  for (int r = 0; r < 4; ++r) {
    int row = i0 + (lane >> 4) * 4 + r;
    out[row * 512 + col] = acc[r] + b;
  }
}

// ---------------- U/V_ef = emb @ efW1 as MFMA (hi/lo 3-product) ---------------------
__global__ __launch_bounds__(256) void k_uvef(const u16* xfr, const u16* wfr,
    const float* vecf, float* uvf) {
  int tid = threadIdx.x, lane = tid & 63, w = tid >> 6;
  int n0 = blockIdx.x * 32 + (w & 1) * 16;     // grid.x = 32
  int i0 = blockIdx.y * 32 + (w >> 1) * 16;    // grid.y = 8
  int it = i0 >> 4, nt = n0 >> 4;
  const u16* ap = xfr + (it * 16) * 1024 + lane * 16;
  const u16* bp = wfr + (nt * 16) * 1024 + lane * 16;
  f32x4 acc = (f32x4){0.f, 0.f, 0.f, 0.f};
#pragma unroll
  for (int kc = 0; kc < 16; ++kc) {
    short8 ah = *(const short8*)(ap + kc * 1024);
    short8 al = *(const short8*)(ap + kc * 1024 + 8);
    short8 bh = *(const short8*)(bp + kc * 1024);
    short8 bl = *(const short8*)(bp + kc * 1024 + 8);
    acc = __builtin_amdgcn_mfma_f32_16x16x32_bf16(ah, bh, acc, 0, 0, 0);
    acc = __builtin_amdgcn_mfma_f32_16x16x32_bf16(ah, bl, acc, 0, 0, 0);
    acc = __builtin_amdgcn_mfma_f32_16x16x32_bf16(al, bh, acc, 0, 0, 0);
  }
  int col = n0 + (lane & 15);
  float bias = (col >= 512) ? vecf[2064 + col - 512] : 0.f;
  float* outb = (col < 512) ? (uvf + 262144 + col) : (uvf + 393216 + col - 512);
#pragma unroll
  for (int r = 0; r < 4; ++r) {
    int row = i0 + (lane >> 4) * 4 + r;
    outb[row * 512] = acc[r] + bias;
  }
}

// ---------------- U/V_ep = emb @ epW1 halves, f64 (r17-validated, ep only) ----------
__global__ __launch_bounds__(256) void k_uv(const float* embf, const float* epw1f,
    const float* vecf, float* uvf) {
  int tid = threadIdx.x;
  int col = blockIdx.x * 256 + tid;
  int r0 = blockIdx.y * 4;
  int arr = blockIdx.z;
  const float* W = epw1f + arr * 262144 + col;
  const float* e = embf + r0 * 512;
  float bias = (arr == 1) ? vecf[col] : 0.f;
  float* outp = uvf + arr * 131072 + r0 * 512 + col;
  double a0 = 0.0, a1 = 0.0, a2 = 0.0, a3 = 0.0;
  for (int k = 0; k < 512; k += 2) {
    double w0 = (double)W[k * 512];
    double w1 = (double)W[(k + 1) * 512];
    float2 e0 = *(const float2*)(e + k);
    float2 e1 = *(const float2*)(e + 512 + k);
    float2 e2 = *(const float2*)(e + 1024 + k);
    float2 e3 = *(const float2*)(e + 1536 + k);
    a0 += (double)e0.x * w0 + (double)e0.y * w1;
    a1 += (double)e1.x * w0 + (double)e1.y * w1;
    a2 += (double)e2.x * w0 + (double)e2.y * w1;
    a3 += (double)e3.x * w0 + (double)e3.y * w1;
  }
  outp[0]    = (float)(a0 + (double)bias);
  outp[512]  = (float)(a1 + (double)bias);
  outp[1024] = (float)(a2 + (double)bias);
  outp[1536] = (float)(a3 + (double)bias);
}

// ---------------- f64 row sums / sums-of-squares ------------------------------------
__global__ __launch_bounds__(64) void k_stats64(const float* uvf, double* sums, double* sumsq) {
  int bid = blockIdx.x;           // arr*256 + row
  int lane = threadIdx.x;
  const float* p = uvf + bid * 512;
  double s = 0.0, s2 = 0.0;
  for (int q = lane; q < 512; q += 64) { double v = p[q]; s += v; s2 += v * v; }
#pragma unroll
  for (int m = 1; m < 64; m <<= 1) { s += __shfl_xor(s, m, 64); s2 += __shfl_xor(s2, m, 64); }
  if (lane == 0) { sums[bid] = s; sumsq[bid] = s2; }
}

// ---------------- cross[i][j] = U_i . V_j (f64): z=0 -> ep, z=1 -> ef ---------------
__global__ __launch_bounds__(256) void k_cross(const float* uvf, double* crossep,
                                               double* crossef) {
  __shared__ float Uc[16][132], Vc[16][132];
  int z = blockIdx.z;
  const float* U = uvf + z * 262144;
  const float* V = U + 131072;
  double* out = z ? crossef : crossep;
  int tid = threadIdx.x, ti = tid & 15, tj = tid >> 4;
  int i0 = blockIdx.y * 16, j0 = blockIdx.x * 16;
  double acc = 0.0;
  for (int c0 = 0; c0 < 512; c0 += 128) {
    __syncthreads();
    for (int idx = tid; idx < 2048; idx += 256) {
      int r = idx >> 7, c = idx & 127;
      Uc[r][c] = U[(i0 + r) * 512 + c0 + c];
      Vc[r][c] = V[(j0 + r) * 512 + c0 + c];
    }
    __syncthreads();
#pragma unroll
    for (int c4 = 0; c4 < 128; c4 += 4) {
      float4 uu = *(const float4*)&Uc[ti][c4];
      float4 vv = *(const float4*)&Vc[tj][c4];
      float p = fmaf(uu.x, vv.x, fmaf(uu.y, vv.y, fmaf(uu.z, vv.z, uu.w * vv.w)));
      acc += (double)p;
    }
  }
  out[(i0 + ti) * 256 + j0 + tj] = acc;
}

// ---------------- edge predictor, stats-based tiled (1 thread / pair) ---------------
__global__ __launch_bounds__(256) void k_ep_t(const float* uvf, const double* sums,
    const double* sumsq, const double* crossep, const float* vecf,
    float* act, float* maskv) {
  __shared__ float Uc[16][132], Vc[16][132];
  int tid = threadIdx.x, ti = tid & 15, tj = tid >> 4;
  int i0 = blockIdx.y * 16, j0 = blockIdx.x * 16;
  int i = i0 + ti, j = j0 + tj;
  double md = (sums[i] + sums[256 + j]) * (1.0 / 512.0);
  double qd = (sumsq[i] + 2.0 * crossep[i * 256 + j] + sumsq[256 + j]) * (1.0 / 512.0);
  float iv = (float)(1.0 / sqrt(qd - md * md + 1e-5));
  float bb = (float)(-md) * iv;
  const float* U = uvf;
  const float* V = uvf + 131072;
  const float* g_ = vecf + 512;
  const float* be_ = vecf + 1024;
  const float* w2_ = vecf + 1536;
  double acc = 0.0;
  for (int c0 = 0; c0 < 512; c0 += 128) {
    __syncthreads();
    for (int idx = tid; idx < 2048; idx += 256) {
      int r = idx >> 7, c = idx & 127;
      Uc[r][c] = U[(i0 + r) * 512 + c0 + c];
      Vc[r][c] = V[(j0 + r) * 512 + c0 + c];
    }
    __syncthreads();
#pragma unroll
    for (int c4 = 0; c4 < 128; c4 += 4) {
      float4 uu = *(const float4*)&Uc[ti][c4];
      float4 vv = *(const float4*)&Vc[tj][c4];
      float4 gg = *(const float4*)(g_ + c0 + c4);
      float4 b4 = *(const float4*)(be_ + c0 + c4);
      float4 w4 = *(const float4*)(w2_ + c0 + c4);
      float z, s4 = 0.f;
      z = fmaf(fmaf(uu.x + vv.x, iv, bb), gg.x, b4.x); s4 = fmaf(lrelu(z), w4.x, s4);
      z = fmaf(fmaf(uu.y + vv.y, iv, bb), gg.y, b4.y); s4 = fmaf(lrelu(z), w4.y, s4);
      z = fmaf(fmaf(uu.z + vv.z, iv, bb), gg.z, b4.z); s4 = fmaf(lrelu(z), w4.z, s4);
      z = fmaf(fmaf(uu.w + vv.w, iv, bb), gg.w, b4.w); s4 = fmaf(lrelu(z), w4.w, s4);
      acc += (double)s4;
    }
  }
  double logit = acc + (double)vecf[2048];
  bool a = (logit > 0.0) && (i != j);
  act[i * 256 + j] = a ? 1.0f : 0.0f;
  maskv[j * 256 + i] = (a || i == j) ? 0.f : -1e9f;         // adj[dst][src] mask
}

// ---------------- edge features: all-LDS inner loop + bf16 MFMA (r15, validated) ----
__global__ __launch_bounds__(512, 2) void k_ef(const float* uvf, const double* sums,
    const double* sumsq, const double* crossef, const float* vecf,
    const u16* w2fr, const float* vfrag, float* ef_f) {
  __shared__ u16 w2S[16384];                 // 32 KB: 4 kc x 8 nt x 512
  __shared__ float vS0[4096], vS1[4096];     // 16+16 KB
  __shared__ float uS[8192];                 // 32 KB: 16 rows x 512
  __shared__ float gS[512], beS[512];        // 4 KB
  int tid = threadIdx.x;
  int lane = tid & 63, w = tid >> 6;         // w 0..7
  int bx = blockIdx.x;
  int bi = bx >> 4, bj = bx & 15;
  int i0 = bi * 16;
  int iA = i0 + w * 2, iB = iA + 1;
  int l15 = lane & 15;
  int j = bj * 16 + l15;
  int ksl = (lane >> 4) * 8;

  double sj = sums[768 + j], s2j = sumsq[768 + j];
  double mA = (sums[512 + iA] + sj) * (1.0 / 512.0);
  double qA = (sumsq[512 + iA] + 2.0 * crossef[iA * 256 + j] + s2j) * (1.0 / 512.0);
  float ivA = (float)(1.0 / sqrt(qA - mA * mA + 1e-5));
  float bbA = (float)(-mA) * ivA;
  double mB = (sums[512 + iB] + sj) * (1.0 / 512.0);
  double qB = (sumsq[512 + iB] + 2.0 * crossef[iB * 256 + j] + s2j) * (1.0 / 512.0);
  float ivB = (float)(1.0 / sqrt(qB - mB * mB + 1e-5));
  float bbB = (float)(-mB) * ivB;

  const float* Vg = vfrag + bj * 8192;
  for (int q = tid; q < 2048; q += 512) {
    float4 v = *(const float4*)(Vg + q * 4);
    int kc = q >> 7, r = q & 127, ln = r >> 1;
    if (r & 1) *(float4*)(vS1 + kc * 256 + ln * 4) = v;
    else       *(float4*)(vS0 + kc * 256 + ln * 4) = v;
  }
  const float* Ug = uvf + 262144 + i0 * 512;
  for (int q = tid; q < 2048; q += 512)
    *(float4*)(uS + q * 4) = *(const float4*)(Ug + q * 4);
  if (tid < 128)      *(float4*)(gS + tid * 4)  = *(const float4*)(vecf + 2576 + tid * 4);
  else if (tid < 256) *(float4*)(beS + (tid - 128) * 4) = *(const float4*)(vecf + 3088 + (tid - 128) * 4);

  f32x4 acc[2][8];
#pragma unroll
  for (int ai = 0; ai < 2; ++ai)
#pragma unroll
    for (int bq = 0; bq < 8; ++bq) acc[ai][bq] = (f32x4){0.f, 0.f, 0.f, 0.f};

  auto H8 = [&](float4 u0, float4 u1, float4 v0, float4 v1, float4 g0, float4 g1,
                float4 e0, float4 e1, float iv, float bb) -> short8 {
    short8 a; float z;
    z = fmaf(u0.x + v0.x, iv, bb); z = fmaf(z, g0.x, e0.x); a[0] = (short)f2bf(lrelu(z));
    z = fmaf(u0.y + v0.y, iv, bb); z = fmaf(z, g0.y, e0.y); a[1] = (short)f2bf(lrelu(z));
    z = fmaf(u0.z + v0.z, iv, bb); z = fmaf(z, g0.z, e0.z); a[2] = (short)f2bf(lrelu(z));
    z = fmaf(u0.w + v0.w, iv, bb); z = fmaf(z, g0.w, e0.w); a[3] = (short)f2bf(lrelu(z));
    z = fmaf(u1.x + v1.x, iv, bb); z = fmaf(z, g1.x, e1.x); a[4] = (short)f2bf(lrelu(z));
    z = fmaf(u1.y + v1.y, iv, bb); z = fmaf(z, g1.y, e1.y); a[5] = (short)f2bf(lrelu(z));
    z = fmaf(u1.z + v1.z, iv, bb); z = fmaf(z, g1.z, e1.z); a[6] = (short)f2bf(lrelu(z));
    z = fmaf(u1.w + v1.w, iv, bb); z = fmaf(z, g1.w, e1.w); a[7] = (short)f2bf(lrelu(z));
    return a;
  };

  const float* uA = uS + (w * 2) * 512;
  const float* uB = uA + 512;

  for (int kq = 0; kq < 4; ++kq) {
    __syncthreads();
    const short8* src = (const short8*)(w2fr + kq * 16384);
    for (int q = tid; q < 2048; q += 512)
      *(short8*)(w2S + q * 8) = src[q];
    __syncthreads();
#pragma unroll
    for (int kk = 0; kk < 4; ++kk) {
      int kc = kq * 4 + kk;
      int k0 = kc * 32 + ksl;
      float4 u0 = *(const float4*)(uA + k0);
      float4 u1 = *(const float4*)(uA + k0 + 4);
      float4 b0 = *(const float4*)(uB + k0);
      float4 b1 = *(const float4*)(uB + k0 + 4);
      float4 v0 = *(const float4*)(vS0 + kc * 256 + lane * 4);
      float4 v1 = *(const float4*)(vS1 + kc * 256 + lane * 4);
      float4 g0 = *(const float4*)(gS + k0);
      float4 g1 = *(const float4*)(gS + k0 + 4);
      float4 e0 = *(const float4*)(beS + k0);
      float4 e1 = *(const float4*)(beS + k0 + 4);
      short8 aA = H8(u0, u1, v0, v1, g0, g1, e0, e1, ivA, bbA);
      short8 aB = H8(b0, b1, v0, v1, g0, g1, e0, e1, ivB, bbB);
#pragma unroll
      for (int nt = 0; nt < 8; ++nt) {
        short8 bv = *(const short8*)(w2S + kk * 4096 + nt * 512 + lane * 8);
        acc[0][nt] = __builtin_amdgcn_mfma_f32_16x16x32_bf16(aA, bv, acc[0][nt], 0, 0, 0);
        acc[1][nt] = __builtin_amdgcn_mfma_f32_16x16x32_bf16(aB, bv, acc[1][nt], 0, 0, 0);
      }
    }
  }
#pragma unroll
  for (int mi = 0; mi < 2; ++mi) {
    int ii = mi ? iB : iA;
#pragma unroll
    for (int nt = 0; nt < 8; ++nt) {
      int n = nt * 16 + l15;
      float bias = vecf[3600 + n];
#pragma unroll
      for (int r = 0; r < 4; ++r) {
        int row = (lane >> 4) * 4 + r;
        ef_f[(ii * 256 + bj * 16 + row) * 128 + n] = acc[mi][nt][r] + bias;
      }
    }
  }
}

// ---------------- naive a_src/a_dst dots (block per (n,h)) --------------------------
__global__ __launch_bounds__(64) void k_ad(const float* sf, const float* vecf, int l,
                                           float* asf, float* adf) {
  int b = blockIdx.x;            // n*4+h
  int n = b >> 2, h = b & 3;
  int lane = threadIdx.x;
  const float* s = sf + n * 2048 + h * 512;
  const float* as_ = vecf + 3728 + l * 2048 + h * 512;
  const float* ad_ = vecf + 9872 + l * 2048 + h * 512;
  float sa = 0.f, sd = 0.f;
  for (int c = lane; c < 512; c += 64) { sa = fmaf(s[c], as_[c], sa); sd = fmaf(s[c], ad_[c], sd); }
#pragma unroll
  for (int m = 1; m < 64; m <<= 1) { sa += __shfl_xor(sa, m, 64); sd += __shfl_xor(sd, m, 64); }
  if (lane == 0) { asf[b] = sa; adf[b] = sd; }
}

// ---------------- GAT attention softmax -> alpha bf16 hi/lo [dst][h*256+src] --------
__global__ __launch_bounds__(256) void k_alpha(const float* asf, const float* adf,
    const float* maskv, u16* a_hib, u16* a_lob) {
  int dd = blockIdx.x, s = threadIdx.x;
  int lane = s & 63, w = s >> 6;
  __shared__ float wr[2][4][4];
  float mk = maskv[dd * 256 + s];
  float lg[4];
#pragma unroll
  for (int h = 0; h < 4; ++h) {
    float v = adf[dd * 4 + h] + asf[s * 4 + h];
    lg[h] = lrelu(v) + mk;
  }
#pragma unroll
  for (int h = 0; h < 4; ++h) {
    float v = lg[h];
#pragma unroll
    for (int m = 1; m < 64; m <<= 1) v = fmaxf(v, __shfl_xor(v, m, 64));
    if (lane == 0) wr[0][h][w] = v;
  }
  __syncthreads();
  float e[4];
#pragma unroll
  for (int h = 0; h < 4; ++h) {
    float mx = fmaxf(fmaxf(wr[0][h][0], wr[0][h][1]), fmaxf(wr[0][h][2], wr[0][h][3]));
    float v = __expf(lg[h] - mx);
    e[h] = v;
#pragma unroll
    for (int m = 1; m < 64; m <<= 1) v += __shfl_xor(v, m, 64);
    if (lane == 0) wr[1][h][w] = v;
  }
  __syncthreads();
#pragma unroll
  for (int h = 0; h < 4; ++h) {
    float sm = wr[1][h][0] + wr[1][h][1] + wr[1][h][2] + wr[1][h][3];
    float v = e[h] / sm;
    u16 hi = f2bf(v);
    int o = dd * 1024 + h * 256 + s;
    a_hib[o] = hi;
    a_lob[o] = f2bf(v - bf2f(hi));    // v-hi exact in f32
  }
}

// ---------------- s transpose -> sT bf16 hi/lo: sT[c][h*256+n] = s[n][h*512+c] ------
__global__ __launch_bounds__(256) void k_st(const float* sf, u16* sT_hi, u16* sT_lo) {
  __shared__ float T[64][65];
  int tid = threadIdx.x;
  int hc0 = blockIdx.x * 64;
  int n0 = blockIdx.y * 64;
  int h = hc0 >> 9, c0 = hc0 & 511, q0 = h * 256 + n0;
  int cl = tid & 63, rw = tid >> 6;
#pragma unroll
  for (int rr = 0; rr < 16; ++rr) {
    int r = rr * 4 + rw;
    T[r][cl] = sf[(n0 + r) * 2048 + hc0 + cl];
  }
  __syncthreads();
#pragma unroll
  for (int rr = 0; rr < 16; ++rr) {
    int r = rr * 4 + rw;              // c-offset within tile
    float v = T[cl][r];               // stride-65 read: conflict-free
    u16 hi = f2bf(v);
    int o = (c0 + r) * 1024 + q0 + cl;
    sT_hi[o] = hi;
    sT_lo[o] = f2bf(v - bf2f(hi));
  }
}

// ---------------- aggregation as MFMA GEMM: x[i][c] = lrelu(0.25*A.B + b) -----------
__global__ __launch_bounds__(256) void k_aggm(const u16* a_hi, const u16* a_lo,
    const u16* sT_hi, const u16* sT_lo, const float* vecf, int l, float* xout) {
  int tid = threadIdx.x, lane = tid & 63, w = tid >> 6;
  int c0 = blockIdx.x * 32 + (w & 1) * 16;     // grid.x = 16
  int i0 = blockIdx.y * 32 + (w >> 1) * 16;    // grid.y = 8
  int kb = (lane >> 4) * 8;
  int ar = (i0 + (lane & 15)) * 1024 + kb;
  int br = (c0 + (lane & 15)) * 1024 + kb;
  f32x4 acc = (f32x4){0.f, 0.f, 0.f, 0.f};
#pragma unroll 4
  for (int k0 = 0; k0 < 1024; k0 += 32) {
    short8 ah = *(const short8*)(a_hi + ar + k0);
    short8 al = *(const short8*)(a_lo + ar + k0);
    short8 bh = *(const short8*)(sT_hi + br + k0);
    short8 bl = *(const short8*)(sT_lo + br + k0);
    acc = __builtin_amdgcn_mfma_f32_16x16x32_bf16(ah, bh, acc, 0, 0, 0);
    acc = __builtin_amdgcn_mfma_f32_16x16x32_bf16(ah, bl, acc, 0, 0, 0);
    acc = __builtin_amdgcn_mfma_f32_16x16x32_bf16(al, bh, acc, 0, 0, 0);
  }
  int c = c0 + (lane & 15);
  float b = vecf[16016 + l * 512 + c];
#pragma unroll
  for (int r = 0; r < 4; ++r) {
    int i = i0 + (lane >> 4) * 4 + r;
    xout[i * 512 + c] = lrelu(fmaf(acc[r], 0.25f, b));
  }
}

// ---------------- output-proj LayerNorm + leaky -> f32 ------------------------------
__global__ __launch_bounds__(256) void k_ln(const float* t1, const float* vecf, float* h1f) {
  const float* g_ = vecf + 18064;
  const float* be_ = vecf + 18576;
  int row = blockIdx.x, tid = threadIdx.x, lane = tid & 63, w = tid >> 6;
  __shared__ float wr[2][4];
  float v0 = t1[row * 512 + tid];
  float v1 = t1[row * 512 + 256 + tid];
  float s = v0 + v1, s2 = fmaf(v0, v0, v1 * v1);
#pragma unroll
  for (int m = 1; m < 64; m <<= 1) { s += __shfl_xor(s, m, 64); s2 += __shfl_xor(s2, m, 64); }
  if (lane == 0) { wr[0][w] = s; wr[1][w] = s2; }
  __syncthreads();
  s = wr[0][0] + wr[0][1] + wr[0][2] + wr[0][3];
  s2 = wr[1][0] + wr[1][1] + wr[1][2] + wr[1][3];
  float m = s * (1.f / 512.f);
  float var = fmaxf(s2 * (1.f / 512.f) - m * m, 0.f);
  float iv = 1.f / sqrtf(var + 1e-5f);
  float z0 = (v0 - m) * iv * g_[tid] + be_[tid];
  float z1 = (v1 - m) * iv * g_[tid + 256] + be_[tid + 256];
  h1f[row * 512 + tid] = lrelu(z0);
  h1f[row * 512 + 256 + tid] = lrelu(z1);
}

extern "C" void kernel_launch(void* const* d_in, const int* in_sizes, int n_in,
                              void* d_out, int out_size, void* d_ws, size_t ws_size,
                              hipStream_t stream) {
  (void)out_size;
  static const int dictT[23] = {0,1,2,3,4,5,6,7,8,9,10,11,12,13,14,15,16,17,18,19,20,21,22};
  static const int alphaT[23] = {6,11,7,10,9,12,8,4,0,3,2,5,1,13,15,14,16,21,17,20,19,22,18};
  const int* tbl = (n_in == 23 && in_sizes[0] == 512) ? alphaT : dictT;
  auto IN = [&](int role) -> const void* { return d_in[tbl[role]]; };

  float* out_f = (float*)d_out;                    // [256,512] f32
  float* act_f = out_f + 256 * 512;                // [256,256] f32 0/1
  float* ef_f  = out_f + 256 * 512 + 256 * 256;    // [256,256,128] f32

  char* cur = (char*)d_ws;
  auto alloc = [&](size_t bytes) -> void* {
    void* r = (void*)cur;
    cur += (bytes + 255) & ~(size_t)255;
    return r;
  };
  float* vecf    = (float*)alloc(20480 * 4);
  float* embf    = (float*)alloc(131072 * 4);
  float* epw1f   = (float*)alloc(524288 * 4);
  float* efw1f   = (float*)alloc(524288 * 4);
  float* gatWf   = (float*)alloc(3145728 * 4);
  float* opw1f   = (float*)alloc(262144 * 4);
  float* opw2f   = (float*)alloc(262144 * 4);
  float* efw2f   = (float*)alloc(65536 * 4);
  float* uvf     = (float*)alloc(524288 * 4);
  float* sf      = (float*)alloc(524288 * 4);
  float* asf     = (float*)alloc(1024 * 4);
  float* adf     = (float*)alloc(1024 * 4);
  float* xf      = (float*)alloc(262144 * 4);
  float* t1      = (float*)alloc(131072 * 4);
  float* h1f     = (float*)alloc(131072 * 4);
  float* maskv   = (float*)alloc(65536 * 4);
  double* sums   = (double*)alloc(1024 * 8);
  double* sumsq  = (double*)alloc(1024 * 8);
  double* crossep = (double*)alloc(65536 * 8);
  double* crossef = (double*)alloc(65536 * 8);
  u16* w2tb      = (u16*)alloc(65536 * 2);
  float* vfrag   = (float*)alloc(131072 * 4);
  u16* wfrb      = (u16*)alloc(2097152 * 2);   // W frag-linear hi/lo (4MB; also ef-pack)
  u16* xfrb      = (u16*)alloc(262144 * 2);    // x frag-linear hi/lo (512KB)
  u16* opw1p     = (u16*)alloc(524288 * 2);    // opw1 frag-linear hi/lo (1MB)
  u16* opw2p     = (u16*)alloc(524288 * 2);    // opw2 frag-linear hi/lo (1MB)
  int* flag      = (int*)alloc(256);
  if ((size_t)(cur - (char*)d_ws) > ws_size) return;

  // GAT-phase buffers aliased onto epw1f/efw1f (both dead after k_uv/k_uvef):
  u16* sT_hi = (u16*)epw1f;            // 512*1024 u16 = 1 MB
  u16* sT_lo = sT_hi + 524288;         // second 1 MB of epw1f's 2 MB
  u16* a_hib = (u16*)efw1f;            // 256*1024 u16 = 512 KB
  u16* a_lob = a_hib + 262144;         // next 512 KB of efw1f's 2 MB

  hipMemsetAsync(flag, 0, 256, stream);
  hipLaunchKernelGGL(k_detect, dim3(64), dim3(256), 0, stream, (const u16*)IN(0), flag);

  { // small vectors -> canonical f32
    VArgs va;
    auto setV = [&](int qi, int role, int dst, int n) { va.v[qi] = {IN(role), dst, n}; };
    setV(0, 2, 0, 512);       // ep_b1
    setV(1, 3, 512, 512);     // ep_g
    setV(2, 4, 1024, 512);    // ep_beta
    setV(3, 5, 1536, 512);    // ep_w2
    setV(4, 6, 2048, 1);      // ep_b2
    setV(5, 8, 2064, 512);    // ef_b1
    setV(6, 9, 2576, 512);    // ef_g
    setV(7, 10, 3088, 512);   // ef_beta
    setV(8, 12, 3600, 128);   // ef_b2
    setV(9, 14, 3728, 6144);  // gat_a_src
    setV(10, 15, 9872, 6144); // gat_a_dst
    setV(11, 16, 16016, 1536);// gat_b
    setV(12, 18, 17552, 512); // op_b1
    setV(13, 19, 18064, 512); // op_g
    setV(14, 20, 18576, 512); // op_beta
    setV(15, 22, 19088, 512); // op_b2
    hipLaunchKernelGGL(k_vec, dim3(16), dim3(256), 0, stream, va, (const int*)flag, vecf);
  }

  { // big matrices -> canonical f32
    CArgs ca;
    ca.src[0] = IN(0);  ca.dst[0] = embf;  ca.n[0] = 131072;
    ca.src[1] = IN(1);  ca.dst[1] = epw1f; ca.n[1] = 524288;
    ca.src[2] = IN(7);  ca.dst[2] = efw1f; ca.n[2] = 524288;
    ca.src[3] = IN(13); ca.dst[3] = gatWf; ca.n[3] = 3145728;
    ca.src[4] = IN(17); ca.dst[4] = opw1f; ca.n[4] = 262144;
    ca.src[5] = IN(21); ca.dst[5] = opw2f; ca.n[5] = 262144;
    ca.src[6] = IN(11); ca.dst[6] = efw2f; ca.n[6] = 65536;
    hipLaunchKernelGGL(k_cvt, dim3(2048, 7), dim3(256), 0, stream, ca, (const int*)flag);
  }
  hipLaunchKernelGGL(k_w2tb, dim3(256), dim3(256), 0, stream, efw2f, w2tb);
  hipLaunchKernelGGL(k_wop, dim3(128), dim3(256), 0, stream, opw1f, opw1p);
  hipLaunchKernelGGL(k_wop, dim3(128), dim3(256), 0, stream, opw2f, opw2p);

  // ef half via MFMA: pack emb + efW1, then GEMM with bias on V half.
  hipLaunchKernelGGL(k_xb, dim3(64), dim3(256), 0, stream, embf, xfrb);
  hipLaunchKernelGGL(k_wfr_ef, dim3(256), dim3(256), 0, stream, efw1f, wfrb);
  hipLaunchKernelGGL(k_uvef, dim3(32, 8), dim3(256), 0, stream, xfrb, wfrb, vecf, uvf);
  // ep half: r17-validated f64 streaming (bit-identical act).
  hipLaunchKernelGGL(k_uv, dim3(2, 64, 2), dim3(256), 0, stream, embf, epw1f, vecf, uvf);

  hipLaunchKernelGGL(k_vfr, dim3(512), dim3(256), 0, stream, uvf, vfrag);
  hipLaunchKernelGGL(k_stats64, dim3(1024), dim3(64), 0, stream, uvf, sums, sumsq);
  hipLaunchKernelGGL(k_cross, dim3(16, 16, 2), dim3(256), 0, stream, uvf, crossep, crossef);

  hipLaunchKernelGGL(k_ep_t, dim3(16, 16), dim3(256), 0, stream,
                     uvf, sums, sumsq, crossep, vecf, act_f, maskv);
  hipLaunchKernelGGL(k_ef, dim3(256), dim3(512), 0, stream,
                     uvf, sums, sumsq, crossef, vecf, w2tb, vfrag, ef_f);

  const float* xsrc = embf;
  for (int l = 0; l < 3; ++l) {
    hipLaunchKernelGGL(k_wfr, dim3(512), dim3(256), 0, stream,
                       gatWf + l * 1048576, wfrb);
    hipLaunchKernelGGL(k_xb, dim3(64), dim3(256), 0, stream, xsrc, xfrb);
    hipLaunchKernelGGL(k_sm, dim3(64, 8), dim3(256), 0, stream, xfrb, wfrb, sf);
    hipLaunchKernelGGL(k_ad, dim3(1024), dim3(64), 0, stream, sf, vecf, l, asf, adf);
    hipLaunchKernelGGL(k_alpha, dim3(256), dim3(256), 0, stream, asf, adf, maskv,
                       a_hib, a_lob);
    hipLaunchKernelGGL(k_st, dim3(32, 4), dim3(256), 0, stream, sf, sT_hi, sT_lo);
    float* xdst = xf + (l & 1) * 131072;
    hipLaunchKernelGGL(k_aggm, dim3(16, 8), dim3(256), 0, stream,
                       a_hib, a_lob, sT_hi, sT_lo, vecf, l, xdst);
    xsrc = xdst;
  }

  // output projection: both linears via validated MFMA path.
  hipLaunchKernelGGL(k_xb, dim3(64), dim3(256), 0, stream, xsrc, xfrb);
  hipLaunchKernelGGL(k_opm, dim3(16, 8), dim3(256), 0, stream,
                     xfrb, opw1p, vecf + 17552, t1);
  hipLaunchKernelGGL(k_ln, dim3(256), dim3(256), 0, stream, t1, vecf, h1f);
  hipLaunchKernelGGL(k_xb, dim3(64), dim3(256), 0, stream, h1f, xfrb);
  hipLaunchKernelGGL(k_opm, dim3(16, 8), dim3(256), 0, stream,
                     xfrb, opw2p, vecf + 19088, out_f);
}

// Round 14
// 387.244 us; speedup vs baseline: 1.1050x; 1.0244x over previous
//
#include <hip/hip_runtime.h>

// NeuralAudioGraph: N=256, D=H=512, E=128, 4 heads, 3 GAT layers.
// r21: ep k_uv W-chain fix. r20 (k_op/k_opm MFMA) banked 29us -> 396.7us.
// Last ~40us kernel: ep k_uv (f64, act-threshold-locked math) walks 256
// k-iterations x 2 strided (2KB) W loads -> ~512-load serial chain. Fix the
// ADDRESSING only: k_wt transposes epW1 once (LDS-tiled, 2MB, ~2us) into
// wt[arr][col][k]; k_uv then reads its column contiguously as float4 -> 128
// load instrs/thread (4x shorter chain). Same f64 expressions, same k-order
// -> bit-identical uvf_ep/act/maskv. Everything else frozen from r20.
// Baseline r20: 396.7us, absmax 0.0078125.

typedef __attribute__((ext_vector_type(8))) short short8;   // 8 x bf16 (MFMA frag)
typedef __attribute__((ext_vector_type(4))) float f32x4;    // MFMA accumulator
typedef unsigned short u16;
typedef unsigned int u32;

__device__ __forceinline__ float bf2f(u16 h) { return __uint_as_float(((u32)h) << 16); }
__device__ __forceinline__ u16 f2bf(float f) {
  u32 u = __float_as_uint(f);
  u += 0x7fffu + ((u >> 16) & 1u);   // round-to-nearest-even
  return (u16)(u >> 16);
}
__device__ __forceinline__ float lrelu(float v) { return fmaxf(v, 0.2f * v); }
__device__ __forceinline__ float ldany(int f32mode, const void* p, int i) {
  return f32mode ? ((const float*)p)[i] : bf2f(((const u16*)p)[i]);
}

// ---------------- dtype detector ----------------------------------------------------
__global__ __launch_bounds__(256) void k_detect(const u16* emb, int* flag) {
  bool big = false;
  for (int i = blockIdx.x * 256 + threadIdx.x; i < 131072; i += 256 * 64) {
    float v = bf2f(emb[i]);
    big |= !(fabsf(v) <= 1e6f);
  }
  unsigned long long m = __ballot(big);
  if (m && (threadIdx.x & 63) == 0) atomicOr(flag, 1);
}

// ---------------- small-vector ingest -> canonical f32 ------------------------------
struct VD { const void* src; int dst, n; };
struct VArgs { VD v[16]; };
__global__ __launch_bounds__(256) void k_vec(VArgs a, const int* flag, float* out) {
  int f = *flag;
  VD d = a.v[blockIdx.x];
  for (int i = threadIdx.x; i < d.n; i += 256)
    out[d.dst + i] = ldany(f, d.src, i);
}

// ---------------- big-matrix ingest -> canonical f32 --------------------------------
struct CArgs { const void* src[7]; float* dst[7]; int n[7]; };
__global__ __launch_bounds__(256) void k_cvt(CArgs a, const int* flag) {
  int f = *flag;
  int e = blockIdx.y;
  const void* s = a.src[e];
  float* d = a.dst[e];
  int n = a.n[e];
  for (int i = blockIdx.x * 256 + threadIdx.x; i < n; i += 2048 * 256)
    d[i] = ldany(f, s, i);
}

// ---------------- ef_w2 f32 [512][128] -> bf16 MFMA-fragment-linear -----------------
__global__ __launch_bounds__(256) void k_w2tb(const float* efw2f, u16* w2fr) {
  int idx = blockIdx.x * 256 + threadIdx.x;   // 65536
  int e = idx & 7, l = (idx >> 3) & 63, nt = (idx >> 9) & 7, kc = idx >> 12;
  int n = nt * 16 + (l & 15);
  int c = kc * 32 + ((l >> 4) << 3) + e;
  w2fr[idx] = f2bf(efw2f[c * 128 + n]);
}

// ---------------- V rows -> f32 MFMA-fragment-linear --------------------------------
__global__ __launch_bounds__(256) void k_vfr(const float* uvf, float* vfrag) {
  const float* V = uvf + 393216;
  int idx = blockIdx.x * 256 + threadIdx.x;   // grid 512 -> 131072
  int e = idx & 7, l = (idx >> 3) & 63, kc = (idx >> 9) & 15, jb = idx >> 13;
  int j = jb * 16 + (l & 15);
  int c = kc * 32 + ((l >> 4) << 3) + e;
  vfrag[idx] = V[j * 512 + c];
}

// ---------------- epW1 [k][col] -> wt[arr][col][k] (LDS-tiled transpose) ------------
// grid (8, 8, 2): x = 64-wide k tile, y = 64-wide col tile, z = arr.
__global__ __launch_bounds__(256) void k_wt(const float* epw1f, float* wt) {
  __shared__ float T[64][65];
  int tid = threadIdx.x;
  int k0 = blockIdx.x * 64, c0 = blockIdx.y * 64;
  const float* src = epw1f + blockIdx.z * 262144;
  float* dst = wt + blockIdx.z * 262144;
  int cl = tid & 63, rw = tid >> 6;
#pragma unroll
  for (int rr = 0; rr < 16; ++rr) {
    int r = rr * 4 + rw;                      // k offset in tile
    T[r][cl] = src[(k0 + r) * 512 + c0 + cl];
  }
  __syncthreads();
#pragma unroll
  for (int rr = 0; rr < 16; ++rr) {
    int r = rr * 4 + rw;                      // col offset in tile
    dst[(c0 + r) * 512 + k0 + cl] = T[cl][r]; // stride-65 read: conflict-free
  }
}

// ---------------- GAT W[l] -> fragment-linear interleaved bf16 hi/lo ----------------
__global__ __launch_bounds__(256) void k_wfr(const float* Wf, u16* wfr) {
  int idx = blockIdx.x * 256 + threadIdx.x;   // 131072
  int lane = idx & 63, kc = (idx >> 6) & 15, nt = idx >> 10;
  int n = nt * 16 + (lane & 15);
  int c0 = kc * 32 + ((lane >> 4) << 3);
  u16* dst = wfr + idx * 16;
#pragma unroll
  for (int e = 0; e < 8; ++e) {
    float v = Wf[(c0 + e) * 2048 + n];
    u16 hi = f2bf(v);
    dst[e] = hi;
    dst[8 + e] = f2bf(v - bf2f(hi));
  }
}

// ---------------- ef W1 ([512][512] x2 halves) -> frag-linear hi/lo, N=1024 ---------
__global__ __launch_bounds__(256) void k_wfr_ef(const float* efw1f, u16* wfr) {
  int idx = blockIdx.x * 256 + threadIdx.x;   // 65536
  int lane = idx & 63, kc = (idx >> 6) & 15, nt = idx >> 10;   // nt in [0,64)
  int n = nt * 16 + (lane & 15);              // [0,1024)
  int c0 = kc * 32 + ((lane >> 4) << 3);
  const float* base = (n < 512) ? (efw1f + n) : (efw1f + 262144 + n - 512);
  u16* dst = wfr + idx * 16;
#pragma unroll
  for (int e = 0; e < 8; ++e) {
    float v = base[(c0 + e) * 512];
    u16 hi = f2bf(v);
    dst[e] = hi;
    dst[8 + e] = f2bf(v - bf2f(hi));
  }
}

// ---------------- W [512][512] -> frag-linear interleaved bf16 hi/lo, N=512 ---------
__global__ __launch_bounds__(256) void k_wop(const float* Wf, u16* wop) {
  int idx = blockIdx.x * 256 + threadIdx.x;   // grid 128 -> 32768
  int lane = idx & 63, kc = (idx >> 6) & 15, nt = idx >> 10;   // nt in [0,32)
  int n = nt * 16 + (lane & 15);              // [0,512)
  int c0 = kc * 32 + ((lane >> 4) << 3);
  u16* dst = wop + idx * 16;
#pragma unroll
  for (int e = 0; e < 8; ++e) {
    float v = Wf[(c0 + e) * 512 + n];
    u16 hi = f2bf(v);
    dst[e] = hi;
    dst[8 + e] = f2bf(v - bf2f(hi));
  }
}

// ---------------- x -> fragment-linear interleaved bf16 hi/lo -----------------------
__global__ __launch_bounds__(256) void k_xb(const float* x, u16* xfr) {
  int idx = blockIdx.x * 256 + threadIdx.x;   // 16384
  int lane = idx & 63, kc = (idx >> 6) & 15, it = idx >> 10;
  int i = it * 16 + (lane & 15);
  int c0 = kc * 32 + ((lane >> 4) << 3);
  const float* src = x + i * 512 + c0;
  float4 v0 = *(const float4*)(src);
  float4 v1 = *(const float4*)(src + 4);
  float vv[8] = {v0.x, v0.y, v0.z, v0.w, v1.x, v1.y, v1.z, v1.w};
  u16* dst = xfr + idx * 16;
#pragma unroll
  for (int e = 0; e < 8; ++e) {
    u16 hi = f2bf(vv[e]);
    dst[e] = hi;
    dst[8 + e] = f2bf(vv[e] - bf2f(hi));
  }
}

// ---------------- GAT s = x @ W[l] as MFMA (hi/lo 3-product) ------------------------
__global__ __launch_bounds__(256) void k_sm(const u16* xfr, const u16* wfr, float* sf) {
  int tid = threadIdx.x, lane = tid & 63, w = tid >> 6;
  int n0 = blockIdx.x * 32 + (w & 1) * 16;     // grid.x = 64
  int i0 = blockIdx.y * 32 + (w >> 1) * 16;    // grid.y = 8
  int it = i0 >> 4, nt = n0 >> 4;
  const u16* ap = xfr + (it * 16) * 1024 + lane * 16;
  const u16* bp = wfr + (nt * 16) * 1024 + lane * 16;
  f32x4 acc = (f32x4){0.f, 0.f, 0.f, 0.f};
#pragma unroll
  for (int kc = 0; kc < 16; ++kc) {
    short8 ah = *(const short8*)(ap + kc * 1024);
    short8 al = *(const short8*)(ap + kc * 1024 + 8);
    short8 bh = *(const short8*)(bp + kc * 1024);
    short8 bl = *(const short8*)(bp + kc * 1024 + 8);
    acc = __builtin_amdgcn_mfma_f32_16x16x32_bf16(ah, bh, acc, 0, 0, 0);
    acc = __builtin_amdgcn_mfma_f32_16x16x32_bf16(ah, bl, acc, 0, 0, 0);
    acc = __builtin_amdgcn_mfma_f32_16x16x32_bf16(al, bh, acc, 0, 0, 0);
  }
  int col = n0 + (lane & 15);
#pragma unroll
  for (int r = 0; r < 4; ++r) {
    int row = i0 + (lane >> 4) * 4 + r;
    sf[row * 2048 + col] = acc[r];
  }
}

// ---------------- generic 256x512 @ K=512 MFMA linear + bias (k_op/k_op2) -----------
__global__ __launch_bounds__(256) void k_opm(const u16* xfr, const u16* wop,
    const float* bias, float* out) {
  int tid = threadIdx.x, lane = tid & 63, w = tid >> 6;
  int n0 = blockIdx.x * 32 + (w & 1) * 16;     // grid.x = 16
  int i0 = blockIdx.y * 32 + (w >> 1) * 16;    // grid.y = 8
  int it = i0 >> 4, nt = n0 >> 4;
  const u16* ap = xfr + (it * 16) * 1024 + lane * 16;
  const u16* bp = wop + (nt * 16) * 1024 + lane * 16;
  f32x4 acc = (f32x4){0.f, 0.f, 0.f, 0.f};
#pragma unroll
  for (int kc = 0; kc < 16; ++kc) {
    short8 ah = *(const short8*)(ap + kc * 1024);
    short8 al = *(const short8*)(ap + kc * 1024 + 8);
    short8 bh = *(const short8*)(bp + kc * 1024);
    short8 bl = *(const short8*)(bp + kc * 1024 + 8);
    acc = __builtin_amdgcn_mfma_f32_16x16x32_bf16(ah, bh, acc, 0, 0, 0);
    acc = __builtin_amdgcn_mfma_f32_16x16x32_bf16(ah, bl, acc, 0, 0, 0);
    acc = __builtin_amdgcn_mfma_f32_16x16x32_bf16(al, bh, acc, 0, 0, 0);
  }
  int col = n0 + (lane & 15);
  float b = bias[col];
#pragma unroll
  for (int r = 0; r < 4; ++r) {
    int row = i0 + (lane >> 4) * 4 + r;
    out[row * 512 + col] = acc[r] + b;
  }
}

// ---------------- U/V_ef = emb @ efW1 as MFMA (hi/lo 3-product) ---------------------
__global__ __launch_bounds__(256) void k_uvef(const u16* xfr, const u16* wfr,
    const float* vecf, float* uvf) {
  int tid = threadIdx.x, lane = tid & 63, w = tid >> 6;
  int n0 = blockIdx.x * 32 + (w & 1) * 16;     // grid.x = 32
  int i0 = blockIdx.y * 32 + (w >> 1) * 16;    // grid.y = 8
  int it = i0 >> 4, nt = n0 >> 4;
  const u16* ap = xfr + (it * 16) * 1024 + lane * 16;
  const u16* bp = wfr + (nt * 16) * 1024 + lane * 16;
  f32x4 acc = (f32x4){0.f, 0.f, 0.f, 0.f};
#pragma unroll
  for (int kc = 0; kc < 16; ++kc) {
    short8 ah = *(const short8*)(ap + kc * 1024);
    short8 al = *(const short8*)(ap + kc * 1024 + 8);
    short8 bh = *(const short8*)(bp + kc * 1024);
    short8 bl = *(const short8*)(bp + kc * 1024 + 8);
    acc = __builtin_amdgcn_mfma_f32_16x16x32_bf16(ah, bh, acc, 0, 0, 0);
    acc = __builtin_amdgcn_mfma_f32_16x16x32_bf16(ah, bl, acc, 0, 0, 0);
    acc = __builtin_amdgcn_mfma_f32_16x16x32_bf16(al, bh, acc, 0, 0, 0);
  }
  int col = n0 + (lane & 15);
  float bias = (col >= 512) ? vecf[2064 + col - 512] : 0.f;
  float* outb = (col < 512) ? (uvf + 262144 + col) : (uvf + 393216 + col - 512);
#pragma unroll
  for (int r = 0; r < 4; ++r) {
    int row = i0 + (lane >> 4) * 4 + r;
    outb[row * 512] = acc[r] + bias;
  }
}

// ---------------- U/V_ep = emb @ epW1 halves, f64; W via transposed wt --------------
// grid (2, 64, 2). Same f64 accumulation expressions & k-order as r17/r19
// (bit-identical uvf_ep); only the W load addresses changed (contiguous float4
// from wt[arr][col][k] -> 128 load instrs/thread instead of 512 strided).
__global__ __launch_bounds__(256) void k_uv(const float* embf, const float* wt,
    const float* vecf, float* uvf) {
  int tid = threadIdx.x;
  int col = blockIdx.x * 256 + tid;
  int r0 = blockIdx.y * 4;
  int arr = blockIdx.z;
  const float* Wc = wt + arr * 262144 + col * 512;
  const float* e = embf + r0 * 512;
  float bias = (arr == 1) ? vecf[col] : 0.f;
  float* outp = uvf + arr * 131072 + r0 * 512 + col;
  double a0 = 0.0, a1 = 0.0, a2 = 0.0, a3 = 0.0;
  for (int k = 0; k < 512; k += 4) {
    float4 wv = *(const float4*)(Wc + k);
    double w0 = (double)wv.x, w1 = (double)wv.y;
    double w2 = (double)wv.z, w3 = (double)wv.w;
    float2 e0 = *(const float2*)(e + k);
    float2 e1 = *(const float2*)(e + 512 + k);
    float2 e2 = *(const float2*)(e + 1024 + k);
    float2 e3 = *(const float2*)(e + 1536 + k);
    a0 += (double)e0.x * w0 + (double)e0.y * w1;
    a1 += (double)e1.x * w0 + (double)e1.y * w1;
    a2 += (double)e2.x * w0 + (double)e2.y * w1;
    a3 += (double)e3.x * w0 + (double)e3.y * w1;
    float2 f0 = *(const float2*)(e + k + 2);
    float2 f1 = *(const float2*)(e + 512 + k + 2);
    float2 f2 = *(const float2*)(e + 1024 + k + 2);
    float2 f3 = *(const float2*)(e + 1536 + k + 2);
    a0 += (double)f0.x * w2 + (double)f0.y * w3;
    a1 += (double)f1.x * w2 + (double)f1.y * w3;
    a2 += (double)f2.x * w2 + (double)f2.y * w3;
    a3 += (double)f3.x * w2 + (double)f3.y * w3;
  }
  outp[0]    = (float)(a0 + (double)bias);
  outp[512]  = (float)(a1 + (double)bias);
  outp[1024] = (float)(a2 + (double)bias);
  outp[1536] = (float)(a3 + (double)bias);
}

// ---------------- f64 row sums / sums-of-squares ------------------------------------
__global__ __launch_bounds__(64) void k_stats64(const float* uvf, double* sums, double* sumsq) {
  int bid = blockIdx.x;           // arr*256 + row
  int lane = threadIdx.x;
  const float* p = uvf + bid * 512;
  double s = 0.0, s2 = 0.0;
  for (int q = lane; q < 512; q += 64) { double v = p[q]; s += v; s2 += v * v; }
#pragma unroll
  for (int m = 1; m < 64; m <<= 1) { s += __shfl_xor(s, m, 64); s2 += __shfl_xor(s2, m, 64); }
  if (lane == 0) { sums[bid] = s; sumsq[bid] = s2; }
}

// ---------------- cross[i][j] = U_i . V_j (f64): z=0 -> ep, z=1 -> ef ---------------
__global__ __launch_bounds__(256) void k_cross(const float* uvf, double* crossep,
                                               double* crossef) {
  __shared__ float Uc[16][132], Vc[16][132];
  int z = blockIdx.z;
  const float* U = uvf + z * 262144;
  const float* V = U + 131072;
  double* out = z ? crossef : crossep;
  int tid = threadIdx.x, ti = tid & 15, tj = tid >> 4;
  int i0 = blockIdx.y * 16, j0 = blockIdx.x * 16;
  double acc = 0.0;
  for (int c0 = 0; c0 < 512; c0 += 128) {
    __syncthreads();
    for (int idx = tid; idx < 2048; idx += 256) {
      int r = idx >> 7, c = idx & 127;
      Uc[r][c] = U[(i0 + r) * 512 + c0 + c];
      Vc[r][c] = V[(j0 + r) * 512 + c0 + c];
    }
    __syncthreads();
#pragma unroll
    for (int c4 = 0; c4 < 128; c4 += 4) {
      float4 uu = *(const float4*)&Uc[ti][c4];
      float4 vv = *(const float4*)&Vc[tj][c4];
      float p = fmaf(uu.x, vv.x, fmaf(uu.y, vv.y, fmaf(uu.z, vv.z, uu.w * vv.w)));
      acc += (double)p;
    }
  }
  out[(i0 + ti) * 256 + j0 + tj] = acc;
}

// ---------------- edge predictor, stats-based tiled (1 thread / pair) ---------------
__global__ __launch_bounds__(256) void k_ep_t(const float* uvf, const double* sums,
    const double* sumsq, const double* crossep, const float* vecf,
    float* act, float* maskv) {
  __shared__ float Uc[16][132], Vc[16][132];
  int tid = threadIdx.x, ti = tid & 15, tj = tid >> 4;
  int i0 = blockIdx.y * 16, j0 = blockIdx.x * 16;
  int i = i0 + ti, j = j0 + tj;
  double md = (sums[i] + sums[256 + j]) * (1.0 / 512.0);
  double qd = (sumsq[i] + 2.0 * crossep[i * 256 + j] + sumsq[256 + j]) * (1.0 / 512.0);
  float iv = (float)(1.0 / sqrt(qd - md * md + 1e-5));
  float bb = (float)(-md) * iv;
  const float* U = uvf;
  const float* V = uvf + 131072;
  const float* g_ = vecf + 512;
  const float* be_ = vecf + 1024;
  const float* w2_ = vecf + 1536;
  double acc = 0.0;
  for (int c0 = 0; c0 < 512; c0 += 128) {
    __syncthreads();
    for (int idx = tid; idx < 2048; idx += 256) {
      int r = idx >> 7, c = idx & 127;
      Uc[r][c] = U[(i0 + r) * 512 + c0 + c];
      Vc[r][c] = V[(j0 + r) * 512 + c0 + c];
    }
    __syncthreads();
#pragma unroll
    for (int c4 = 0; c4 < 128; c4 += 4) {
      float4 uu = *(const float4*)&Uc[ti][c4];
      float4 vv = *(const float4*)&Vc[tj][c4];
      float4 gg = *(const float4*)(g_ + c0 + c4);
      float4 b4 = *(const float4*)(be_ + c0 + c4);
      float4 w4 = *(const float4*)(w2_ + c0 + c4);
      float z, s4 = 0.f;
      z = fmaf(fmaf(uu.x + vv.x, iv, bb), gg.x, b4.x); s4 = fmaf(lrelu(z), w4.x, s4);
      z = fmaf(fmaf(uu.y + vv.y, iv, bb), gg.y, b4.y); s4 = fmaf(lrelu(z), w4.y, s4);
      z = fmaf(fmaf(uu.z + vv.z, iv, bb), gg.z, b4.z); s4 = fmaf(lrelu(z), w4.z, s4);
      z = fmaf(fmaf(uu.w + vv.w, iv, bb), gg.w, b4.w); s4 = fmaf(lrelu(z), w4.w, s4);
      acc += (double)s4;
    }
  }
  double logit = acc + (double)vecf[2048];
  bool a = (logit > 0.0) && (i != j);
  act[i * 256 + j] = a ? 1.0f : 0.0f;
  maskv[j * 256 + i] = (a || i == j) ? 0.f : -1e9f;         // adj[dst][src] mask
}

// ---------------- edge features: all-LDS inner loop + bf16 MFMA (r15, validated) ----
__global__ __launch_bounds__(512, 2) void k_ef(const float* uvf, const double* sums,
    const double* sumsq, const double* crossef, const float* vecf,
    const u16* w2fr, const float* vfrag, float* ef_f) {
  __shared__ u16 w2S[16384];                 // 32 KB: 4 kc x 8 nt x 512
  __shared__ float vS0[4096], vS1[4096];     // 16+16 KB
  __shared__ float uS[8192];                 // 32 KB: 16 rows x 512
  __shared__ float gS[512], beS[512];        // 4 KB
  int tid = threadIdx.x;
  int lane = tid & 63, w = tid >> 6;         // w 0..7
  int bx = blockIdx.x;
  int bi = bx >> 4, bj = bx & 15;
  int i0 = bi * 16;
  int iA = i0 + w * 2, iB = iA + 1;
  int l15 = lane & 15;
  int j = bj * 16 + l15;
  int ksl = (lane >> 4) * 8;

  double sj = sums[768 + j], s2j = sumsq[768 + j];
  double mA = (sums[512 + iA] + sj) * (1.0 / 512.0);
  double qA = (sumsq[512 + iA] + 2.0 * crossef[iA * 256 + j] + s2j) * (1.0 / 512.0);
  float ivA = (float)(1.0 / sqrt(qA - mA * mA + 1e-5));
  float bbA = (float)(-mA) * ivA;
  double mB = (sums[512 + iB] + sj) * (1.0 / 512.0);
  double qB = (sumsq[512 + iB] + 2.0 * crossef[iB * 256 + j] + s2j) * (1.0 / 512.0);
  float ivB = (float)(1.0 / sqrt(qB - mB * mB + 1e-5));
  float bbB = (float)(-mB) * ivB;

  const float* Vg = vfrag + bj * 8192;
  for (int q = tid; q < 2048; q += 512) {
    float4 v = *(const float4*)(Vg + q * 4);
    int kc = q >> 7, r = q & 127, ln = r >> 1;
    if (r & 1) *(float4*)(vS1 + kc * 256 + ln * 4) = v;
    else       *(float4*)(vS0 + kc * 256 + ln * 4) = v;
  }
  const float* Ug = uvf + 262144 + i0 * 512;
  for (int q = tid; q < 2048; q += 512)
    *(float4*)(uS + q * 4) = *(const float4*)(Ug + q * 4);
  if (tid < 128)      *(float4*)(gS + tid * 4)  = *(const float4*)(vecf + 2576 + tid * 4);
  else if (tid < 256) *(float4*)(beS + (tid - 128) * 4) = *(const float4*)(vecf + 3088 + (tid - 128) * 4);

  f32x4 acc[2][8];
#pragma unroll
  for (int ai = 0; ai < 2; ++ai)
#pragma unroll
    for (int bq = 0; bq < 8; ++bq) acc[ai][bq] = (f32x4){0.f, 0.f, 0.f, 0.f};

  auto H8 = [&](float4 u0, float4 u1, float4 v0, float4 v1, float4 g0, float4 g1,
                float4 e0, float4 e1, float iv, float bb) -> short8 {
    short8 a; float z;
    z = fmaf(u0.x + v0.x, iv, bb); z = fmaf(z, g0.x, e0.x); a[0] = (short)f2bf(lrelu(z));
    z = fmaf(u0.y + v0.y, iv, bb); z = fmaf(z, g0.y, e0.y); a[1] = (short)f2bf(lrelu(z));
    z = fmaf(u0.z + v0.z, iv, bb); z = fmaf(z, g0.z, e0.z); a[2] = (short)f2bf(lrelu(z));
    z = fmaf(u0.w + v0.w, iv, bb); z = fmaf(z, g0.w, e0.w); a[3] = (short)f2bf(lrelu(z));
    z = fmaf(u1.x + v1.x, iv, bb); z = fmaf(z, g1.x, e1.x); a[4] = (short)f2bf(lrelu(z));
    z = fmaf(u1.y + v1.y, iv, bb); z = fmaf(z, g1.y, e1.y); a[5] = (short)f2bf(lrelu(z));
    z = fmaf(u1.z + v1.z, iv, bb); z = fmaf(z, g1.z, e1.z); a[6] = (short)f2bf(lrelu(z));
    z = fmaf(u1.w + v1.w, iv, bb); z = fmaf(z, g1.w, e1.w); a[7] = (short)f2bf(lrelu(z));
    return a;
  };

  const float* uA = uS + (w * 2) * 512;
  const float* uB = uA + 512;

  for (int kq = 0; kq < 4; ++kq) {
    __syncthreads();
    const short8* src = (const short8*)(w2fr + kq * 16384);
    for (int q = tid; q < 2048; q += 512)
      *(short8*)(w2S + q * 8) = src[q];
    __syncthreads();
#pragma unroll
    for (int kk = 0; kk < 4; ++kk) {
      int kc = kq * 4 + kk;
      int k0 = kc * 32 + ksl;
      float4 u0 = *(const float4*)(uA + k0);
      float4 u1 = *(const float4*)(uA + k0 + 4);
      float4 b0 = *(const float4*)(uB + k0);
      float4 b1 = *(const float4*)(uB + k0 + 4);
      float4 v0 = *(const float4*)(vS0 + kc * 256 + lane * 4);
      float4 v1 = *(const float4*)(vS1 + kc * 256 + lane * 4);
      float4 g0 = *(const float4*)(gS + k0);
      float4 g1 = *(const float4*)(gS + k0 + 4);
      float4 e0 = *(const float4*)(beS + k0);
      float4 e1 = *(const float4*)(beS + k0 + 4);
      short8 aA = H8(u0, u1, v0, v1, g0, g1, e0, e1, ivA, bbA);
      short8 aB = H8(b0, b1, v0, v1, g0, g1, e0, e1, ivB, bbB);
#pragma unroll
      for (int nt = 0; nt < 8; ++nt) {
        short8 bv = *(const short8*)(w2S + kk * 4096 + nt * 512 + lane * 8);
        acc[0][nt] = __builtin_amdgcn_mfma_f32_16x16x32_bf16(aA, bv, acc[0][nt], 0, 0, 0);
        acc[1][nt] = __builtin_amdgcn_mfma_f32_16x16x32_bf16(aB, bv, acc[1][nt], 0, 0, 0);
      }
    }
  }
#pragma unroll
  for (int mi = 0; mi < 2; ++mi) {
    int ii = mi ? iB : iA;
#pragma unroll
    for (int nt = 0; nt < 8; ++nt) {
      int n = nt * 16 + l15;
      float bias = vecf[3600 + n];
#pragma unroll
      for (int r = 0; r < 4; ++r) {
        int row = (lane >> 4) * 4 + r;
        ef_f[(ii * 256 + bj * 16 + row) * 128 + n] = acc[mi][nt][r] + bias;
      }
    }
  }
}

// ---------------- naive a_src/a_dst dots (block per (n,h)) --------------------------
__global__ __launch_bounds__(64) void k_ad(const float* sf, const float* vecf, int l,
                                           float* asf, float* adf) {
  int b = blockIdx.x;            // n*4+h
  int n = b >> 2, h = b & 3;
  int lane = threadIdx.x;
  const float* s = sf + n * 2048 + h * 512;
  const float* as_ = vecf + 3728 + l * 2048 + h * 512;
  const float* ad_ = vecf + 9872 + l * 2048 + h * 512;
  float sa = 0.f, sd = 0.f;
  for (int c = lane; c < 512; c += 64) { sa = fmaf(s[c], as_[c], sa); sd = fmaf(s[c], ad_[c], sd); }
#pragma unroll
  for (int m = 1; m < 64; m <<= 1) { sa += __shfl_xor(sa, m, 64); sd += __shfl_xor(sd, m, 64); }
  if (lane == 0) { asf[b] = sa; adf[b] = sd; }
}

// ---------------- GAT attention softmax -> alpha bf16 hi/lo [dst][h*256+src] --------
__global__ __launch_bounds__(256) void k_alpha(const float* asf, const float* adf,
    const float* maskv, u16* a_hib, u16* a_lob) {
  int dd = blockIdx.x, s = threadIdx.x;
  int lane = s & 63, w = s >> 6;
  __shared__ float wr[2][4][4];
  float mk = maskv[dd * 256 + s];
  float lg[4];
#pragma unroll
  for (int h = 0; h < 4; ++h) {
    float v = adf[dd * 4 + h] + asf[s * 4 + h];
    lg[h] = lrelu(v) + mk;
  }
#pragma unroll
  for (int h = 0; h < 4; ++h) {
    float v = lg[h];
#pragma unroll
    for (int m = 1; m < 64; m <<= 1) v = fmaxf(v, __shfl_xor(v, m, 64));
    if (lane == 0) wr[0][h][w] = v;
  }
  __syncthreads();
  float e[4];
#pragma unroll
  for (int h = 0; h < 4; ++h) {
    float mx = fmaxf(fmaxf(wr[0][h][0], wr[0][h][1]), fmaxf(wr[0][h][2], wr[0][h][3]));
    float v = __expf(lg[h] - mx);
    e[h] = v;
#pragma unroll
    for (int m = 1; m < 64; m <<= 1) v += __shfl_xor(v, m, 64);
    if (lane == 0) wr[1][h][w] = v;
  }
  __syncthreads();
#pragma unroll
  for (int h = 0; h < 4; ++h) {
    float sm = wr[1][h][0] + wr[1][h][1] + wr[1][h][2] + wr[1][h][3];
    float v = e[h] / sm;
    u16 hi = f2bf(v);
    int o = dd * 1024 + h * 256 + s;
    a_hib[o] = hi;
    a_lob[o] = f2bf(v - bf2f(hi));    // v-hi exact in f32
  }
}

// ---------------- s transpose -> sT bf16 hi/lo: sT[c][h*256+n] = s[n][h*512+c] ------
__global__ __launch_bounds__(256) void k_st(const float* sf, u16* sT_hi, u16* sT_lo) {
  __shared__ float T[64][65];
  int tid = threadIdx.x;
  int hc0 = blockIdx.x * 64;
  int n0 = blockIdx.y * 64;
  int h = hc0 >> 9, c0 = hc0 & 511, q0 = h * 256 + n0;
  int cl = tid & 63, rw = tid >> 6;
#pragma unroll
  for (int rr = 0; rr < 16; ++rr) {
    int r = rr * 4 + rw;
    T[r][cl] = sf[(n0 + r) * 2048 + hc0 + cl];
  }
  __syncthreads();
#pragma unroll
  for (int rr = 0; rr < 16; ++rr) {
    int r = rr * 4 + rw;              // c-offset within tile
    float v = T[cl][r];               // stride-65 read: conflict-free
    u16 hi = f2bf(v);
    int o = (c0 + r) * 1024 + q0 + cl;
    sT_hi[o] = hi;
    sT_lo[o] = f2bf(v - bf2f(hi));
  }
}

// ---------------- aggregation as MFMA GEMM: x[i][c] = lrelu(0.25*A.B + b) -----------
__global__ __launch_bounds__(256) void k_aggm(const u16* a_hi, const u16* a_lo,
    const u16* sT_hi, const u16* sT_lo, const float* vecf, int l, float* xout) {
  int tid = threadIdx.x, lane = tid & 63, w = tid >> 6;
  int c0 = blockIdx.x * 32 + (w & 1) * 16;     // grid.x = 16
  int i0 = blockIdx.y * 32 + (w >> 1) * 16;    // grid.y = 8
  int kb = (lane >> 4) * 8;
  int ar = (i0 + (lane & 15)) * 1024 + kb;
  int br = (c0 + (lane & 15)) * 1024 + kb;
  f32x4 acc = (f32x4){0.f, 0.f, 0.f, 0.f};
#pragma unroll 4
  for (int k0 = 0; k0 < 1024; k0 += 32) {
    short8 ah = *(const short8*)(a_hi + ar + k0);
    short8 al = *(const short8*)(a_lo + ar + k0);
    short8 bh = *(const short8*)(sT_hi + br + k0);
    short8 bl = *(const short8*)(sT_lo + br + k0);
    acc = __builtin_amdgcn_mfma_f32_16x16x32_bf16(ah, bh, acc, 0, 0, 0);
    acc = __builtin_amdgcn_mfma_f32_16x16x32_bf16(ah, bl, acc, 0, 0, 0);
    acc = __builtin_amdgcn_mfma_f32_16x16x32_bf16(al, bh, acc, 0, 0, 0);
  }
  int c = c0 + (lane & 15);
  float b = vecf[16016 + l * 512 + c];
#pragma unroll
  for (int r = 0; r < 4; ++r) {
    int i = i0 + (lane >> 4) * 4 + r;
    xout[i * 512 + c] = lrelu(fmaf(acc[r], 0.25f, b));
  }
}

// ---------------- output-proj LayerNorm + leaky -> f32 ------------------------------
__global__ __launch_bounds__(256) void k_ln(const float* t1, const float* vecf, float* h1f) {
  const float* g_ = vecf + 18064;
  const float* be_ = vecf + 18576;
  int row = blockIdx.x, tid = threadIdx.x, lane = tid & 63, w = tid >> 6;
  __shared__ float wr[2][4];
  float v0 = t1[row * 512 + tid];
  float v1 = t1[row * 512 + 256 + tid];
  float s = v0 + v1, s2 = fmaf(v0, v0, v1 * v1);
#pragma unroll
  for (int m = 1; m < 64; m <<= 1) { s += __shfl_xor(s, m, 64); s2 += __shfl_xor(s2, m, 64); }
  if (lane == 0) { wr[0][w] = s; wr[1][w] = s2; }
  __syncthreads();
  s = wr[0][0] + wr[0][1] + wr[0][2] + wr[0][3];
  s2 = wr[1][0] + wr[1][1] + wr[1][2] + wr[1][3];
  float m = s * (1.f / 512.f);
  float var = fmaxf(s2 * (1.f / 512.f) - m * m, 0.f);
  float iv = 1.f / sqrtf(var + 1e-5f);
  float z0 = (v0 - m) * iv * g_[tid] + be_[tid];
  float z1 = (v1 - m) * iv * g_[tid + 256] + be_[tid + 256];
  h1f[row * 512 + tid] = lrelu(z0);
  h1f[row * 512 + 256 + tid] = lrelu(z1);
}

extern "C" void kernel_launch(void* const* d_in, const int* in_sizes, int n_in,
                              void* d_out, int out_size, void* d_ws, size_t ws_size,
                              hipStream_t stream) {
  (void)out_size;
  static const int dictT[23] = {0,1,2,3,4,5,6,7,8,9,10,11,12,13,14,15,16,17,18,19,20,21,22};
  static const int alphaT[23] = {6,11,7,10,9,12,8,4,0,3,2,5,1,13,15,14,16,21,17,20,19,22,18};
  const int* tbl = (n_in == 23 && in_sizes[0] == 512) ? alphaT : dictT;
  auto IN = [&](int role) -> const void* { return d_in[tbl[role]]; };

  float* out_f = (float*)d_out;                    // [256,512] f32
  float* act_f = out_f + 256 * 512;                // [256,256] f32 0/1
  float* ef_f  = out_f + 256 * 512 + 256 * 256;    // [256,256,128] f32

  char* cur = (char*)d_ws;
  auto alloc = [&](size_t bytes) -> void* {
    void* r = (void*)cur;
    cur += (bytes + 255) & ~(size_t)255;
    return r;
  };
  float* vecf    = (float*)alloc(20480 * 4);
  float* embf    = (float*)alloc(131072 * 4);
  float* epw1f   = (float*)alloc(524288 * 4);
  float* efw1f   = (float*)alloc(524288 * 4);
  float* gatWf   = (float*)alloc(3145728 * 4);
  float* opw1f   = (float*)alloc(262144 * 4);
  float* opw2f   = (float*)alloc(262144 * 4);
  float* efw2f   = (float*)alloc(65536 * 4);
  float* uvf     = (float*)alloc(524288 * 4);
  float* sf      = (float*)alloc(524288 * 4);
  float* asf     = (float*)alloc(1024 * 4);
  float* adf     = (float*)alloc(1024 * 4);
  float* xf      = (float*)alloc(262144 * 4);
  float* t1      = (float*)alloc(131072 * 4);
  float* h1f     = (float*)alloc(131072 * 4);
  float* maskv   = (float*)alloc(65536 * 4);
  double* sums   = (double*)alloc(1024 * 8);
  double* sumsq  = (double*)alloc(1024 * 8);
  double* crossep = (double*)alloc(65536 * 8);
  double* crossef = (double*)alloc(65536 * 8);
  u16* w2tb      = (u16*)alloc(65536 * 2);
  float* vfrag   = (float*)alloc(131072 * 4);
  u16* wfrb      = (u16*)alloc(2097152 * 2);   // W frag-linear hi/lo (4MB; also ef-pack)
  u16* xfrb      = (u16*)alloc(262144 * 2);    // x frag-linear hi/lo (512KB)
  u16* opw1p     = (u16*)alloc(524288 * 2);    // opw1 frag-linear hi/lo (1MB)
  u16* opw2p     = (u16*)alloc(524288 * 2);    // opw2 frag-linear hi/lo (1MB)
  float* wt      = (float*)alloc(524288 * 4);  // epW1 transposed [arr][col][k] (2MB)
  int* flag      = (int*)alloc(256);
  if ((size_t)(cur - (char*)d_ws) > ws_size) return;

  // GAT-phase buffers aliased onto epw1f/efw1f (both dead after k_uv/k_uvef):
  u16* sT_hi = (u16*)epw1f;            // 512*1024 u16 = 1 MB
  u16* sT_lo = sT_hi + 524288;         // second 1 MB of epw1f's 2 MB
  u16* a_hib = (u16*)efw1f;            // 256*1024 u16 = 512 KB
  u16* a_lob = a_hib + 262144;         // next 512 KB of efw1f's 2 MB

  hipMemsetAsync(flag, 0, 256, stream);
  hipLaunchKernelGGL(k_detect, dim3(64), dim3(256), 0, stream, (const u16*)IN(0), flag);

  { // small vectors -> canonical f32
    VArgs va;
    auto setV = [&](int qi, int role, int dst, int n) { va.v[qi] = {IN(role), dst, n}; };
    setV(0, 2, 0, 512);       // ep_b1
    setV(1, 3, 512, 512);     // ep_g
    setV(2, 4, 1024, 512);    // ep_beta
    setV(3, 5, 1536, 512);    // ep_w2
    setV(4, 6, 2048, 1);      // ep_b2
    setV(5, 8, 2064, 512);    // ef_b1
    setV(6, 9, 2576, 512);    // ef_g
    setV(7, 10, 3088, 512);   // ef_beta
    setV(8, 12, 3600, 128);   // ef_b2
    setV(9, 14, 3728, 6144);  // gat_a_src
    setV(10, 15, 9872, 6144); // gat_a_dst
    setV(11, 16, 16016, 1536);// gat_b
    setV(12, 18, 17552, 512); // op_b1
    setV(13, 19, 18064, 512); // op_g
    setV(14, 20, 18576, 512); // op_beta
    setV(15, 22, 19088, 512); // op_b2
    hipLaunchKernelGGL(k_vec, dim3(16), dim3(256), 0, stream, va, (const int*)flag, vecf);
  }

  { // big matrices -> canonical f32
    CArgs ca;
    ca.src[0] = IN(0);  ca.dst[0] = embf;  ca.n[0] = 131072;
    ca.src[1] = IN(1);  ca.dst[1] = epw1f; ca.n[1] = 524288;
    ca.src[2] = IN(7);  ca.dst[2] = efw1f; ca.n[2] = 524288;
    ca.src[3] = IN(13); ca.dst[3] = gatWf; ca.n[3] = 3145728;
    ca.src[4] = IN(17); ca.dst[4] = opw1f; ca.n[4] = 262144;
    ca.src[5] = IN(21); ca.dst[5] = opw2f; ca.n[5] = 262144;
    ca.src[6] = IN(11); ca.dst[6] = efw2f; ca.n[6] = 65536;
    hipLaunchKernelGGL(k_cvt, dim3(2048, 7), dim3(256), 0, stream, ca, (const int*)flag);
  }
  hipLaunchKernelGGL(k_w2tb, dim3(256), dim3(256), 0, stream, efw2f, w2tb);
  hipLaunchKernelGGL(k_wop, dim3(128), dim3(256), 0, stream, opw1f, opw1p);
  hipLaunchKernelGGL(k_wop, dim3(128), dim3(256), 0, stream, opw2f, opw2p);
  hipLaunchKernelGGL(k_wt, dim3(8, 8, 2), dim3(256), 0, stream, epw1f, wt);

  // ef half via MFMA: pack emb + efW1, then GEMM with bias on V half.
  hipLaunchKernelGGL(k_xb, dim3(64), dim3(256), 0, stream, embf, xfrb);
  hipLaunchKernelGGL(k_wfr_ef, dim3(256), dim3(256), 0, stream, efw1f, wfrb);
  hipLaunchKernelGGL(k_uvef, dim3(32, 8), dim3(256), 0, stream, xfrb, wfrb, vecf, uvf);
  // ep half: f64 streaming on transposed W (bit-identical math, 4x shorter chain).
  hipLaunchKernelGGL(k_uv, dim3(2, 64, 2), dim3(256), 0, stream, embf, wt, vecf, uvf);

  hipLaunchKernelGGL(k_vfr, dim3(512), dim3(256), 0, stream, uvf, vfrag);
  hipLaunchKernelGGL(k_stats64, dim3(1024), dim3(64), 0, stream, uvf, sums, sumsq);
  hipLaunchKernelGGL(k_cross, dim3(16, 16, 2), dim3(256), 0, stream, uvf, crossep, crossef);

  hipLaunchKernelGGL(k_ep_t, dim3(16, 16), dim3(256), 0, stream,
                     uvf, sums, sumsq, crossep, vecf, act_f, maskv);
  hipLaunchKernelGGL(k_ef, dim3(256), dim3(512), 0, stream,
                     uvf, sums, sumsq, crossef, vecf, w2tb, vfrag, ef_f);

  const float* xsrc = embf;
  for (int l = 0; l < 3; ++l) {
    hipLaunchKernelGGL(k_wfr, dim3(512), dim3(256), 0, stream,
                       gatWf + l * 1048576, wfrb);
    hipLaunchKernelGGL(k_xb, dim3(64), dim3(256), 0, stream, xsrc, xfrb);
    hipLaunchKernelGGL(k_sm, dim3(64, 8), dim3(256), 0, stream, xfrb, wfrb, sf);
    hipLaunchKernelGGL(k_ad, dim3(1024), dim3(64), 0, stream, sf, vecf, l, asf, adf);
    hipLaunchKernelGGL(k_alpha, dim3(256), dim3(256), 0, stream, asf, adf, maskv,
                       a_hib, a_lob);
    hipLaunchKernelGGL(k_st, dim3(32, 4), dim3(256), 0, stream, sf, sT_hi, sT_lo);
    float* xdst = xf + (l & 1) * 131072;
    hipLaunchKernelGGL(k_aggm, dim3(16, 8), dim3(256), 0, stream,
                       a_hib, a_lob, sT_hi, sT_lo, vecf, l, xdst);
    xsrc = xdst;
  }

  // output projection: both linears via validated MFMA path.
  hipLaunchKernelGGL(k_xb, dim3(64), dim3(256), 0, stream, xsrc, xfrb);
  hipLaunchKernelGGL(k_opm, dim3(16, 8), dim3(256), 0, stream,
                     xfrb, opw1p, vecf + 17552, t1);
  hipLaunchKernelGGL(k_ln, dim3(256), dim3(256), 0, stream, t1, vecf, h1f);
  hipLaunchKernelGGL(k_xb, dim3(64), dim3(256), 0, stream, h1f, xfrb);
  hipLaunchKernelGGL(k_opm, dim3(16, 8), dim3(256), 0, stream,
                     xfrb, opw2p, vecf + 19088, out_f);
}

// Round 15
// 364.203 us; speedup vs baseline: 1.1749x; 1.0633x over previous
//
#include <hip/hip_runtime.h>

// NeuralAudioGraph: N=256, D=H=512, E=128, 4 heads, 3 GAT layers.
// r22: launch-count cut. r21 (epW1 transpose) banked 10us -> 387.2us; all our
// kernels are now below the harness-fill cutoff (~42us) and the stream has 42
// dispatches -> gaps/launch overhead (~2-4us each) are a first-order cost.
// Fuse independent same-stage kernels via block-range dispatch, math verbatim:
// k_pack = w2tb+wop*2+wt+wfr_ef+xb(emb) (960 blk); k_uvall = uvef+ep-uv (512);
// k_vfst = vfr+stats64(4-wave) (768); per layer k_wfrxb = wfr+xb (576) and
// k_adst = ad(4-wave)+st (384). 42 -> 29 dispatches. All reductions/expressions
// unchanged -> bit-identical outputs. Baseline r21: 387.2us, absmax 0.0078125.

typedef __attribute__((ext_vector_type(8))) short short8;   // 8 x bf16 (MFMA frag)
typedef __attribute__((ext_vector_type(4))) float f32x4;    // MFMA accumulator
typedef unsigned short u16;
typedef unsigned int u32;

__device__ __forceinline__ float bf2f(u16 h) { return __uint_as_float(((u32)h) << 16); }
__device__ __forceinline__ u16 f2bf(float f) {
  u32 u = __float_as_uint(f);
  u += 0x7fffu + ((u >> 16) & 1u);   // round-to-nearest-even
  return (u16)(u >> 16);
}
__device__ __forceinline__ float lrelu(float v) { return fmaxf(v, 0.2f * v); }
__device__ __forceinline__ float ldany(int f32mode, const void* p, int i) {
  return f32mode ? ((const float*)p)[i] : bf2f(((const u16*)p)[i]);
}

// ---------------- dtype detector ----------------------------------------------------
__global__ __launch_bounds__(256) void k_detect(const u16* emb, int* flag) {
  bool big = false;
  for (int i = blockIdx.x * 256 + threadIdx.x; i < 131072; i += 256 * 64) {
    float v = bf2f(emb[i]);
    big |= !(fabsf(v) <= 1e6f);
  }
  unsigned long long m = __ballot(big);
  if (m && (threadIdx.x & 63) == 0) atomicOr(flag, 1);
}

// ---------------- small-vector ingest -> canonical f32 ------------------------------
struct VD { const void* src; int dst, n; };
struct VArgs { VD v[16]; };
__global__ __launch_bounds__(256) void k_vec(VArgs a, const int* flag, float* out) {
  int f = *flag;
  VD d = a.v[blockIdx.x];
  for (int i = threadIdx.x; i < d.n; i += 256)
    out[d.dst + i] = ldany(f, d.src, i);
}

// ---------------- big-matrix ingest -> canonical f32 --------------------------------
struct CArgs { const void* src[7]; float* dst[7]; int n[7]; };
__global__ __launch_bounds__(256) void k_cvt(CArgs a, const int* flag) {
  int f = *flag;
  int e = blockIdx.y;
  const void* s = a.src[e];
  float* d = a.dst[e];
  int n = a.n[e];
  for (int i = blockIdx.x * 256 + threadIdx.x; i < n; i += 2048 * 256)
    d[i] = ldany(f, s, i);
}

// ---------------- fused packing: w2tb | wop x2 | wt | wfr_ef | xb(emb) --------------
// grid 960 x 256 thr. Block ranges dispatch the validated bodies verbatim.
__global__ __launch_bounds__(256) void k_pack(const float* efw2f, u16* w2fr,
    const float* opw1f, u16* opw1p, const float* opw2f, u16* opw2p,
    const float* epw1f, float* wt, const float* efw1f, u16* wfr,
    const float* embf, u16* xfr) {
  __shared__ float T[64][65];
  int b = blockIdx.x, tid = threadIdx.x;
  if (b < 256) {            // ef_w2 -> frag-linear bf16
    int idx = b * 256 + tid;
    int e = idx & 7, l = (idx >> 3) & 63, nt = (idx >> 9) & 7, kc = idx >> 12;
    int n = nt * 16 + (l & 15);
    int c = kc * 32 + ((l >> 4) << 3) + e;
    w2fr[idx] = f2bf(efw2f[c * 128 + n]);
  } else if (b < 512) {     // opw1/opw2 -> frag-linear hi/lo
    int bb = b - 256;
    const float* Wf = (bb < 128) ? opw1f : opw2f;
    u16* wop = (bb < 128) ? opw1p : opw2p;
    int idx = (bb & 127) * 256 + tid;
    int lane = idx & 63, kc = (idx >> 6) & 15, nt = idx >> 10;
    int n = nt * 16 + (lane & 15);
    int c0 = kc * 32 + ((lane >> 4) << 3);
    u16* dst = wop + idx * 16;
#pragma unroll
    for (int e = 0; e < 8; ++e) {
      float v = Wf[(c0 + e) * 512 + n];
      u16 hi = f2bf(v);
      dst[e] = hi;
      dst[8 + e] = f2bf(v - bf2f(hi));
    }
  } else if (b < 640) {     // epW1 -> wt[arr][col][k] transpose
    int q = b - 512;
    int k0 = (q & 7) * 64, c0 = ((q >> 3) & 7) * 64, z = q >> 6;
    const float* src = epw1f + z * 262144;
    float* dst = wt + z * 262144;
    int cl = tid & 63, rw = tid >> 6;
#pragma unroll
    for (int rr = 0; rr < 16; ++rr) {
      int r = rr * 4 + rw;
      T[r][cl] = src[(k0 + r) * 512 + c0 + cl];
    }
    __syncthreads();
#pragma unroll
    for (int rr = 0; rr < 16; ++rr) {
      int r = rr * 4 + rw;
      dst[(c0 + r) * 512 + k0 + cl] = T[cl][r];
    }
  } else if (b < 896) {     // efW1 (2 halves) -> frag-linear hi/lo, N=1024
    int idx = (b - 640) * 256 + tid;
    int lane = idx & 63, kc = (idx >> 6) & 15, nt = idx >> 10;
    int n = nt * 16 + (lane & 15);
    int c0 = kc * 32 + ((lane >> 4) << 3);
    const float* base = (n < 512) ? (efw1f + n) : (efw1f + 262144 + n - 512);
    u16* dst = wfr + idx * 16;
#pragma unroll
    for (int e = 0; e < 8; ++e) {
      float v = base[(c0 + e) * 512];
      u16 hi = f2bf(v);
      dst[e] = hi;
      dst[8 + e] = f2bf(v - bf2f(hi));
    }
  } else {                  // emb -> frag-linear hi/lo
    int idx = (b - 896) * 256 + tid;
    int lane = idx & 63, kc = (idx >> 6) & 15, it = idx >> 10;
    int i = it * 16 + (lane & 15);
    int c0 = kc * 32 + ((lane >> 4) << 3);
    const float* src = embf + i * 512 + c0;
    float4 v0 = *(const float4*)(src);
    float4 v1 = *(const float4*)(src + 4);
    float vv[8] = {v0.x, v0.y, v0.z, v0.w, v1.x, v1.y, v1.z, v1.w};
    u16* dst = xfr + idx * 16;
#pragma unroll
    for (int e = 0; e < 8; ++e) {
      u16 hi = f2bf(vv[e]);
      dst[e] = hi;
      dst[8 + e] = f2bf(vv[e] - bf2f(hi));
    }
  }
}

// ---------------- x -> fragment-linear interleaved bf16 hi/lo (standalone) ----------
__global__ __launch_bounds__(256) void k_xb(const float* x, u16* xfr) {
  int idx = blockIdx.x * 256 + threadIdx.x;   // 16384
  int lane = idx & 63, kc = (idx >> 6) & 15, it = idx >> 10;
  int i = it * 16 + (lane & 15);
  int c0 = kc * 32 + ((lane >> 4) << 3);
  const float* src = x + i * 512 + c0;
  float4 v0 = *(const float4*)(src);
  float4 v1 = *(const float4*)(src + 4);
  float vv[8] = {v0.x, v0.y, v0.z, v0.w, v1.x, v1.y, v1.z, v1.w};
  u16* dst = xfr + idx * 16;
#pragma unroll
  for (int e = 0; e < 8; ++e) {
    u16 hi = f2bf(vv[e]);
    dst[e] = hi;
    dst[8 + e] = f2bf(vv[e] - bf2f(hi));
  }
}

// ---------------- fused U/V: uvef (MFMA) | ep-uv (f64 on wt) ------------------------
// grid 512 x 256 thr. Bodies verbatim from r21 (bit-identical outputs).
__global__ __launch_bounds__(256) void k_uvall(const u16* xfr, const u16* wfr,
    const float* embf, const float* wt, const float* vecf, float* uvf) {
  int b = blockIdx.x, tid = threadIdx.x;
  if (b < 256) {            // ef half via MFMA hi/lo 3-product
    int lane = tid & 63, w = tid >> 6;
    int n0 = (b & 31) * 32 + (w & 1) * 16;
    int i0 = (b >> 5) * 32 + (w >> 1) * 16;
    int it = i0 >> 4, nt = n0 >> 4;
    const u16* ap = xfr + (it * 16) * 1024 + lane * 16;
    const u16* bp = wfr + (nt * 16) * 1024 + lane * 16;
    f32x4 acc = (f32x4){0.f, 0.f, 0.f, 0.f};
#pragma unroll
    for (int kc = 0; kc < 16; ++kc) {
      short8 ah = *(const short8*)(ap + kc * 1024);
      short8 al = *(const short8*)(ap + kc * 1024 + 8);
      short8 bh = *(const short8*)(bp + kc * 1024);
      short8 bl = *(const short8*)(bp + kc * 1024 + 8);
      acc = __builtin_amdgcn_mfma_f32_16x16x32_bf16(ah, bh, acc, 0, 0, 0);
      acc = __builtin_amdgcn_mfma_f32_16x16x32_bf16(ah, bl, acc, 0, 0, 0);
      acc = __builtin_amdgcn_mfma_f32_16x16x32_bf16(al, bh, acc, 0, 0, 0);
    }
    int col = n0 + (lane & 15);
    float bias = (col >= 512) ? vecf[2064 + col - 512] : 0.f;
    float* outb = (col < 512) ? (uvf + 262144 + col) : (uvf + 393216 + col - 512);
#pragma unroll
    for (int r = 0; r < 4; ++r) {
      int row = i0 + (lane >> 4) * 4 + r;
      outb[row * 512] = acc[r] + bias;
    }
  } else {                  // ep half: f64 streaming on transposed W
    int q = b - 256;
    int col = (q & 1) * 256 + tid;
    int r0 = ((q >> 1) & 63) * 4;
    int arr = q >> 7;
    const float* Wc = wt + arr * 262144 + col * 512;
    const float* e = embf + r0 * 512;
    float bias = (arr == 1) ? vecf[col] : 0.f;
    float* outp = uvf + arr * 131072 + r0 * 512 + col;
    double a0 = 0.0, a1 = 0.0, a2 = 0.0, a3 = 0.0;
    for (int k = 0; k < 512; k += 4) {
      float4 wv = *(const float4*)(Wc + k);
      double w0 = (double)wv.x, w1 = (double)wv.y;
      double w2 = (double)wv.z, w3 = (double)wv.w;
      float2 e0 = *(const float2*)(e + k);
      float2 e1 = *(const float2*)(e + 512 + k);
      float2 e2 = *(const float2*)(e + 1024 + k);
      float2 e3 = *(const float2*)(e + 1536 + k);
      a0 += (double)e0.x * w0 + (double)e0.y * w1;
      a1 += (double)e1.x * w0 + (double)e1.y * w1;
      a2 += (double)e2.x * w0 + (double)e2.y * w1;
      a3 += (double)e3.x * w0 + (double)e3.y * w1;
      float2 f0 = *(const float2*)(e + k + 2);
      float2 f1 = *(const float2*)(e + 512 + k + 2);
      float2 f2 = *(const float2*)(e + 1024 + k + 2);
      float2 f3 = *(const float2*)(e + 1536 + k + 2);
      a0 += (double)f0.x * w2 + (double)f0.y * w3;
      a1 += (double)f1.x * w2 + (double)f1.y * w3;
      a2 += (double)f2.x * w2 + (double)f2.y * w3;
      a3 += (double)f3.x * w2 + (double)f3.y * w3;
    }
    outp[0]    = (float)(a0 + (double)bias);
    outp[512]  = (float)(a1 + (double)bias);
    outp[1024] = (float)(a2 + (double)bias);
    outp[1536] = (float)(a3 + (double)bias);
  }
}

// ---------------- fused: vfrag pack | f64 stats (4 rows/block) ----------------------
// grid 768 x 256 thr. stats rows mapped to waves; per-row math identical.
__global__ __launch_bounds__(256) void k_vfst(const float* uvf, float* vfrag,
    double* sums, double* sumsq) {
  int b = blockIdx.x, tid = threadIdx.x;
  if (b < 512) {            // V rows -> f32 frag-linear
    const float* V = uvf + 393216;
    int idx = b * 256 + tid;
    int e = idx & 7, l = (idx >> 3) & 63, kc = (idx >> 9) & 15, jb = idx >> 13;
    int j = jb * 16 + (l & 15);
    int c = kc * 32 + ((l >> 4) << 3) + e;
    vfrag[idx] = V[j * 512 + c];
  } else {                  // f64 row sums/sumsq, 4 waves = 4 rows
    int lane = tid & 63, w = tid >> 6;
    int bid = (b - 512) * 4 + w;          // arr*256 + row in [0,1024)
    const float* p = uvf + bid * 512;
    double s = 0.0, s2 = 0.0;
    for (int q = lane; q < 512; q += 64) { double v = p[q]; s += v; s2 += v * v; }
#pragma unroll
    for (int m = 1; m < 64; m <<= 1) { s += __shfl_xor(s, m, 64); s2 += __shfl_xor(s2, m, 64); }
    if (lane == 0) { sums[bid] = s; sumsq[bid] = s2; }
  }
}

// ---------------- cross[i][j] = U_i . V_j (f64): z=0 -> ep, z=1 -> ef ---------------
__global__ __launch_bounds__(256) void k_cross(const float* uvf, double* crossep,
                                               double* crossef) {
  __shared__ float Uc[16][132], Vc[16][132];
  int z = blockIdx.z;
  const float* U = uvf + z * 262144;
  const float* V = U + 131072;
  double* out = z ? crossef : crossep;
  int tid = threadIdx.x, ti = tid & 15, tj = tid >> 4;
  int i0 = blockIdx.y * 16, j0 = blockIdx.x * 16;
  double acc = 0.0;
  for (int c0 = 0; c0 < 512; c0 += 128) {
    __syncthreads();
    for (int idx = tid; idx < 2048; idx += 256) {
      int r = idx >> 7, c = idx & 127;
      Uc[r][c] = U[(i0 + r) * 512 + c0 + c];
      Vc[r][c] = V[(j0 + r) * 512 + c0 + c];
    }
    __syncthreads();
#pragma unroll
    for (int c4 = 0; c4 < 128; c4 += 4) {
      float4 uu = *(const float4*)&Uc[ti][c4];
      float4 vv = *(const float4*)&Vc[tj][c4];
      float p = fmaf(uu.x, vv.x, fmaf(uu.y, vv.y, fmaf(uu.z, vv.z, uu.w * vv.w)));
      acc += (double)p;
    }
  }
  out[(i0 + ti) * 256 + j0 + tj] = acc;
}

// ---------------- edge predictor, stats-based tiled (1 thread / pair) ---------------
__global__ __launch_bounds__(256) void k_ep_t(const float* uvf, const double* sums,
    const double* sumsq, const double* crossep, const float* vecf,
    float* act, float* maskv) {
  __shared__ float Uc[16][132], Vc[16][132];
  int tid = threadIdx.x, ti = tid & 15, tj = tid >> 4;
  int i0 = blockIdx.y * 16, j0 = blockIdx.x * 16;
  int i = i0 + ti, j = j0 + tj;
  double md = (sums[i] + sums[256 + j]) * (1.0 / 512.0);
  double qd = (sumsq[i] + 2.0 * crossep[i * 256 + j] + sumsq[256 + j]) * (1.0 / 512.0);
  float iv = (float)(1.0 / sqrt(qd - md * md + 1e-5));
  float bb = (float)(-md) * iv;
  const float* U = uvf;
  const float* V = uvf + 131072;
  const float* g_ = vecf + 512;
  const float* be_ = vecf + 1024;
  const float* w2_ = vecf + 1536;
  double acc = 0.0;
  for (int c0 = 0; c0 < 512; c0 += 128) {
    __syncthreads();
    for (int idx = tid; idx < 2048; idx += 256) {
      int r = idx >> 7, c = idx & 127;
      Uc[r][c] = U[(i0 + r) * 512 + c0 + c];
      Vc[r][c] = V[(j0 + r) * 512 + c0 + c];
    }
    __syncthreads();
#pragma unroll
    for (int c4 = 0; c4 < 128; c4 += 4) {
      float4 uu = *(const float4*)&Uc[ti][c4];
      float4 vv = *(const float4*)&Vc[tj][c4];
      float4 gg = *(const float4*)(g_ + c0 + c4);
      float4 b4 = *(const float4*)(be_ + c0 + c4);
      float4 w4 = *(const float4*)(w2_ + c0 + c4);
      float z, s4 = 0.f;
      z = fmaf(fmaf(uu.x + vv.x, iv, bb), gg.x, b4.x); s4 = fmaf(lrelu(z), w4.x, s4);
      z = fmaf(fmaf(uu.y + vv.y, iv, bb), gg.y, b4.y); s4 = fmaf(lrelu(z), w4.y, s4);
      z = fmaf(fmaf(uu.z + vv.z, iv, bb), gg.z, b4.z); s4 = fmaf(lrelu(z), w4.z, s4);
      z = fmaf(fmaf(uu.w + vv.w, iv, bb), gg.w, b4.w); s4 = fmaf(lrelu(z), w4.w, s4);
      acc += (double)s4;
    }
  }
  double logit = acc + (double)vecf[2048];
  bool a = (logit > 0.0) && (i != j);
  act[i * 256 + j] = a ? 1.0f : 0.0f;
  maskv[j * 256 + i] = (a || i == j) ? 0.f : -1e9f;         // adj[dst][src] mask
}

// ---------------- edge features: all-LDS inner loop + bf16 MFMA (r15, validated) ----
__global__ __launch_bounds__(512, 2) void k_ef(const float* uvf, const double* sums,
    const double* sumsq, const double* crossef, const float* vecf,
    const u16* w2fr, const float* vfrag, float* ef_f) {
  __shared__ u16 w2S[16384];                 // 32 KB: 4 kc x 8 nt x 512
  __shared__ float vS0[4096], vS1[4096];     // 16+16 KB
  __shared__ float uS[8192];                 // 32 KB: 16 rows x 512
  __shared__ float gS[512], beS[512];        // 4 KB
  int tid = threadIdx.x;
  int lane = tid & 63, w = tid >> 6;         // w 0..7
  int bx = blockIdx.x;
  int bi = bx >> 4, bj = bx & 15;
  int i0 = bi * 16;
  int iA = i0 + w * 2, iB = iA + 1;
  int l15 = lane & 15;
  int j = bj * 16 + l15;
  int ksl = (lane >> 4) * 8;

  double sj = sums[768 + j], s2j = sumsq[768 + j];
  double mA = (sums[512 + iA] + sj) * (1.0 / 512.0);
  double qA = (sumsq[512 + iA] + 2.0 * crossef[iA * 256 + j] + s2j) * (1.0 / 512.0);
  float ivA = (float)(1.0 / sqrt(qA - mA * mA + 1e-5));
  float bbA = (float)(-mA) * ivA;
  double mB = (sums[512 + iB] + sj) * (1.0 / 512.0);
  double qB = (sumsq[512 + iB] + 2.0 * crossef[iB * 256 + j] + s2j) * (1.0 / 512.0);
  float ivB = (float)(1.0 / sqrt(qB - mB * mB + 1e-5));
  float bbB = (float)(-mB) * ivB;

  const float* Vg = vfrag + bj * 8192;
  for (int q = tid; q < 2048; q += 512) {
    float4 v = *(const float4*)(Vg + q * 4);
    int kc = q >> 7, r = q & 127, ln = r >> 1;
    if (r & 1) *(float4*)(vS1 + kc * 256 + ln * 4) = v;
    else       *(float4*)(vS0 + kc * 256 + ln * 4) = v;
  }
  const float* Ug = uvf + 262144 + i0 * 512;
  for (int q = tid; q < 2048; q += 512)
    *(float4*)(uS + q * 4) = *(const float4*)(Ug + q * 4);
  if (tid < 128)      *(float4*)(gS + tid * 4)  = *(const float4*)(vecf + 2576 + tid * 4);
  else if (tid < 256) *(float4*)(beS + (tid - 128) * 4) = *(const float4*)(vecf + 3088 + (tid - 128) * 4);

  f32x4 acc[2][8];
#pragma unroll
  for (int ai = 0; ai < 2; ++ai)
#pragma unroll
    for (int bq = 0; bq < 8; ++bq) acc[ai][bq] = (f32x4){0.f, 0.f, 0.f, 0.f};

  auto H8 = [&](float4 u0, float4 u1, float4 v0, float4 v1, float4 g0, float4 g1,
                float4 e0, float4 e1, float iv, float bb) -> short8 {
    short8 a; float z;
    z = fmaf(u0.x + v0.x, iv, bb); z = fmaf(z, g0.x, e0.x); a[0] = (short)f2bf(lrelu(z));
    z = fmaf(u0.y + v0.y, iv, bb); z = fmaf(z, g0.y, e0.y); a[1] = (short)f2bf(lrelu(z));
    z = fmaf(u0.z + v0.z, iv, bb); z = fmaf(z, g0.z, e0.z); a[2] = (short)f2bf(lrelu(z));
    z = fmaf(u0.w + v0.w, iv, bb); z = fmaf(z, g0.w, e0.w); a[3] = (short)f2bf(lrelu(z));
    z = fmaf(u1.x + v1.x, iv, bb); z = fmaf(z, g1.x, e1.x); a[4] = (short)f2bf(lrelu(z));
    z = fmaf(u1.y + v1.y, iv, bb); z = fmaf(z, g1.y, e1.y); a[5] = (short)f2bf(lrelu(z));
    z = fmaf(u1.z + v1.z, iv, bb); z = fmaf(z, g1.z, e1.z); a[6] = (short)f2bf(lrelu(z));
    z = fmaf(u1.w + v1.w, iv, bb); z = fmaf(z, g1.w, e1.w); a[7] = (short)f2bf(lrelu(z));
    return a;
  };

  const float* uA = uS + (w * 2) * 512;
  const float* uB = uA + 512;

  for (int kq = 0; kq < 4; ++kq) {
    __syncthreads();
    const short8* src = (const short8*)(w2fr + kq * 16384);
    for (int q = tid; q < 2048; q += 512)
      *(short8*)(w2S + q * 8) = src[q];
    __syncthreads();
#pragma unroll
    for (int kk = 0; kk < 4; ++kk) {
      int kc = kq * 4 + kk;
      int k0 = kc * 32 + ksl;
      float4 u0 = *(const float4*)(uA + k0);
      float4 u1 = *(const float4*)(uA + k0 + 4);
      float4 b0 = *(const float4*)(uB + k0);
      float4 b1 = *(const float4*)(uB + k0 + 4);
      float4 v0 = *(const float4*)(vS0 + kc * 256 + lane * 4);
      float4 v1 = *(const float4*)(vS1 + kc * 256 + lane * 4);
      float4 g0 = *(const float4*)(gS + k0);
      float4 g1 = *(const float4*)(gS + k0 + 4);
      float4 e0 = *(const float4*)(beS + k0);
      float4 e1 = *(const float4*)(beS + k0 + 4);
      short8 aA = H8(u0, u1, v0, v1, g0, g1, e0, e1, ivA, bbA);
      short8 aB = H8(b0, b1, v0, v1, g0, g1, e0, e1, ivB, bbB);
#pragma unroll
      for (int nt = 0; nt < 8; ++nt) {
        short8 bv = *(const short8*)(w2S + kk * 4096 + nt * 512 + lane * 8);
        acc[0][nt] = __builtin_amdgcn_mfma_f32_16x16x32_bf16(aA, bv, acc[0][nt], 0, 0, 0);
        acc[1][nt] = __builtin_amdgcn_mfma_f32_16x16x32_bf16(aB, bv, acc[1][nt], 0, 0, 0);
      }
    }
  }
#pragma unroll
  for (int mi = 0; mi < 2; ++mi) {
    int ii = mi ? iB : iA;
#pragma unroll
    for (int nt = 0; nt < 8; ++nt) {
      int n = nt * 16 + l15;
      float bias = vecf[3600 + n];
#pragma unroll
      for (int r = 0; r < 4; ++r) {
        int row = (lane >> 4) * 4 + r;
        ef_f[(ii * 256 + bj * 16 + row) * 128 + n] = acc[mi][nt][r] + bias;
      }
    }
  }
}

// ---------------- fused per-layer: wfr(gatW) | xb(x) --------------------------------
// grid 576 x 256 thr.
__global__ __launch_bounds__(256) void k_wfrxb(const float* Wf, u16* wfr,
    const float* x, u16* xfr) {
  int b = blockIdx.x, tid = threadIdx.x;
  if (b < 512) {            // gatW -> frag-linear hi/lo (N=2048 layout)
    int idx = b * 256 + tid;
    int lane = idx & 63, kc = (idx >> 6) & 15, nt = idx >> 10;
    int n = nt * 16 + (lane & 15);
    int c0 = kc * 32 + ((lane >> 4) << 3);
    u16* dst = wfr + idx * 16;
#pragma unroll
    for (int e = 0; e < 8; ++e) {
      float v = Wf[(c0 + e) * 2048 + n];
      u16 hi = f2bf(v);
      dst[e] = hi;
      dst[8 + e] = f2bf(v - bf2f(hi));
    }
  } else {                  // x -> frag-linear hi/lo
    int idx = (b - 512) * 256 + tid;
    int lane = idx & 63, kc = (idx >> 6) & 15, it = idx >> 10;
    int i = it * 16 + (lane & 15);
    int c0 = kc * 32 + ((lane >> 4) << 3);
    const float* src = x + i * 512 + c0;
    float4 v0 = *(const float4*)(src);
    float4 v1 = *(const float4*)(src + 4);
    float vv[8] = {v0.x, v0.y, v0.z, v0.w, v1.x, v1.y, v1.z, v1.w};
    u16* dst = xfr + idx * 16;
#pragma unroll
    for (int e = 0; e < 8; ++e) {
      u16 hi = f2bf(vv[e]);
      dst[e] = hi;
      dst[8 + e] = f2bf(vv[e] - bf2f(hi));
    }
  }
}

// ---------------- GAT s = x @ W[l] as MFMA (hi/lo 3-product) ------------------------
__global__ __launch_bounds__(256) void k_sm(const u16* xfr, const u16* wfr, float* sf) {
  int tid = threadIdx.x, lane = tid & 63, w = tid >> 6;
  int n0 = blockIdx.x * 32 + (w & 1) * 16;     // grid.x = 64
  int i0 = blockIdx.y * 32 + (w >> 1) * 16;    // grid.y = 8
  int it = i0 >> 4, nt = n0 >> 4;
  const u16* ap = xfr + (it * 16) * 1024 + lane * 16;
  const u16* bp = wfr + (nt * 16) * 1024 + lane * 16;
  f32x4 acc = (f32x4){0.f, 0.f, 0.f, 0.f};
#pragma unroll
  for (int kc = 0; kc < 16; ++kc) {
    short8 ah = *(const short8*)(ap + kc * 1024);
    short8 al = *(const short8*)(ap + kc * 1024 + 8);
    short8 bh = *(const short8*)(bp + kc * 1024);
    short8 bl = *(const short8*)(bp + kc * 1024 + 8);
    acc = __builtin_amdgcn_mfma_f32_16x16x32_bf16(ah, bh, acc, 0, 0, 0);
    acc = __builtin_amdgcn_mfma_f32_16x16x32_bf16(ah, bl, acc, 0, 0, 0);
    acc = __builtin_amdgcn_mfma_f32_16x16x32_bf16(al, bh, acc, 0, 0, 0);
  }
  int col = n0 + (lane & 15);
#pragma unroll
  for (int r = 0; r < 4; ++r) {
    int row = i0 + (lane >> 4) * 4 + r;
    sf[row * 2048 + col] = acc[r];
  }
}

// ---------------- generic 256x512 @ K=512 MFMA linear + bias (k_op/k_op2) -----------
__global__ __launch_bounds__(256) void k_opm(const u16* xfr, const u16* wop,
    const float* bias, float* out) {
  int tid = threadIdx.x, lane = tid & 63, w = tid >> 6;
  int n0 = blockIdx.x * 32 + (w & 1) * 16;     // grid.x = 16
  int i0 = blockIdx.y * 32 + (w >> 1) * 16;    // grid.y = 8
  int it = i0 >> 4, nt = n0 >> 4;
  const u16* ap = xfr + (it * 16) * 1024 + lane * 16;
  const u16* bp = wop + (nt * 16) * 1024 + lane * 16;
  f32x4 acc = (f32x4){0.f, 0.f, 0.f, 0.f};
#pragma unroll
  for (int kc = 0; kc < 16; ++kc) {
    short8 ah = *(const short8*)(ap + kc * 1024);
    short8 al = *(const short8*)(ap + kc * 1024 + 8);
    short8 bh = *(const short8*)(bp + kc * 1024);
    short8 bl = *(const short8*)(bp + kc * 1024 + 8);
    acc = __builtin_amdgcn_mfma_f32_16x16x32_bf16(ah, bh, acc, 0, 0, 0);
    acc = __builtin_amdgcn_mfma_f32_16x16x32_bf16(ah, bl, acc, 0, 0, 0);
    acc = __builtin_amdgcn_mfma_f32_16x16x32_bf16(al, bh, acc, 0, 0, 0);
  }
  int col = n0 + (lane & 15);
  float b = bias[col];
#pragma unroll
  for (int r = 0; r < 4; ++r) {
    int row = i0 + (lane >> 4) * 4 + r;
    out[row * 512 + col] = acc[r] + b;
  }
}

// ---------------- fused per-layer: ad (4 waves/block) | st --------------------------
// grid 384 x 256 thr. Bodies verbatim; ad rows mapped to waves.
__global__ __launch_bounds__(256) void k_adst(const float* sf, const float* vecf, int l,
    float* asf, float* adf, u16* sT_hi, u16* sT_lo) {
  __shared__ float T[64][65];
  int b = blockIdx.x, tid = threadIdx.x;
  if (b < 256) {            // a_src/a_dst dots, 4 (n,h) per block
    int lane = tid & 63, w = tid >> 6;
    int bb = b * 4 + w;     // n*4+h in [0,1024)
    int n = bb >> 2, h = bb & 3;
    const float* s = sf + n * 2048 + h * 512;
    const float* as_ = vecf + 3728 + l * 2048 + h * 512;
    const float* ad_ = vecf + 9872 + l * 2048 + h * 512;
    float sa = 0.f, sd = 0.f;
    for (int c = lane; c < 512; c += 64) { sa = fmaf(s[c], as_[c], sa); sd = fmaf(s[c], ad_[c], sd); }
#pragma unroll
    for (int m = 1; m < 64; m <<= 1) { sa += __shfl_xor(sa, m, 64); sd += __shfl_xor(sd, m, 64); }
    if (lane == 0) { asf[bb] = sa; adf[bb] = sd; }
  } else {                  // s transpose -> sT bf16 hi/lo
    int q = b - 256;
    int hc0 = (q & 31) * 64;
    int n0 = (q >> 5) * 64;
    int h = hc0 >> 9, c0 = hc0 & 511, q0 = h * 256 + n0;
    int cl = tid & 63, rw = tid >> 6;
#pragma unroll
    for (int rr = 0; rr < 16; ++rr) {
      int r = rr * 4 + rw;
      T[r][cl] = sf[(n0 + r) * 2048 + hc0 + cl];
    }
    __syncthreads();
#pragma unroll
    for (int rr = 0; rr < 16; ++rr) {
      int r = rr * 4 + rw;
      float v = T[cl][r];
      u16 hi = f2bf(v);
      int o = (c0 + r) * 1024 + q0 + cl;
      sT_hi[o] = hi;
      sT_lo[o] = f2bf(v - bf2f(hi));
    }
  }
}

// ---------------- GAT attention softmax -> alpha bf16 hi/lo [dst][h*256+src] --------
__global__ __launch_bounds__(256) void k_alpha(const float* asf, const float* adf,
    const float* maskv, u16* a_hib, u16* a_lob) {
  int dd = blockIdx.x, s = threadIdx.x;
  int lane = s & 63, w = s >> 6;
  __shared__ float wr[2][4][4];
  float mk = maskv[dd * 256 + s];
  float lg[4];
#pragma unroll
  for (int h = 0; h < 4; ++h) {
    float v = adf[dd * 4 + h] + asf[s * 4 + h];
    lg[h] = lrelu(v) + mk;
  }
#pragma unroll
  for (int h = 0; h < 4; ++h) {
    float v = lg[h];
#pragma unroll
    for (int m = 1; m < 64; m <<= 1) v = fmaxf(v, __shfl_xor(v, m, 64));
    if (lane == 0) wr[0][h][w] = v;
  }
  __syncthreads();
  float e[4];
#pragma unroll
  for (int h = 0; h < 4; ++h) {
    float mx = fmaxf(fmaxf(wr[0][h][0], wr[0][h][1]), fmaxf(wr[0][h][2], wr[0][h][3]));
    float v = __expf(lg[h] - mx);
    e[h] = v;
#pragma unroll
    for (int m = 1; m < 64; m <<= 1) v += __shfl_xor(v, m, 64);
    if (lane == 0) wr[1][h][w] = v;
  }
  __syncthreads();
#pragma unroll
  for (int h = 0; h < 4; ++h) {
    float sm = wr[1][h][0] + wr[1][h][1] + wr[1][h][2] + wr[1][h][3];
    float v = e[h] / sm;
    u16 hi = f2bf(v);
    int o = dd * 1024 + h * 256 + s;
    a_hib[o] = hi;
    a_lob[o] = f2bf(v - bf2f(hi));    // v-hi exact in f32
  }
}

// ---------------- aggregation as MFMA GEMM: x[i][c] = lrelu(0.25*A.B + b) -----------
__global__ __launch_bounds__(256) void k_aggm(const u16* a_hi, const u16* a_lo,
    const u16* sT_hi, const u16* sT_lo, const float* vecf, int l, float* xout) {
  int tid = threadIdx.x, lane = tid & 63, w = tid >> 6;
  int c0 = blockIdx.x * 32 + (w & 1) * 16;     // grid.x = 16
  int i0 = blockIdx.y * 32 + (w >> 1) * 16;    // grid.y = 8
  int kb = (lane >> 4) * 8;
  int ar = (i0 + (lane & 15)) * 1024 + kb;
  int br = (c0 + (lane & 15)) * 1024 + kb;
  f32x4 acc = (f32x4){0.f, 0.f, 0.f, 0.f};
#pragma unroll 4
  for (int k0 = 0; k0 < 1024; k0 += 32) {
    short8 ah = *(const short8*)(a_hi + ar + k0);
    short8 al = *(const short8*)(a_lo + ar + k0);
    short8 bh = *(const short8*)(sT_hi + br + k0);
    short8 bl = *(const short8*)(sT_lo + br + k0);
    acc = __builtin_amdgcn_mfma_f32_16x16x32_bf16(ah, bh, acc, 0, 0, 0);
    acc = __builtin_amdgcn_mfma_f32_16x16x32_bf16(ah, bl, acc, 0, 0, 0);
    acc = __builtin_amdgcn_mfma_f32_16x16x32_bf16(al, bh, acc, 0, 0, 0);
  }
  int c = c0 + (lane & 15);
  float b = vecf[16016 + l * 512 + c];
#pragma unroll
  for (int r = 0; r < 4; ++r) {
    int i = i0 + (lane >> 4) * 4 + r;
    xout[i * 512 + c] = lrelu(fmaf(acc[r], 0.25f, b));
  }
}

// ---------------- output-proj LayerNorm + leaky -> f32 ------------------------------
__global__ __launch_bounds__(256) void k_ln(const float* t1, const float* vecf, float* h1f) {
  const float* g_ = vecf + 18064;
  const float* be_ = vecf + 18576;
  int row = blockIdx.x, tid = threadIdx.x, lane = tid & 63, w = tid >> 6;
  __shared__ float wr[2][4];
  float v0 = t1[row * 512 + tid];
  float v1 = t1[row * 512 + 256 + tid];
  float s = v0 + v1, s2 = fmaf(v0, v0, v1 * v1);
#pragma unroll
  for (int m = 1; m < 64; m <<= 1) { s += __shfl_xor(s, m, 64); s2 += __shfl_xor(s2, m, 64); }
  if (lane == 0) { wr[0][w] = s; wr[1][w] = s2; }
  __syncthreads();
  s = wr[0][0] + wr[0][1] + wr[0][2] + wr[0][3];
  s2 = wr[1][0] + wr[1][1] + wr[1][2] + wr[1][3];
  float m = s * (1.f / 512.f);
  float var = fmaxf(s2 * (1.f / 512.f) - m * m, 0.f);
  float iv = 1.f / sqrtf(var + 1e-5f);
  float z0 = (v0 - m) * iv * g_[tid] + be_[tid];
  float z1 = (v1 - m) * iv * g_[tid + 256] + be_[tid + 256];
  h1f[row * 512 + tid] = lrelu(z0);
  h1f[row * 512 + 256 + tid] = lrelu(z1);
}

extern "C" void kernel_launch(void* const* d_in, const int* in_sizes, int n_in,
                              void* d_out, int out_size, void* d_ws, size_t ws_size,
                              hipStream_t stream) {
  (void)out_size;
  static const int dictT[23] = {0,1,2,3,4,5,6,7,8,9,10,11,12,13,14,15,16,17,18,19,20,21,22};
  static const int alphaT[23] = {6,11,7,10,9,12,8,4,0,3,2,5,1,13,15,14,16,21,17,20,19,22,18};
  const int* tbl = (n_in == 23 && in_sizes[0] == 512) ? alphaT : dictT;
  auto IN = [&](int role) -> const void* { return d_in[tbl[role]]; };

  float* out_f = (float*)d_out;                    // [256,512] f32
  float* act_f = out_f + 256 * 512;                // [256,256] f32 0/1
  float* ef_f  = out_f + 256 * 512 + 256 * 256;    // [256,256,128] f32

  char* cur = (char*)d_ws;
  auto alloc = [&](size_t bytes) -> void* {
    void* r = (void*)cur;
    cur += (bytes + 255) & ~(size_t)255;
    return r;
  };
  float* vecf    = (float*)alloc(20480 * 4);
  float* embf    = (float*)alloc(131072 * 4);
  float* epw1f   = (float*)alloc(524288 * 4);
  float* efw1f   = (float*)alloc(524288 * 4);
  float* gatWf   = (float*)alloc(3145728 * 4);
  float* opw1f   = (float*)alloc(262144 * 4);
  float* opw2f   = (float*)alloc(262144 * 4);
  float* efw2f   = (float*)alloc(65536 * 4);
  float* uvf     = (float*)alloc(524288 * 4);
  float* sf      = (float*)alloc(524288 * 4);
  float* asf     = (float*)alloc(1024 * 4);
  float* adf     = (float*)alloc(1024 * 4);
  float* xf      = (float*)alloc(262144 * 4);
  float* t1      = (float*)alloc(131072 * 4);
  float* h1f     = (float*)alloc(131072 * 4);
  float* maskv   = (float*)alloc(65536 * 4);
  double* sums   = (double*)alloc(1024 * 8);
  double* sumsq  = (double*)alloc(1024 * 8);
  double* crossep = (double*)alloc(65536 * 8);
  double* crossef = (double*)alloc(65536 * 8);
  u16* w2tb      = (u16*)alloc(65536 * 2);
  float* vfrag   = (float*)alloc(131072 * 4);
  u16* wfrb      = (u16*)alloc(2097152 * 2);   // W frag-linear hi/lo (4MB; also ef-pack)
  u16* xfrb      = (u16*)alloc(262144 * 2);    // x frag-linear hi/lo (512KB)
  u16* opw1p     = (u16*)alloc(524288 * 2);    // opw1 frag-linear hi/lo (1MB)
  u16* opw2p     = (u16*)alloc(524288 * 2);    // opw2 frag-linear hi/lo (1MB)
  float* wt      = (float*)alloc(524288 * 4);  // epW1 transposed [arr][col][k] (2MB)
  int* flag      = (int*)alloc(256);
  if ((size_t)(cur - (char*)d_ws) > ws_size) return;

  // GAT-phase buffers aliased onto epw1f/efw1f (both dead after k_uvall):
  u16* sT_hi = (u16*)epw1f;            // 512*1024 u16 = 1 MB
  u16* sT_lo = sT_hi + 524288;         // second 1 MB of epw1f's 2 MB
  u16* a_hib = (u16*)efw1f;            // 256*1024 u16 = 512 KB
  u16* a_lob = a_hib + 262144;         // next 512 KB of efw1f's 2 MB

  hipMemsetAsync(flag, 0, 256, stream);
  hipLaunchKernelGGL(k_detect, dim3(64), dim3(256), 0, stream, (const u16*)IN(0), flag);

  { // small vectors -> canonical f32
    VArgs va;
    auto setV = [&](int qi, int role, int dst, int n) { va.v[qi] = {IN(role), dst, n}; };
    setV(0, 2, 0, 512);       // ep_b1
    setV(1, 3, 512, 512);     // ep_g
    setV(2, 4, 1024, 512);    // ep_beta
    setV(3, 5, 1536, 512);    // ep_w2
    setV(4, 6, 2048, 1);      // ep_b2
    setV(5, 8, 2064, 512);    // ef_b1
    setV(6, 9, 2576, 512);    // ef_g
    setV(7, 10, 3088, 512);   // ef_beta
    setV(8, 12, 3600, 128);   // ef_b2
    setV(9, 14, 3728, 6144);  // gat_a_src
    setV(10, 15, 9872, 6144); // gat_a_dst
    setV(11, 16, 16016, 1536);// gat_b
    setV(12, 18, 17552, 512); // op_b1
    setV(13, 19, 18064, 512); // op_g
    setV(14, 20, 18576, 512); // op_beta
    setV(15, 22, 19088, 512); // op_b2
    hipLaunchKernelGGL(k_vec, dim3(16), dim3(256), 0, stream, va, (const int*)flag, vecf);
  }

  { // big matrices -> canonical f32
    CArgs ca;
    ca.src[0] = IN(0);  ca.dst[0] = embf;  ca.n[0] = 131072;
    ca.src[1] = IN(1);  ca.dst[1] = epw1f; ca.n[1] = 524288;
    ca.src[2] = IN(7);  ca.dst[2] = efw1f; ca.n[2] = 524288;
    ca.src[3] = IN(13); ca.dst[3] = gatWf; ca.n[3] = 3145728;
    ca.src[4] = IN(17); ca.dst[4] = opw1f; ca.n[4] = 262144;
    ca.src[5] = IN(21); ca.dst[5] = opw2f; ca.n[5] = 262144;
    ca.src[6] = IN(11); ca.dst[6] = efw2f; ca.n[6] = 65536;
    hipLaunchKernelGGL(k_cvt, dim3(2048, 7), dim3(256), 0, stream, ca, (const int*)flag);
  }

  // fused packing (w2tb | wop x2 | wt | wfr_ef | xb(emb)) — all post-cvt, independent.
  hipLaunchKernelGGL(k_pack, dim3(960), dim3(256), 0, stream,
                     efw2f, w2tb, opw1f, opw1p, opw2f, opw2p,
                     epw1f, wt, efw1f, wfrb, embf, xfrb);

  // fused U/V: ef half (MFMA) + ep half (f64 on wt).
  hipLaunchKernelGGL(k_uvall, dim3(512), dim3(256), 0, stream,
                     xfrb, wfrb, embf, wt, vecf, uvf);

  // fused vfrag pack + f64 stats.
  hipLaunchKernelGGL(k_vfst, dim3(768), dim3(256), 0, stream, uvf, vfrag, sums, sumsq);
  hipLaunchKernelGGL(k_cross, dim3(16, 16, 2), dim3(256), 0, stream, uvf, crossep, crossef);

  hipLaunchKernelGGL(k_ep_t, dim3(16, 16), dim3(256), 0, stream,
                     uvf, sums, sumsq, crossep, vecf, act_f, maskv);
  hipLaunchKernelGGL(k_ef, dim3(256), dim3(512), 0, stream,
                     uvf, sums, sumsq, crossef, vecf, w2tb, vfrag, ef_f);

  const float* xsrc = embf;
  for (int l = 0; l < 3; ++l) {
    hipLaunchKernelGGL(k_wfrxb, dim3(576), dim3(256), 0, stream,
                       gatWf + l * 1048576, wfrb, xsrc, xfrb);
    hipLaunchKernelGGL(k_sm, dim3(64, 8), dim3(256), 0, stream, xfrb, wfrb, sf);
    hipLaunchKernelGGL(k_adst, dim3(384), dim3(256), 0, stream,
                       sf, vecf, l, asf, adf, sT_hi, sT_lo);
    hipLaunchKernelGGL(k_alpha, dim3(256), dim3(256), 0, stream, asf, adf, maskv,
                       a_hib, a_lob);
    float* xdst = xf + (l & 1) * 131072;
    hipLaunchKernelGGL(k_aggm, dim3(16, 8), dim3(256), 0, stream,
                       a_hib, a_lob, sT_hi, sT_lo, vecf, l, xdst);
    xsrc = xdst;
  }

  // output projection: both linears via validated MFMA path.
  hipLaunchKernelGGL(k_xb, dim3(64), dim3(256), 0, stream, xsrc, xfrb);
  hipLaunchKernelGGL(k_opm, dim3(16, 8), dim3(256), 0, stream,
                     xfrb, opw1p, vecf + 17552, t1);
  hipLaunchKernelGGL(k_ln, dim3(256), dim3(256), 0, stream, t1, vecf, h1f);
  hipLaunchKernelGGL(k_xb, dim3(64), dim3(256), 0, stream, h1f, xfrb);
  hipLaunchKernelGGL(k_opm, dim3(16, 8), dim3(256), 0, stream,
                     xfrb, opw2p, vecf + 19088, out_f);
}

// Round 16
// 348.932 us; speedup vs baseline: 1.2263x; 1.0438x over previous
//
#include <hip/hip_runtime.h>

// NeuralAudioGraph: N=256, D=H=512, E=128, 4 heads, 3 GAT layers.
// r23: (a) k_uvall ep branch stages the 4 emb rows in LDS (8KB) -- kills 1024
// broadcast global loads/thread (the dominant chain after r21's W transpose);
// (b) k_aggm/k_ln pack bf16 hi/lo xfr directly in their epilogues (f32
// store+load is exact -> identical packed values), xfr double-buffered ->
// both standalone k_xb dispatches and xf round-trip traffic removed;
// (c) vfst+cross fused (1280 blocks). 30 -> 27 dispatches. All transforms
// value-identical -> absmax unchanged. Baseline r22: 364.2us, absmax 0.0078125.

typedef __attribute__((ext_vector_type(8))) short short8;   // 8 x bf16 (MFMA frag)
typedef __attribute__((ext_vector_type(4))) float f32x4;    // MFMA accumulator
typedef unsigned short u16;
typedef unsigned int u32;

__device__ __forceinline__ float bf2f(u16 h) { return __uint_as_float(((u32)h) << 16); }
__device__ __forceinline__ u16 f2bf(float f) {
  u32 u = __float_as_uint(f);
  u += 0x7fffu + ((u >> 16) & 1u);   // round-to-nearest-even
  return (u16)(u >> 16);
}
__device__ __forceinline__ float lrelu(float v) { return fmaxf(v, 0.2f * v); }
__device__ __forceinline__ float ldany(int f32mode, const void* p, int i) {
  return f32mode ? ((const float*)p)[i] : bf2f(((const u16*)p)[i]);
}
// pack one f32 value into frag-linear hi/lo layout at (row,col)
__device__ __forceinline__ void packfr(u16* xfr, float v, int row, int col) {
  int lane2 = (row & 15) + (((col >> 3) & 3) << 4);
  int off = (((row >> 4) * 16 + (col >> 5)) * 64 + lane2) * 16 + (col & 7);
  u16 hi = f2bf(v);
  xfr[off] = hi;
  xfr[off + 8] = f2bf(v - bf2f(hi));
}

// ---------------- dtype detector ----------------------------------------------------
__global__ __launch_bounds__(256) void k_detect(const u16* emb, int* flag) {
  bool big = false;
  for (int i = blockIdx.x * 256 + threadIdx.x; i < 131072; i += 256 * 64) {
    float v = bf2f(emb[i]);
    big |= !(fabsf(v) <= 1e6f);
  }
  unsigned long long m = __ballot(big);
  if (m && (threadIdx.x & 63) == 0) atomicOr(flag, 1);
}

// ---------------- small-vector ingest -> canonical f32 ------------------------------
struct VD { const void* src; int dst, n; };
struct VArgs { VD v[16]; };
__global__ __launch_bounds__(256) void k_vec(VArgs a, const int* flag, float* out) {
  int f = *flag;
  VD d = a.v[blockIdx.x];
  for (int i = threadIdx.x; i < d.n; i += 256)
    out[d.dst + i] = ldany(f, d.src, i);
}

// ---------------- big-matrix ingest -> canonical f32 --------------------------------
struct CArgs { const void* src[7]; float* dst[7]; int n[7]; };
__global__ __launch_bounds__(256) void k_cvt(CArgs a, const int* flag) {
  int f = *flag;
  int e = blockIdx.y;
  const void* s = a.src[e];
  float* d = a.dst[e];
  int n = a.n[e];
  for (int i = blockIdx.x * 256 + threadIdx.x; i < n; i += 2048 * 256)
    d[i] = ldany(f, s, i);
}

// ---------------- fused packing: w2tb | wop x2 | wt | wfr_ef | xb(emb) --------------
__global__ __launch_bounds__(256) void k_pack(const float* efw2f, u16* w2fr,
    const float* opw1f, u16* opw1p, const float* opw2f, u16* opw2p,
    const float* epw1f, float* wt, const float* efw1f, u16* wfr,
    const float* embf, u16* xfr) {
  __shared__ float T[64][65];
  int b = blockIdx.x, tid = threadIdx.x;
  if (b < 256) {            // ef_w2 -> frag-linear bf16
    int idx = b * 256 + tid;
    int e = idx & 7, l = (idx >> 3) & 63, nt = (idx >> 9) & 7, kc = idx >> 12;
    int n = nt * 16 + (l & 15);
    int c = kc * 32 + ((l >> 4) << 3) + e;
    w2fr[idx] = f2bf(efw2f[c * 128 + n]);
  } else if (b < 512) {     // opw1/opw2 -> frag-linear hi/lo
    int bb = b - 256;
    const float* Wf = (bb < 128) ? opw1f : opw2f;
    u16* wop = (bb < 128) ? opw1p : opw2p;
    int idx = (bb & 127) * 256 + tid;
    int lane = idx & 63, kc = (idx >> 6) & 15, nt = idx >> 10;
    int n = nt * 16 + (lane & 15);
    int c0 = kc * 32 + ((lane >> 4) << 3);
    u16* dst = wop + idx * 16;
#pragma unroll
    for (int e = 0; e < 8; ++e) {
      float v = Wf[(c0 + e) * 512 + n];
      u16 hi = f2bf(v);
      dst[e] = hi;
      dst[8 + e] = f2bf(v - bf2f(hi));
    }
  } else if (b < 640) {     // epW1 -> wt[arr][col][k] transpose
    int q = b - 512;
    int k0 = (q & 7) * 64, c0 = ((q >> 3) & 7) * 64, z = q >> 6;
    const float* src = epw1f + z * 262144;
    float* dst = wt + z * 262144;
    int cl = tid & 63, rw = tid >> 6;
#pragma unroll
    for (int rr = 0; rr < 16; ++rr) {
      int r = rr * 4 + rw;
      T[r][cl] = src[(k0 + r) * 512 + c0 + cl];
    }
    __syncthreads();
#pragma unroll
    for (int rr = 0; rr < 16; ++rr) {
      int r = rr * 4 + rw;
      dst[(c0 + r) * 512 + k0 + cl] = T[cl][r];
    }
  } else if (b < 896) {     // efW1 (2 halves) -> frag-linear hi/lo, N=1024
    int idx = (b - 640) * 256 + tid;
    int lane = idx & 63, kc = (idx >> 6) & 15, nt = idx >> 10;
    int n = nt * 16 + (lane & 15);
    int c0 = kc * 32 + ((lane >> 4) << 3);
    const float* base = (n < 512) ? (efw1f + n) : (efw1f + 262144 + n - 512);
    u16* dst = wfr + idx * 16;
#pragma unroll
    for (int e = 0; e < 8; ++e) {
      float v = base[(c0 + e) * 512];
      u16 hi = f2bf(v);
      dst[e] = hi;
      dst[8 + e] = f2bf(v - bf2f(hi));
    }
  } else {                  // emb -> frag-linear hi/lo
    int idx = (b - 896) * 256 + tid;
    int lane = idx & 63, kc = (idx >> 6) & 15, it = idx >> 10;
    int i = it * 16 + (lane & 15);
    int c0 = kc * 32 + ((lane >> 4) << 3);
    const float* src = embf + i * 512 + c0;
    float4 v0 = *(const float4*)(src);
    float4 v1 = *(const float4*)(src + 4);
    float vv[8] = {v0.x, v0.y, v0.z, v0.w, v1.x, v1.y, v1.z, v1.w};
    u16* dst = xfr + idx * 16;
#pragma unroll
    for (int e = 0; e < 8; ++e) {
      u16 hi = f2bf(vv[e]);
      dst[e] = hi;
      dst[8 + e] = f2bf(vv[e] - bf2f(hi));
    }
  }
}

// ---------------- fused U/V: uvef (MFMA) | ep-uv (f64 on wt, emb in LDS) ------------
// grid 512 x 256 thr. Same values & accumulation order as r22 -> bit-identical.
__global__ __launch_bounds__(256) void k_uvall(const u16* xfr, const u16* wfr,
    const float* embf, const float* wt, const float* vecf, float* uvf) {
  __shared__ float eS[2048];
  int b = blockIdx.x, tid = threadIdx.x;
  if (b < 256) {            // ef half via MFMA hi/lo 3-product
    int lane = tid & 63, w = tid >> 6;
    int n0 = (b & 31) * 32 + (w & 1) * 16;
    int i0 = (b >> 5) * 32 + (w >> 1) * 16;
    int it = i0 >> 4, nt = n0 >> 4;
    const u16* ap = xfr + (it * 16) * 1024 + lane * 16;
    const u16* bp = wfr + (nt * 16) * 1024 + lane * 16;
    f32x4 acc = (f32x4){0.f, 0.f, 0.f, 0.f};
#pragma unroll
    for (int kc = 0; kc < 16; ++kc) {
      short8 ah = *(const short8*)(ap + kc * 1024);
      short8 al = *(const short8*)(ap + kc * 1024 + 8);
      short8 bh = *(const short8*)(bp + kc * 1024);
      short8 bl = *(const short8*)(bp + kc * 1024 + 8);
      acc = __builtin_amdgcn_mfma_f32_16x16x32_bf16(ah, bh, acc, 0, 0, 0);
      acc = __builtin_amdgcn_mfma_f32_16x16x32_bf16(ah, bl, acc, 0, 0, 0);
      acc = __builtin_amdgcn_mfma_f32_16x16x32_bf16(al, bh, acc, 0, 0, 0);
    }
    int col = n0 + (lane & 15);
    float bias = (col >= 512) ? vecf[2064 + col - 512] : 0.f;
    float* outb = (col < 512) ? (uvf + 262144 + col) : (uvf + 393216 + col - 512);
#pragma unroll
    for (int r = 0; r < 4; ++r) {
      int row = i0 + (lane >> 4) * 4 + r;
      outb[row * 512] = acc[r] + bias;
    }
  } else {                  // ep half: f64 streaming, W from wt, emb from LDS
    int q = b - 256;
    int col = (q & 1) * 256 + tid;
    int r0 = ((q >> 1) & 63) * 4;
    int arr = q >> 7;
    const float* Wc = wt + arr * 262144 + col * 512;
    const float* eg = embf + r0 * 512;
    for (int qq = tid; qq < 512; qq += 256)
      *(float4*)(eS + qq * 4) = *(const float4*)(eg + qq * 4);
    __syncthreads();
    float bias = (arr == 1) ? vecf[col] : 0.f;
    float* outp = uvf + arr * 131072 + r0 * 512 + col;
    double a0 = 0.0, a1 = 0.0, a2 = 0.0, a3 = 0.0;
    for (int k = 0; k < 512; k += 4) {
      float4 wv = *(const float4*)(Wc + k);
      double w0 = (double)wv.x, w1 = (double)wv.y;
      double w2 = (double)wv.z, w3 = (double)wv.w;
      float2 e0 = *(const float2*)(eS + k);
      float2 e1 = *(const float2*)(eS + 512 + k);
      float2 e2 = *(const float2*)(eS + 1024 + k);
      float2 e3 = *(const float2*)(eS + 1536 + k);
      a0 += (double)e0.x * w0 + (double)e0.y * w1;
      a1 += (double)e1.x * w0 + (double)e1.y * w1;
      a2 += (double)e2.x * w0 + (double)e2.y * w1;
      a3 += (double)e3.x * w0 + (double)e3.y * w1;
      float2 f0 = *(const float2*)(eS + k + 2);
      float2 f1 = *(const float2*)(eS + 512 + k + 2);
      float2 f2 = *(const float2*)(eS + 1024 + k + 2);
      float2 f3 = *(const float2*)(eS + 1536 + k + 2);
      a0 += (double)f0.x * w2 + (double)f0.y * w3;
      a1 += (double)f1.x * w2 + (double)f1.y * w3;
      a2 += (double)f2.x * w2 + (double)f2.y * w3;
      a3 += (double)f3.x * w2 + (double)f3.y * w3;
    }
    outp[0]    = (float)(a0 + (double)bias);
    outp[512]  = (float)(a1 + (double)bias);
    outp[1024] = (float)(a2 + (double)bias);
    outp[1536] = (float)(a3 + (double)bias);
  }
}

// ---------------- fused: vfrag pack | f64 stats | cross (f64) -----------------------
// grid 1280 x 256 thr. Bodies verbatim from r22 -> bit-identical.
__global__ __launch_bounds__(256) void k_vfcr(const float* uvf, float* vfrag,
    double* sums, double* sumsq, double* crossep, double* crossef) {
  __shared__ float Uc[16][132], Vc[16][132];
  int b = blockIdx.x, tid = threadIdx.x;
  if (b < 512) {            // V rows -> f32 frag-linear
    const float* V = uvf + 393216;
    int idx = b * 256 + tid;
    int e = idx & 7, l = (idx >> 3) & 63, kc = (idx >> 9) & 15, jb = idx >> 13;
    int j = jb * 16 + (l & 15);
    int c = kc * 32 + ((l >> 4) << 3) + e;
    vfrag[idx] = V[j * 512 + c];
  } else if (b < 768) {     // f64 row sums/sumsq, 4 waves = 4 rows
    int lane = tid & 63, w = tid >> 6;
    int bid = (b - 512) * 4 + w;          // arr*256 + row in [0,1024)
    const float* p = uvf + bid * 512;
    double s = 0.0, s2 = 0.0;
    for (int q = lane; q < 512; q += 64) { double v = p[q]; s += v; s2 += v * v; }
#pragma unroll
    for (int m = 1; m < 64; m <<= 1) { s += __shfl_xor(s, m, 64); s2 += __shfl_xor(s2, m, 64); }
    if (lane == 0) { sums[bid] = s; sumsq[bid] = s2; }
  } else {                  // cross tiles
    int q = b - 768;
    int z = q >> 8, rem = q & 255;
    const float* U = uvf + z * 262144;
    const float* V = U + 131072;
    double* out = z ? crossef : crossep;
    int ti = tid & 15, tj = tid >> 4;
    int i0 = (rem >> 4) * 16, j0 = (rem & 15) * 16;
    double acc = 0.0;
    for (int c0 = 0; c0 < 512; c0 += 128) {
      __syncthreads();
      for (int idx = tid; idx < 2048; idx += 256) {
        int r = idx >> 7, c = idx & 127;
        Uc[r][c] = U[(i0 + r) * 512 + c0 + c];
        Vc[r][c] = V[(j0 + r) * 512 + c0 + c];
      }
      __syncthreads();
#pragma unroll
      for (int c4 = 0; c4 < 128; c4 += 4) {
        float4 uu = *(const float4*)&Uc[ti][c4];
        float4 vv = *(const float4*)&Vc[tj][c4];
        float p = fmaf(uu.x, vv.x, fmaf(uu.y, vv.y, fmaf(uu.z, vv.z, uu.w * vv.w)));
        acc += (double)p;
      }
    }
    out[(i0 + ti) * 256 + j0 + tj] = acc;
  }
}

// ---------------- edge predictor, stats-based tiled (1 thread / pair) ---------------
__global__ __launch_bounds__(256) void k_ep_t(const float* uvf, const double* sums,
    const double* sumsq, const double* crossep, const float* vecf,
    float* act, float* maskv) {
  __shared__ float Uc[16][132], Vc[16][132];
  int tid = threadIdx.x, ti = tid & 15, tj = tid >> 4;
  int i0 = blockIdx.y * 16, j0 = blockIdx.x * 16;
  int i = i0 + ti, j = j0 + tj;
  double md = (sums[i] + sums[256 + j]) * (1.0 / 512.0);
  double qd = (sumsq[i] + 2.0 * crossep[i * 256 + j] + sumsq[256 + j]) * (1.0 / 512.0);
  float iv = (float)(1.0 / sqrt(qd - md * md + 1e-5));
  float bb = (float)(-md) * iv;
  const float* U = uvf;
  const float* V = uvf + 131072;
  const float* g_ = vecf + 512;
  const float* be_ = vecf + 1024;
  const float* w2_ = vecf + 1536;
  double acc = 0.0;
  for (int c0 = 0; c0 < 512; c0 += 128) {
    __syncthreads();
    for (int idx = tid; idx < 2048; idx += 256) {
      int r = idx >> 7, c = idx & 127;
      Uc[r][c] = U[(i0 + r) * 512 + c0 + c];
      Vc[r][c] = V[(j0 + r) * 512 + c0 + c];
    }
    __syncthreads();
#pragma unroll
    for (int c4 = 0; c4 < 128; c4 += 4) {
      float4 uu = *(const float4*)&Uc[ti][c4];
      float4 vv = *(const float4*)&Vc[tj][c4];
      float4 gg = *(const float4*)(g_ + c0 + c4);
      float4 b4 = *(const float4*)(be_ + c0 + c4);
      float4 w4 = *(const float4*)(w2_ + c0 + c4);
      float z, s4 = 0.f;
      z = fmaf(fmaf(uu.x + vv.x, iv, bb), gg.x, b4.x); s4 = fmaf(lrelu(z), w4.x, s4);
      z = fmaf(fmaf(uu.y + vv.y, iv, bb), gg.y, b4.y); s4 = fmaf(lrelu(z), w4.y, s4);
      z = fmaf(fmaf(uu.z + vv.z, iv, bb), gg.z, b4.z); s4 = fmaf(lrelu(z), w4.z, s4);
      z = fmaf(fmaf(uu.w + vv.w, iv, bb), gg.w, b4.w); s4 = fmaf(lrelu(z), w4.w, s4);
      acc += (double)s4;
    }
  }
  double logit = acc + (double)vecf[2048];
  bool a = (logit > 0.0) && (i != j);
  act[i * 256 + j] = a ? 1.0f : 0.0f;
  maskv[j * 256 + i] = (a || i == j) ? 0.f : -1e9f;         // adj[dst][src] mask
}

// ---------------- edge features: all-LDS inner loop + bf16 MFMA (r15, validated) ----
__global__ __launch_bounds__(512, 2) void k_ef(const float* uvf, const double* sums,
    const double* sumsq, const double* crossef, const float* vecf,
    const u16* w2fr, const float* vfrag, float* ef_f) {
  __shared__ u16 w2S[16384];                 // 32 KB: 4 kc x 8 nt x 512
  __shared__ float vS0[4096], vS1[4096];     // 16+16 KB
  __shared__ float uS[8192];                 // 32 KB: 16 rows x 512
  __shared__ float gS[512], beS[512];        // 4 KB
  int tid = threadIdx.x;
  int lane = tid & 63, w = tid >> 6;         // w 0..7
  int bx = blockIdx.x;
  int bi = bx >> 4, bj = bx & 15;
  int i0 = bi * 16;
  int iA = i0 + w * 2, iB = iA + 1;
  int l15 = lane & 15;
  int j = bj * 16 + l15;
  int ksl = (lane >> 4) * 8;

  double sj = sums[768 + j], s2j = sumsq[768 + j];
  double mA = (sums[512 + iA] + sj) * (1.0 / 512.0);
  double qA = (sumsq[512 + iA] + 2.0 * crossef[iA * 256 + j] + s2j) * (1.0 / 512.0);
  float ivA = (float)(1.0 / sqrt(qA - mA * mA + 1e-5));
  float bbA = (float)(-mA) * ivA;
  double mB = (sums[512 + iB] + sj) * (1.0 / 512.0);
  double qB = (sumsq[512 + iB] + 2.0 * crossef[iB * 256 + j] + s2j) * (1.0 / 512.0);
  float ivB = (float)(1.0 / sqrt(qB - mB * mB + 1e-5));
  float bbB = (float)(-mB) * ivB;

  const float* Vg = vfrag + bj * 8192;
  for (int q = tid; q < 2048; q += 512) {
    float4 v = *(const float4*)(Vg + q * 4);
    int kc = q >> 7, r = q & 127, ln = r >> 1;
    if (r & 1) *(float4*)(vS1 + kc * 256 + ln * 4) = v;
    else       *(float4*)(vS0 + kc * 256 + ln * 4) = v;
  }
  const float* Ug = uvf + 262144 + i0 * 512;
  for (int q = tid; q < 2048; q += 512)
    *(float4*)(uS + q * 4) = *(const float4*)(Ug + q * 4);
  if (tid < 128)      *(float4*)(gS + tid * 4)  = *(const float4*)(vecf + 2576 + tid * 4);
  else if (tid < 256) *(float4*)(beS + (tid - 128) * 4) = *(const float4*)(vecf + 3088 + (tid - 128) * 4);

  f32x4 acc[2][8];
#pragma unroll
  for (int ai = 0; ai < 2; ++ai)
#pragma unroll
    for (int bq = 0; bq < 8; ++bq) acc[ai][bq] = (f32x4){0.f, 0.f, 0.f, 0.f};

  auto H8 = [&](float4 u0, float4 u1, float4 v0, float4 v1, float4 g0, float4 g1,
                float4 e0, float4 e1, float iv, float bb) -> short8 {
    short8 a; float z;
    z = fmaf(u0.x + v0.x, iv, bb); z = fmaf(z, g0.x, e0.x); a[0] = (short)f2bf(lrelu(z));
    z = fmaf(u0.y + v0.y, iv, bb); z = fmaf(z, g0.y, e0.y); a[1] = (short)f2bf(lrelu(z));
    z = fmaf(u0.z + v0.z, iv, bb); z = fmaf(z, g0.z, e0.z); a[2] = (short)f2bf(lrelu(z));
    z = fmaf(u0.w + v0.w, iv, bb); z = fmaf(z, g0.w, e0.w); a[3] = (short)f2bf(lrelu(z));
    z = fmaf(u1.x + v1.x, iv, bb); z = fmaf(z, g1.x, e1.x); a[4] = (short)f2bf(lrelu(z));
    z = fmaf(u1.y + v1.y, iv, bb); z = fmaf(z, g1.y, e1.y); a[5] = (short)f2bf(lrelu(z));
    z = fmaf(u1.z + v1.z, iv, bb); z = fmaf(z, g1.z, e1.z); a[6] = (short)f2bf(lrelu(z));
    z = fmaf(u1.w + v1.w, iv, bb); z = fmaf(z, g1.w, e1.w); a[7] = (short)f2bf(lrelu(z));
    return a;
  };

  const float* uA = uS + (w * 2) * 512;
  const float* uB = uA + 512;

  for (int kq = 0; kq < 4; ++kq) {
    __syncthreads();
    const short8* src = (const short8*)(w2fr + kq * 16384);
    for (int q = tid; q < 2048; q += 512)
      *(short8*)(w2S + q * 8) = src[q];
    __syncthreads();
#pragma unroll
    for (int kk = 0; kk < 4; ++kk) {
      int kc = kq * 4 + kk;
      int k0 = kc * 32 + ksl;
      float4 u0 = *(const float4*)(uA + k0);
      float4 u1 = *(const float4*)(uA + k0 + 4);
      float4 b0 = *(const float4*)(uB + k0);
      float4 b1 = *(const float4*)(uB + k0 + 4);
      float4 v0 = *(const float4*)(vS0 + kc * 256 + lane * 4);
      float4 v1 = *(const float4*)(vS1 + kc * 256 + lane * 4);
      float4 g0 = *(const float4*)(gS + k0);
      float4 g1 = *(const float4*)(gS + k0 + 4);
      float4 e0 = *(const float4*)(beS + k0);
      float4 e1 = *(const float4*)(beS + k0 + 4);
      short8 aA = H8(u0, u1, v0, v1, g0, g1, e0, e1, ivA, bbA);
      short8 aB = H8(b0, b1, v0, v1, g0, g1, e0, e1, ivB, bbB);
#pragma unroll
      for (int nt = 0; nt < 8; ++nt) {
        short8 bv = *(const short8*)(w2S + kk * 4096 + nt * 512 + lane * 8);
        acc[0][nt] = __builtin_amdgcn_mfma_f32_16x16x32_bf16(aA, bv, acc[0][nt], 0, 0, 0);
        acc[1][nt] = __builtin_amdgcn_mfma_f32_16x16x32_bf16(aB, bv, acc[1][nt], 0, 0, 0);
      }
    }
  }
#pragma unroll
  for (int mi = 0; mi < 2; ++mi) {
    int ii = mi ? iB : iA;
#pragma unroll
    for (int nt = 0; nt < 8; ++nt) {
      int n = nt * 16 + l15;
      float bias = vecf[3600 + n];
#pragma unroll
      for (int r = 0; r < 4; ++r) {
        int row = (lane >> 4) * 4 + r;
        ef_f[(ii * 256 + bj * 16 + row) * 128 + n] = acc[mi][nt][r] + bias;
      }
    }
  }
}

// ---------------- GAT W[l] -> fragment-linear interleaved bf16 hi/lo ----------------
__global__ __launch_bounds__(256) void k_wfr(const float* Wf, u16* wfr) {
  int idx = blockIdx.x * 256 + threadIdx.x;   // 131072
  int lane = idx & 63, kc = (idx >> 6) & 15, nt = idx >> 10;
  int n = nt * 16 + (lane & 15);
  int c0 = kc * 32 + ((lane >> 4) << 3);
  u16* dst = wfr + idx * 16;
#pragma unroll
  for (int e = 0; e < 8; ++e) {
    float v = Wf[(c0 + e) * 2048 + n];
    u16 hi = f2bf(v);
    dst[e] = hi;
    dst[8 + e] = f2bf(v - bf2f(hi));
  }
}

// ---------------- GAT s = x @ W[l] as MFMA (hi/lo 3-product) ------------------------
__global__ __launch_bounds__(256) void k_sm(const u16* xfr, const u16* wfr, float* sf) {
  int tid = threadIdx.x, lane = tid & 63, w = tid >> 6;
  int n0 = blockIdx.x * 32 + (w & 1) * 16;     // grid.x = 64
  int i0 = blockIdx.y * 32 + (w >> 1) * 16;    // grid.y = 8
  int it = i0 >> 4, nt = n0 >> 4;
  const u16* ap = xfr + (it * 16) * 1024 + lane * 16;
  const u16* bp = wfr + (nt * 16) * 1024 + lane * 16;
  f32x4 acc = (f32x4){0.f, 0.f, 0.f, 0.f};
#pragma unroll
  for (int kc = 0; kc < 16; ++kc) {
    short8 ah = *(const short8*)(ap + kc * 1024);
    short8 al = *(const short8*)(ap + kc * 1024 + 8);
    short8 bh = *(const short8*)(bp + kc * 1024);
    short8 bl = *(const short8*)(bp + kc * 1024 + 8);
    acc = __builtin_amdgcn_mfma_f32_16x16x32_bf16(ah, bh, acc, 0, 0, 0);
    acc = __builtin_amdgcn_mfma_f32_16x16x32_bf16(ah, bl, acc, 0, 0, 0);
    acc = __builtin_amdgcn_mfma_f32_16x16x32_bf16(al, bh, acc, 0, 0, 0);
  }
  int col = n0 + (lane & 15);
#pragma unroll
  for (int r = 0; r < 4; ++r) {
    int row = i0 + (lane >> 4) * 4 + r;
    sf[row * 2048 + col] = acc[r];
  }
}

// ---------------- generic 256x512 @ K=512 MFMA linear + bias (k_op/k_op2) -----------
__global__ __launch_bounds__(256) void k_opm(const u16* xfr, const u16* wop,
    const float* bias, float* out) {
  int tid = threadIdx.x, lane = tid & 63, w = tid >> 6;
  int n0 = blockIdx.x * 32 + (w & 1) * 16;     // grid.x = 16
  int i0 = blockIdx.y * 32 + (w >> 1) * 16;    // grid.y = 8
  int it = i0 >> 4, nt = n0 >> 4;
  const u16* ap = xfr + (it * 16) * 1024 + lane * 16;
  const u16* bp = wop + (nt * 16) * 1024 + lane * 16;
  f32x4 acc = (f32x4){0.f, 0.f, 0.f, 0.f};
#pragma unroll
  for (int kc = 0; kc < 16; ++kc) {
    short8 ah = *(const short8*)(ap + kc * 1024);
    short8 al = *(const short8*)(ap + kc * 1024 + 8);
    short8 bh = *(const short8*)(bp + kc * 1024);
    short8 bl = *(const short8*)(bp + kc * 1024 + 8);
    acc = __builtin_amdgcn_mfma_f32_16x16x32_bf16(ah, bh, acc, 0, 0, 0);
    acc = __builtin_amdgcn_mfma_f32_16x16x32_bf16(ah, bl, acc, 0, 0, 0);
    acc = __builtin_amdgcn_mfma_f32_16x16x32_bf16(al, bh, acc, 0, 0, 0);
  }
  int col = n0 + (lane & 15);
  float b = bias[col];
#pragma unroll
  for (int r = 0; r < 4; ++r) {
    int row = i0 + (lane >> 4) * 4 + r;
    out[row * 512 + col] = acc[r] + b;
  }
}

// ---------------- fused per-layer: ad (4 waves/block) | st --------------------------
__global__ __launch_bounds__(256) void k_adst(const float* sf, const float* vecf, int l,
    float* asf, float* adf, u16* sT_hi, u16* sT_lo) {
  __shared__ float T[64][65];
  int b = blockIdx.x, tid = threadIdx.x;
  if (b < 256) {            // a_src/a_dst dots, 4 (n,h) per block
    int lane = tid & 63, w = tid >> 6;
    int bb = b * 4 + w;     // n*4+h in [0,1024)
    int n = bb >> 2, h = bb & 3;
    const float* s = sf + n * 2048 + h * 512;
    const float* as_ = vecf + 3728 + l * 2048 + h * 512;
    const float* ad_ = vecf + 9872 + l * 2048 + h * 512;
    float sa = 0.f, sd = 0.f;
    for (int c = lane; c < 512; c += 64) { sa = fmaf(s[c], as_[c], sa); sd = fmaf(s[c], ad_[c], sd); }
#pragma unroll
    for (int m = 1; m < 64; m <<= 1) { sa += __shfl_xor(sa, m, 64); sd += __shfl_xor(sd, m, 64); }
    if (lane == 0) { asf[bb] = sa; adf[bb] = sd; }
  } else {                  // s transpose -> sT bf16 hi/lo
    int q = b - 256;
    int hc0 = (q & 31) * 64;
    int n0 = (q >> 5) * 64;
    int h = hc0 >> 9, c0 = hc0 & 511, q0 = h * 256 + n0;
    int cl = tid & 63, rw = tid >> 6;
#pragma unroll
    for (int rr = 0; rr < 16; ++rr) {
      int r = rr * 4 + rw;
      T[r][cl] = sf[(n0 + r) * 2048 + hc0 + cl];
    }
    __syncthreads();
#pragma unroll
    for (int rr = 0; rr < 16; ++rr) {
      int r = rr * 4 + rw;
      float v = T[cl][r];
      u16 hi = f2bf(v);
      int o = (c0 + r) * 1024 + q0 + cl;
      sT_hi[o] = hi;
      sT_lo[o] = f2bf(v - bf2f(hi));
    }
  }
}

// ---------------- GAT attention softmax -> alpha bf16 hi/lo [dst][h*256+src] --------
__global__ __launch_bounds__(256) void k_alpha(const float* asf, const float* adf,
    const float* maskv, u16* a_hib, u16* a_lob) {
  int dd = blockIdx.x, s = threadIdx.x;
  int lane = s & 63, w = s >> 6;
  __shared__ float wr[2][4][4];
  float mk = maskv[dd * 256 + s];
  float lg[4];
#pragma unroll
  for (int h = 0; h < 4; ++h) {
    float v = adf[dd * 4 + h] + asf[s * 4 + h];
    lg[h] = lrelu(v) + mk;
  }
#pragma unroll
  for (int h = 0; h < 4; ++h) {
    float v = lg[h];
#pragma unroll
    for (int m = 1; m < 64; m <<= 1) v = fmaxf(v, __shfl_xor(v, m, 64));
    if (lane == 0) wr[0][h][w] = v;
  }
  __syncthreads();
  float e[4];
#pragma unroll
  for (int h = 0; h < 4; ++h) {
    float mx = fmaxf(fmaxf(wr[0][h][0], wr[0][h][1]), fmaxf(wr[0][h][2], wr[0][h][3]));
    float v = __expf(lg[h] - mx);
    e[h] = v;
#pragma unroll
    for (int m = 1; m < 64; m <<= 1) v += __shfl_xor(v, m, 64);
    if (lane == 0) wr[1][h][w] = v;
  }
  __syncthreads();
#pragma unroll
  for (int h = 0; h < 4; ++h) {
    float sm = wr[1][h][0] + wr[1][h][1] + wr[1][h][2] + wr[1][h][3];
    float v = e[h] / sm;
    u16 hi = f2bf(v);
    int o = dd * 1024 + h * 256 + s;
    a_hib[o] = hi;
    a_lob[o] = f2bf(v - bf2f(hi));    // v-hi exact in f32
  }
}

// ---------------- aggregation MFMA GEMM; epilogue packs xfr directly ----------------
// x[i][c] = lrelu(0.25*A.B + b); pack hi/lo into xfr_out (identical values to the
// old store->k_xb path since f32 store/load is exact).
__global__ __launch_bounds__(256) void k_aggm(const u16* a_hi, const u16* a_lo,
    const u16* sT_hi, const u16* sT_lo, const float* vecf, int l, u16* xfr_out) {
  int tid = threadIdx.x, lane = tid & 63, w = tid >> 6;
  int c0 = blockIdx.x * 32 + (w & 1) * 16;     // grid.x = 16
  int i0 = blockIdx.y * 32 + (w >> 1) * 16;    // grid.y = 8
  int kb = (lane >> 4) * 8;
  int ar = (i0 + (lane & 15)) * 1024 + kb;
  int br = (c0 + (lane & 15)) * 1024 + kb;
  f32x4 acc = (f32x4){0.f, 0.f, 0.f, 0.f};
#pragma unroll 4
  for (int k0 = 0; k0 < 1024; k0 += 32) {
    short8 ah = *(const short8*)(a_hi + ar + k0);
    short8 al = *(const short8*)(a_lo + ar + k0);
    short8 bh = *(const short8*)(sT_hi + br + k0);
    short8 bl = *(const short8*)(sT_lo + br + k0);
    acc = __builtin_amdgcn_mfma_f32_16x16x32_bf16(ah, bh, acc, 0, 0, 0);
    acc = __builtin_amdgcn_mfma_f32_16x16x32_bf16(ah, bl, acc, 0, 0, 0);
    acc = __builtin_amdgcn_mfma_f32_16x16x32_bf16(al, bh, acc, 0, 0, 0);
  }
  int c = c0 + (lane & 15);
  float b = vecf[16016 + l * 512 + c];
#pragma unroll
  for (int r = 0; r < 4; ++r) {
    int i = i0 + (lane >> 4) * 4 + r;
    packfr(xfr_out, lrelu(fmaf(acc[r], 0.25f, b)), i, c);
  }
}

// ---------------- output-proj LayerNorm + leaky -> packs xfr directly ---------------
__global__ __launch_bounds__(256) void k_ln(const float* t1, const float* vecf,
                                            u16* xfr_out) {
  const float* g_ = vecf + 18064;
  const float* be_ = vecf + 18576;
  int row = blockIdx.x, tid = threadIdx.x, lane = tid & 63, w = tid >> 6;
  __shared__ float wr[2][4];
  float v0 = t1[row * 512 + tid];
  float v1 = t1[row * 512 + 256 + tid];
  float s = v0 + v1, s2 = fmaf(v0, v0, v1 * v1);
#pragma unroll
  for (int m = 1; m < 64; m <<= 1) { s += __shfl_xor(s, m, 64); s2 += __shfl_xor(s2, m, 64); }
  if (lane == 0) { wr[0][w] = s; wr[1][w] = s2; }
  __syncthreads();
  s = wr[0][0] + wr[0][1] + wr[0][2] + wr[0][3];
  s2 = wr[1][0] + wr[1][1] + wr[1][2] + wr[1][3];
  float m = s * (1.f / 512.f);
  float var = fmaxf(s2 * (1.f / 512.f) - m * m, 0.f);
  float iv = 1.f / sqrtf(var + 1e-5f);
  float z0 = (v0 - m) * iv * g_[tid] + be_[tid];
  float z1 = (v1 - m) * iv * g_[tid + 256] + be_[tid + 256];
  packfr(xfr_out, lrelu(z0), row, tid);
  packfr(xfr_out, lrelu(z1), row, tid + 256);
}

extern "C" void kernel_launch(void* const* d_in, const int* in_sizes, int n_in,
                              void* d_out, int out_size, void* d_ws, size_t ws_size,
                              hipStream_t stream) {
  (void)out_size;
  static const int dictT[23] = {0,1,2,3,4,5,6,7,8,9,10,11,12,13,14,15,16,17,18,19,20,21,22};
  static const int alphaT[23] = {6,11,7,10,9,12,8,4,0,3,2,5,1,13,15,14,16,21,17,20,19,22,18};
  const int* tbl = (n_in == 23 && in_sizes[0] == 512) ? alphaT : dictT;
  auto IN = [&](int role) -> const void* { return d_in[tbl[role]]; };

  float* out_f = (float*)d_out;                    // [256,512] f32
  float* act_f = out_f + 256 * 512;                // [256,256] f32 0/1
  float* ef_f  = out_f + 256 * 512 + 256 * 256;    // [256,256,128] f32

  char* cur = (char*)d_ws;
  auto alloc = [&](size_t bytes) -> void* {
    void* r = (void*)cur;
    cur += (bytes + 255) & ~(size_t)255;
    return r;
  };
  float* vecf    = (float*)alloc(20480 * 4);
  float* embf    = (float*)alloc(131072 * 4);
  float* epw1f   = (float*)alloc(524288 * 4);
  float* efw1f   = (float*)alloc(524288 * 4);
  float* gatWf   = (float*)alloc(3145728 * 4);
  float* opw1f   = (float*)alloc(262144 * 4);
  float* opw2f   = (float*)alloc(262144 * 4);
  float* efw2f   = (float*)alloc(65536 * 4);
  float* uvf     = (float*)alloc(524288 * 4);
  float* sf      = (float*)alloc(524288 * 4);
  float* asf     = (float*)alloc(1024 * 4);
  float* adf     = (float*)alloc(1024 * 4);
  float* t1      = (float*)alloc(131072 * 4);
  float* maskv   = (float*)alloc(65536 * 4);
  double* sums   = (double*)alloc(1024 * 8);
  double* sumsq  = (double*)alloc(1024 * 8);
  double* crossep = (double*)alloc(65536 * 8);
  double* crossef = (double*)alloc(65536 * 8);
  u16* w2tb      = (u16*)alloc(65536 * 2);
  float* vfrag   = (float*)alloc(131072 * 4);
  u16* wfrb      = (u16*)alloc(2097152 * 2);   // W frag-linear hi/lo (4MB; also ef-pack)
  u16* xfrA      = (u16*)alloc(262144 * 2);    // x frag-linear hi/lo buf A (512KB)
  u16* xfrB      = (u16*)alloc(262144 * 2);    // x frag-linear hi/lo buf B (512KB)
  u16* opw1p     = (u16*)alloc(524288 * 2);    // opw1 frag-linear hi/lo (1MB)
  u16* opw2p     = (u16*)alloc(524288 * 2);    // opw2 frag-linear hi/lo (1MB)
  float* wt      = (float*)alloc(524288 * 4);  // epW1 transposed [arr][col][k] (2MB)
  int* flag      = (int*)alloc(256);
  if ((size_t)(cur - (char*)d_ws) > ws_size) return;

  // GAT-phase buffers aliased onto epw1f/efw1f (both dead after k_uvall):
  u16* sT_hi = (u16*)epw1f;            // 512*1024 u16 = 1 MB
  u16* sT_lo = sT_hi + 524288;         // second 1 MB of epw1f's 2 MB
  u16* a_hib = (u16*)efw1f;            // 256*1024 u16 = 512 KB
  u16* a_lob = a_hib + 262144;         // next 512 KB of efw1f's 2 MB

  hipMemsetAsync(flag, 0, 256, stream);
  hipLaunchKernelGGL(k_detect, dim3(64), dim3(256), 0, stream, (const u16*)IN(0), flag);

  { // small vectors -> canonical f32
    VArgs va;
    auto setV = [&](int qi, int role, int dst, int n) { va.v[qi] = {IN(role), dst, n}; };
    setV(0, 2, 0, 512);       // ep_b1
    setV(1, 3, 512, 512);     // ep_g
    setV(2, 4, 1024, 512);    // ep_beta
    setV(3, 5, 1536, 512);    // ep_w2
    setV(4, 6, 2048, 1);      // ep_b2
    setV(5, 8, 2064, 512);    // ef_b1
    setV(6, 9, 2576, 512);    // ef_g
    setV(7, 10, 3088, 512);   // ef_beta
    setV(8, 12, 3600, 128);   // ef_b2
    setV(9, 14, 3728, 6144);  // gat_a_src
    setV(10, 15, 9872, 6144); // gat_a_dst
    setV(11, 16, 16016, 1536);// gat_b
    setV(12, 18, 17552, 512); // op_b1
    setV(13, 19, 18064, 512); // op_g
    setV(14, 20, 18576, 512); // op_beta
    setV(15, 22, 19088, 512); // op_b2
    hipLaunchKernelGGL(k_vec, dim3(16), dim3(256), 0, stream, va, (const int*)flag, vecf);
  }

  { // big matrices -> canonical f32
    CArgs ca;
    ca.src[0] = IN(0);  ca.dst[0] = embf;  ca.n[0] = 131072;
    ca.src[1] = IN(1);  ca.dst[1] = epw1f; ca.n[1] = 524288;
    ca.src[2] = IN(7);  ca.dst[2] = efw1f; ca.n[2] = 524288;
    ca.src[3] = IN(13); ca.dst[3] = gatWf; ca.n[3] = 3145728;
    ca.src[4] = IN(17); ca.dst[4] = opw1f; ca.n[4] = 262144;
    ca.src[5] = IN(21); ca.dst[5] = opw2f; ca.n[5] = 262144;
    ca.src[6] = IN(11); ca.dst[6] = efw2f; ca.n[6] = 65536;
    hipLaunchKernelGGL(k_cvt, dim3(2048, 7), dim3(256), 0, stream, ca, (const int*)flag);
  }

  // fused packing (w2tb | wop x2 | wt | wfr_ef | xb(emb)->xfrA).
  hipLaunchKernelGGL(k_pack, dim3(960), dim3(256), 0, stream,
                     efw2f, w2tb, opw1f, opw1p, opw2f, opw2p,
                     epw1f, wt, efw1f, wfrb, embf, xfrA);

  // fused U/V: ef half (MFMA) + ep half (f64 on wt, emb staged in LDS).
  hipLaunchKernelGGL(k_uvall, dim3(512), dim3(256), 0, stream,
                     xfrA, wfrb, embf, wt, vecf, uvf);

  // fused vfrag pack + f64 stats + cross.
  hipLaunchKernelGGL(k_vfcr, dim3(1280), dim3(256), 0, stream,
                     uvf, vfrag, sums, sumsq, crossep, crossef);

  hipLaunchKernelGGL(k_ep_t, dim3(16, 16), dim3(256), 0, stream,
                     uvf, sums, sumsq, crossep, vecf, act_f, maskv);
  hipLaunchKernelGGL(k_ef, dim3(256), dim3(512), 0, stream,
                     uvf, sums, sumsq, crossef, vecf, w2tb, vfrag, ef_f);

  // GAT layers; x flows through alternating xfr buffers (packed in epilogues).
  u16* xcur = xfrA;
  u16* xnxt = xfrB;
  for (int l = 0; l < 3; ++l) {
    hipLaunchKernelGGL(k_wfr, dim3(512), dim3(256), 0, stream,
                       gatWf + l * 1048576, wfrb);
    hipLaunchKernelGGL(k_sm, dim3(64, 8), dim3(256), 0, stream, xcur, wfrb, sf);
    hipLaunchKernelGGL(k_adst, dim3(384), dim3(256), 0, stream,
                       sf, vecf, l, asf, adf, sT_hi, sT_lo);
    hipLaunchKernelGGL(k_alpha, dim3(256), dim3(256), 0, stream, asf, adf, maskv,
                       a_hib, a_lob);
    hipLaunchKernelGGL(k_aggm, dim3(16, 8), dim3(256), 0, stream,
                       a_hib, a_lob, sT_hi, sT_lo, vecf, l, xnxt);
    u16* t = xcur; xcur = xnxt; xnxt = t;
  }

  // output projection: both linears via validated MFMA path; ln packs directly.
  hipLaunchKernelGGL(k_opm, dim3(16, 8), dim3(256), 0, stream,
                     xcur, opw1p, vecf + 17552, t1);
  hipLaunchKernelGGL(k_ln, dim3(256), dim3(256), 0, stream, t1, vecf, xnxt);
  hipLaunchKernelGGL(k_opm, dim3(16, 8), dim3(256), 0, stream,
                     xnxt, opw2p, vecf + 19088, out_f);
}